// Round 1
// baseline (14569.693 us; speedup 1.0000x reference)
//
#include <hip/hip_runtime.h>
#include <hip/hip_bf16.h>
#include <cstddef>

// Problem constants
#define BB 8
#define LL 5
#define NN 4096
#define NANCH 64
#define NPTS 4160      // NN + NANCH
#define MM 260         // NPTS / 16
#define NFRAME 3
#define SSEQ 780       // NFRAME * MM
#define DIMC 512
#define NHEAD 8
#define DHEAD 64
#define MLPD 1024
#define OUTD 1088
#define NROWS 6240     // BB * SSEQ

// exact (non-contracted) squared distance, matching numpy fp32 op order:
// ((dx*dx + dy*dy) + dz*dz), each op round-to-nearest
__device__ __forceinline__ float sqdist_rn(float x1, float y1, float z1,
                                           float x2, float y2, float z2) {
    float dx = __fsub_rn(x1, x2);
    float dy = __fsub_rn(y1, y2);
    float dz = __fsub_rn(z1, z2);
    return __fadd_rn(__fadd_rn(__fmul_rn(dx, dx), __fmul_rn(dy, dy)), __fmul_rn(dz, dz));
}

__device__ __forceinline__ float gelu_exact(float v) {
    return 0.5f * v * (1.0f + erff(v * 0.70710678118654752440f));
}

// ---------------------------------------------------------------------------
// Build pts = concat(points, anchor_grid) : (B, L, NPTS, 3)
// anchors: linspace(-1.5,1.5,4) meshgrid 'ij', C-order ravel
// ---------------------------------------------------------------------------
__global__ __launch_bounds__(256) void build_pts_kernel(const float* __restrict__ points,
                                                        float* __restrict__ pts) {
    int i = blockIdx.x * 256 + threadIdx.x;   // over B*L*NPTS = 166400
    if (i >= BB * LL * NPTS) return;
    int n = i % NPTS;
    int bl = i / NPTS;
    if (n < NN) {
        const float* src = points + ((size_t)bl * NN + n) * 3;
        pts[(size_t)i * 3 + 0] = src[0];
        pts[(size_t)i * 3 + 1] = src[1];
        pts[(size_t)i * 3 + 2] = src[2];
    } else {
        int j = n - NN;
        int ix = j >> 4, iy = (j >> 2) & 3, iz = j & 3;
        pts[(size_t)i * 3 + 0] = -1.5f + (float)ix;
        pts[(size_t)i * 3 + 1] = -1.5f + (float)iy;
        pts[(size_t)i * 3 + 2] = -1.5f + (float)iz;
    }
}

// ---------------------------------------------------------------------------
// Farthest point sampling: 1 block per (b, f). Sequential 260 iterations.
// idx[0]=0; each step: dist=min(dist, d(pts, pts[last])); last=argmax(dist)
// argmax tie-break = smallest index (numpy first-occurrence).
// Writes a_xyz coords directly: axyz[(b*3+f)*260 + m][3]
// ---------------------------------------------------------------------------
__global__ __launch_bounds__(256) void fps_kernel(const float* __restrict__ pts,
                                                  float* __restrict__ axyz) {
    int blk = blockIdx.x;           // 0..23
    int b = blk / 3, f = blk % 3;
    const float* P = pts + (size_t)(b * LL + 2 * f) * NPTS * 3;
    int tid = threadIdx.x;
    const int PPT = 17;             // ceil(4160/256)
    float px[PPT], py[PPT], pz[PPT], dist[PPT];
#pragma unroll
    for (int j = 0; j < PPT; j++) {
        int n = tid + 256 * j;
        if (n < NPTS) {
            px[j] = P[(size_t)n * 3 + 0];
            py[j] = P[(size_t)n * 3 + 1];
            pz[j] = P[(size_t)n * 3 + 2];
            dist[j] = 1e10f;
        } else {
            px[j] = 0.f; py[j] = 0.f; pz[j] = 0.f;
            dist[j] = -1.0f;   // never selected
        }
    }
    __shared__ float lx, ly, lz;
    __shared__ float redv[4];
    __shared__ int redi[4];
    if (tid == 0) { lx = px[0]; ly = py[0]; lz = pz[0]; }   // last = 0
    __syncthreads();
    float* out = axyz + (size_t)blk * MM * 3;
    for (int m = 0; m < MM; m++) {
        float ax = lx, ay = ly, az = lz;
        if (tid == 0) { out[m * 3 + 0] = ax; out[m * 3 + 1] = ay; out[m * 3 + 2] = az; }
        float bestv = -1.0f;
        int bestn = NPTS;
#pragma unroll
        for (int j = 0; j < PPT; j++) {
            int n = tid + 256 * j;
            if (n < NPTS) {
                float d = sqdist_rn(px[j], py[j], pz[j], ax, ay, az);
                float dj = fminf(dist[j], d);
                dist[j] = dj;
                if (dj > bestv) { bestv = dj; bestn = n; }   // strict: smaller n kept on tie
            }
        }
#pragma unroll
        for (int off = 32; off; off >>= 1) {
            float ov = __shfl_xor(bestv, off);
            int on = __shfl_xor(bestn, off);
            if (ov > bestv || (ov == bestv && on < bestn)) { bestv = ov; bestn = on; }
        }
        if ((tid & 63) == 0) { redv[tid >> 6] = bestv; redi[tid >> 6] = bestn; }
        __syncthreads();
        if (tid == 0) {
            float bv = redv[0]; int bn = redi[0];
#pragma unroll
            for (int w = 1; w < 4; w++) {
                if (redv[w] > bv || (redv[w] == bv && redi[w] < bn)) { bv = redv[w]; bn = redi[w]; }
            }
            lx = P[(size_t)bn * 3 + 0];
            ly = P[(size_t)bn * 3 + 1];
            lz = P[(size_t)bn * 3 + 2];
        }
        __syncthreads();
    }
}

// ---------------------------------------------------------------------------
// Ball query (first K=32 indices with d2 < 0.49, ascending) + grouped conv +
// max over k + max over 3 window frames + positional embedding.
// 1 block (64 threads) per (b, f, m). Writes x[b, f*260+m, 512].
// ---------------------------------------------------------------------------
__global__ __launch_bounds__(64) void group_conv_kernel(
    const float* __restrict__ pts, const float* __restrict__ axyz,
    const float* __restrict__ conv_d_w, const float* __restrict__ conv_f_w,
    const float* __restrict__ pos_w, const float* __restrict__ pos_b,
    float* __restrict__ x) {
    int gid = blockIdx.x;                 // b*780 + f*260 + m
    int b = gid / SSEQ;
    int rem = gid % SSEQ;
    int f = rem / MM;
    int lane = threadIdx.x;
    const float* A = axyz + (size_t)gid * 3;
    float ax = A[0], ay = A[1], az = A[2];

    float cf0[8], cf1[8], cf2[8], cd0[8], cd1[8], cd2[8], cd3[8], fmx[8];
#pragma unroll
    for (int c = 0; c < 8; c++) {
        int d = lane + 64 * c;
        cf0[c] = conv_f_w[d * 3 + 0];
        cf1[c] = conv_f_w[d * 3 + 1];
        cf2[c] = conv_f_w[d * 3 + 2];
        cd0[c] = conv_d_w[d * 4 + 0];
        cd1[c] = conv_d_w[d * 4 + 1];
        cd2[c] = conv_d_w[d * 4 + 2];
        cd3[c] = conv_d_w[d * 4 + 3];
        fmx[c] = -INFINITY;
    }
    __shared__ int nbr[32];
    __shared__ float gxs[32], gys[32], gzs[32];
    const float R2 = 0.49000000953674316f;   // (float)(0.7*0.7) in double

    for (int wi = 0; wi < 3; wi++) {
        int l = 2 * f + wi - 1;
        l = l < 0 ? 0 : (l > 4 ? 4 : l);
        const float* P = pts + (size_t)(b * LL + l) * NPTS * 3;
        int cnt = 0;
        for (int base = 0; base < NPTS && cnt < 32; base += 64) {
            int n = base + lane;            // NPTS = 65*64, no guard needed
            float d2 = sqdist_rn(P[(size_t)n * 3], P[(size_t)n * 3 + 1], P[(size_t)n * 3 + 2],
                                 ax, ay, az);
            bool hit = d2 < R2;
            unsigned long long mk = __ballot(hit);
            int rank = (int)__popcll(mk & (((unsigned long long)1 << lane) - 1ull));
            if (hit && (cnt + rank) < 32) nbr[cnt + rank] = n;
            cnt += (int)__popcll(mk);
        }
        __syncthreads();
        int eff = cnt < 32 ? cnt : 32;
        if (lane < 32) {
            int idx = (eff == 0) ? 0 : (lane < eff ? nbr[lane] : nbr[0]);
            gxs[lane] = P[(size_t)idx * 3 + 0];
            gys[lane] = P[(size_t)idx * 3 + 1];
            gzs[lane] = P[(size_t)idx * 3 + 2];
        }
        __syncthreads();
        float tf = (float)(wi - 1);
        for (int k = 0; k < 32; k++) {
            float gx = gxs[k], gy = gys[k], gz = gzs[k];
            float dx = gx - ax, dy = gy - ay, dz = gz - az;
#pragma unroll
            for (int c = 0; c < 8; c++) {
                float v = gx * cf0[c] + gy * cf1[c] + gz * cf2[c] +
                          dx * cd0[c] + dy * cd1[c] + dz * cd2[c] + tf * cd3[c];
                fmx[c] = fmaxf(fmx[c], v);
            }
        }
        __syncthreads();
    }
    float tcol = (float)(f + 1);
#pragma unroll
    for (int c = 0; c < 8; c++) {
        int d = lane + 64 * c;
        float pos = ax * pos_w[d * 4 + 0] + ay * pos_w[d * 4 + 1] +
                    az * pos_w[d * 4 + 2] + tcol * pos_w[d * 4 + 3] + pos_b[d];
        x[(size_t)gid * DIMC + d] = fmx[c] + pos;
    }
}

// ---------------------------------------------------------------------------
// LayerNorm over last dim 512. 1 wave per row.
// ---------------------------------------------------------------------------
__global__ __launch_bounds__(64) void ln_kernel(const float* __restrict__ x,
                                                const float* __restrict__ g,
                                                const float* __restrict__ b,
                                                float* __restrict__ y) {
    int r = blockIdx.x;
    int lane = threadIdx.x;
    const float* xr = x + (size_t)r * DIMC;
    float4 v0 = *(const float4*)(xr + lane * 8);
    float4 v1 = *(const float4*)(xr + lane * 8 + 4);
    float s = v0.x + v0.y + v0.z + v0.w + v1.x + v1.y + v1.z + v1.w;
#pragma unroll
    for (int off = 32; off; off >>= 1) s += __shfl_xor(s, off);
    float mean = s * (1.0f / 512.0f);
    float d0 = v0.x - mean, d1 = v0.y - mean, d2 = v0.z - mean, d3 = v0.w - mean;
    float d4 = v1.x - mean, d5 = v1.y - mean, d6 = v1.z - mean, d7 = v1.w - mean;
    float sq = d0 * d0 + d1 * d1 + d2 * d2 + d3 * d3 + d4 * d4 + d5 * d5 + d6 * d6 + d7 * d7;
#pragma unroll
    for (int off = 32; off; off >>= 1) sq += __shfl_xor(sq, off);
    float var = sq * (1.0f / 512.0f);
    float inv = 1.0f / sqrtf(var + 1e-5f);
    float* yr = y + (size_t)r * DIMC;
    int d = lane * 8;
    yr[d + 0] = d0 * inv * g[d + 0] + b[d + 0];
    yr[d + 1] = d1 * inv * g[d + 1] + b[d + 1];
    yr[d + 2] = d2 * inv * g[d + 2] + b[d + 2];
    yr[d + 3] = d3 * inv * g[d + 3] + b[d + 3];
    yr[d + 4] = d4 * inv * g[d + 4] + b[d + 4];
    yr[d + 5] = d5 * inv * g[d + 5] + b[d + 5];
    yr[d + 6] = d6 * inv * g[d + 6] + b[d + 6];
    yr[d + 7] = d7 * inv * g[d + 7] + b[d + 7];
}

// ---------------------------------------------------------------------------
// Generic fp32 GEMM: C(M,N) = A(M,K) @ W(K,N)  [row-major]
// EPI: 0 = none, 2 = +bias then gelu, 3 = +bias +residual R
// Requires K%16==0, N%64==0 (true for 512/1024/1536).
// ---------------------------------------------------------------------------
#define TM 64
#define TN 64
#define TK 16
#define LPAD 68

template <int EPI>
__global__ __launch_bounds__(256) void gemm_kernel(const float* __restrict__ A,
                                                   const float* __restrict__ W,
                                                   const float* __restrict__ bias,
                                                   const float* R, float* C,
                                                   int M, int N, int K) {
    __shared__ float As[TK][LPAD];
    __shared__ float Bs[TK][LPAD];
    int tid = threadIdx.x;
    int n0 = blockIdx.x * TN;
    int m0 = blockIdx.y * TM;
    int tx = tid & 15, ty = tid >> 4;
    int la_m = tid >> 2;            // 0..63
    int la_k = (tid & 3) * 4;       // 0,4,8,12
    int lb_k = tid >> 4;            // 0..15
    int lb_n = (tid & 15) * 4;      // 0..60
    float acc[4][4] = {};
    for (int k0 = 0; k0 < K; k0 += TK) {
        float4 av = make_float4(0.f, 0.f, 0.f, 0.f);
        if (m0 + la_m < M) av = *(const float4*)(A + (size_t)(m0 + la_m) * K + k0 + la_k);
        As[la_k + 0][la_m] = av.x;
        As[la_k + 1][la_m] = av.y;
        As[la_k + 2][la_m] = av.z;
        As[la_k + 3][la_m] = av.w;
        float4 bv = *(const float4*)(W + (size_t)(k0 + lb_k) * N + n0 + lb_n);
        *(float4*)&Bs[lb_k][lb_n] = bv;
        __syncthreads();
#pragma unroll
        for (int kk = 0; kk < TK; kk++) {
            float4 a4 = *(const float4*)&As[kk][ty * 4];
            float4 b4 = *(const float4*)&Bs[kk][tx * 4];
            acc[0][0] += a4.x * b4.x; acc[0][1] += a4.x * b4.y;
            acc[0][2] += a4.x * b4.z; acc[0][3] += a4.x * b4.w;
            acc[1][0] += a4.y * b4.x; acc[1][1] += a4.y * b4.y;
            acc[1][2] += a4.y * b4.z; acc[1][3] += a4.y * b4.w;
            acc[2][0] += a4.z * b4.x; acc[2][1] += a4.z * b4.y;
            acc[2][2] += a4.z * b4.z; acc[2][3] += a4.z * b4.w;
            acc[3][0] += a4.w * b4.x; acc[3][1] += a4.w * b4.y;
            acc[3][2] += a4.w * b4.z; acc[3][3] += a4.w * b4.w;
        }
        __syncthreads();
    }
#pragma unroll
    for (int i = 0; i < 4; i++) {
        int row = m0 + ty * 4 + i;
        if (row < M) {
#pragma unroll
            for (int j = 0; j < 4; j++) {
                int col = n0 + tx * 4 + j;
                float v = acc[i][j];
                if (EPI >= 2) v += bias[col];
                if (EPI == 2) v = gelu_exact(v);
                if (EPI == 3) v += R[(size_t)row * N + col];
                C[(size_t)row * N + col] = v;
            }
        }
    }
}

// ---------------------------------------------------------------------------
// Attention: 1 block (256 threads) per (query s, head h, batch b).
// qkv layout (B, S, 1536): q @ +0, k @ +512, v @ +1024; inner = h*64+d.
// ---------------------------------------------------------------------------
__global__ __launch_bounds__(256) void attn_kernel(const float* __restrict__ qkv,
                                                   float* __restrict__ o) {
    int sq = blockIdx.x, h = blockIdx.y, b = blockIdx.z;
    int tid = threadIdx.x;
    __shared__ float qs[64];
    __shared__ float sc[SSEQ];
    __shared__ float red[256];
    const float* qrow = qkv + ((size_t)(b * SSEQ + sq) * 1536) + h * 64;
    if (tid < 64) qs[tid] = qrow[tid];
    __syncthreads();
    for (int k0 = tid; k0 < SSEQ; k0 += 256) {
        const float* kr = qkv + ((size_t)(b * SSEQ + k0) * 1536) + 512 + h * 64;
        float dot = 0.f;
#pragma unroll
        for (int d = 0; d < 64; d += 4) {
            float4 kk = *(const float4*)(kr + d);
            float4 qq = *(const float4*)(qs + d);
            dot += qq.x * kk.x + qq.y * kk.y + qq.z * kk.z + qq.w * kk.w;
        }
        sc[k0] = dot * 0.125f;
    }
    __syncthreads();
    float lm = -INFINITY;
    for (int k0 = tid; k0 < SSEQ; k0 += 256) lm = fmaxf(lm, sc[k0]);
    red[tid] = lm;
    __syncthreads();
    for (int s = 128; s > 0; s >>= 1) {
        if (tid < s) red[tid] = fmaxf(red[tid], red[tid + s]);
        __syncthreads();
    }
    float gm = red[0];
    __syncthreads();
    float ls = 0.f;
    for (int k0 = tid; k0 < SSEQ; k0 += 256) {
        float p = expf(sc[k0] - gm);
        sc[k0] = p;
        ls += p;
    }
    red[tid] = ls;
    __syncthreads();
    for (int s = 128; s > 0; s >>= 1) {
        if (tid < s) red[tid] += red[tid + s];
        __syncthreads();
    }
    float gs = red[0];
    __syncthreads();
    int d = tid & 63, ty = tid >> 6;
    const float* vbase = qkv + (size_t)b * SSEQ * 1536 + 1024 + h * 64 + d;
    float acc = 0.f;
    for (int k = ty; k < SSEQ; k += 4) acc += sc[k] * vbase[(size_t)k * 1536];
    red[tid] = acc;
    __syncthreads();
    if (ty == 0) {
        float s4 = red[d] + red[64 + d] + red[128 + d] + red[192 + d];
        o[((size_t)(b * SSEQ + sq)) * DIMC + h * 64 + d] = s4 / gs;
    }
}

// ---------------------------------------------------------------------------
// Final head
// ---------------------------------------------------------------------------
__global__ __launch_bounds__(512) void pool_ln_kernel(const float* __restrict__ x,
                                                      const float* __restrict__ g,
                                                      const float* __restrict__ b,
                                                      float* __restrict__ out) {
    int bb = blockIdx.x;
    int d = threadIdx.x;
    const float* xb = x + (size_t)bb * SSEQ * DIMC + d;
    float m = -INFINITY;
    for (int s = 0; s < SSEQ; s++) m = fmaxf(m, xb[(size_t)s * DIMC]);
    __shared__ float col[512];
    __shared__ float red[512];
    col[d] = m;
    red[d] = m;
    __syncthreads();
    for (int s = 256; s > 0; s >>= 1) {
        if (d < s) red[d] += red[d + s];
        __syncthreads();
    }
    float mean = red[0] * (1.0f / 512.0f);
    __syncthreads();
    float dv = col[d] - mean;
    red[d] = dv * dv;
    __syncthreads();
    for (int s = 256; s > 0; s >>= 1) {
        if (d < s) red[d] += red[d + s];
        __syncthreads();
    }
    float var = red[0] * (1.0f / 512.0f);
    float inv = 1.0f / sqrtf(var + 1e-5f);
    out[(size_t)bb * DIMC + d] = dv * inv * g[d] + b[d];
}

__global__ __launch_bounds__(256) void head1_kernel(const float* __restrict__ in,
                                                    const float* __restrict__ W,
                                                    const float* __restrict__ bias,
                                                    float* __restrict__ out) {
    int bb = blockIdx.x;
    int tid = threadIdx.x;
    __shared__ float xr[512];
    xr[tid] = in[(size_t)bb * 512 + tid];
    xr[tid + 256] = in[(size_t)bb * 512 + tid + 256];
    __syncthreads();
    float acc[4] = {0.f, 0.f, 0.f, 0.f};
    for (int k = 0; k < 512; k++) {
        float xv = xr[k];
#pragma unroll
        for (int i = 0; i < 4; i++) acc[i] += xv * W[(size_t)k * 1024 + tid + 256 * i];
    }
#pragma unroll
    for (int i = 0; i < 4; i++) {
        int n = tid + 256 * i;
        out[(size_t)bb * 1024 + n] = gelu_exact(acc[i] + bias[n]);
    }
}

__global__ __launch_bounds__(256) void head2_kernel(const float* __restrict__ in,
                                                    const float* __restrict__ W,
                                                    const float* __restrict__ bias,
                                                    float* __restrict__ out) {
    int bb = blockIdx.x;
    int tid = threadIdx.x;
    __shared__ float xr[1024];
    xr[tid] = in[(size_t)bb * 1024 + tid];
    xr[tid + 256] = in[(size_t)bb * 1024 + tid + 256];
    xr[tid + 512] = in[(size_t)bb * 1024 + tid + 512];
    xr[tid + 768] = in[(size_t)bb * 1024 + tid + 768];
    __syncthreads();
    float acc[5] = {0.f, 0.f, 0.f, 0.f, 0.f};
    for (int k = 0; k < 1024; k++) {
        float xv = xr[k];
#pragma unroll
        for (int i = 0; i < 4; i++) acc[i] += xv * W[(size_t)k * OUTD + tid + 256 * i];
        if (tid < 64) acc[4] += xv * W[(size_t)k * OUTD + 1024 + tid];
    }
#pragma unroll
    for (int i = 0; i < 4; i++) {
        int n = tid + 256 * i;
        out[(size_t)bb * OUTD + n] = acc[i] + bias[n];
    }
    if (tid < 64) out[(size_t)bb * OUTD + 1024 + tid] = acc[4] + bias[1024 + tid];
}

__global__ __launch_bounds__(64) void smax_anchor_kernel(const float* __restrict__ h2,
                                                         float* __restrict__ out) {
    int bb = blockIdx.x / 17;
    int gcol = blockIdx.x % 17;
    int j = threadIdx.x;
    float v = h2[(size_t)bb * OUTD + gcol * 64 + j];
    float mx = v;
#pragma unroll
    for (int off = 32; off; off >>= 1) mx = fmaxf(mx, __shfl_xor(mx, off));
    float p = expf(v - mx);
    float sum = p;
#pragma unroll
    for (int off = 32; off; off >>= 1) sum += __shfl_xor(sum, off);
    int ix = j >> 4, iy = (j >> 2) & 3, iz = j & 3;
    float sx = p * (-1.5f + (float)ix);
    float sy = p * (-1.5f + (float)iy);
    float sz = p * (-1.5f + (float)iz);
#pragma unroll
    for (int off = 32; off; off >>= 1) {
        sx += __shfl_xor(sx, off);
        sy += __shfl_xor(sy, off);
        sz += __shfl_xor(sz, off);
    }
    if (j == 0) {
        float* o = out + ((size_t)bb * 17 + gcol) * 3;
        o[0] = sx / sum;
        o[1] = sy / sum;
        o[2] = sz / sum;
    }
}

// ---------------------------------------------------------------------------
extern "C" void kernel_launch(void* const* d_in, const int* in_sizes, int n_in,
                              void* d_out, int out_size, void* d_ws, size_t ws_size,
                              hipStream_t stream) {
    const float* points     = (const float*)d_in[0];
    const float* conv_d_w   = (const float*)d_in[1];
    const float* conv_f_w   = (const float*)d_in[2];
    const float* pos_w      = (const float*)d_in[3];
    const float* pos_b      = (const float*)d_in[4];
    const float* ln1_g      = (const float*)d_in[5];
    const float* ln1_b      = (const float*)d_in[6];
    const float* qkv_w      = (const float*)d_in[7];
    const float* attn_out_w = (const float*)d_in[8];
    const float* attn_out_b = (const float*)d_in[9];
    const float* ln2_g      = (const float*)d_in[10];
    const float* ln2_b      = (const float*)d_in[11];
    const float* ff1_w      = (const float*)d_in[12];
    const float* ff1_b      = (const float*)d_in[13];
    const float* ff2_w      = (const float*)d_in[14];
    const float* ff2_b      = (const float*)d_in[15];
    const float* head_ln_g  = (const float*)d_in[16];
    const float* head_ln_b  = (const float*)d_in[17];
    const float* head1_w    = (const float*)d_in[18];
    const float* head1_b    = (const float*)d_in[19];
    const float* head2_w    = (const float*)d_in[20];
    const float* head2_b    = (const float*)d_in[21];

    // workspace layout (floats); total ~19.7M floats = ~75 MiB
    float* ws = (float*)d_ws;
    float* pts    = ws;                    // 499200
    float* axyz   = pts + 499200;          // 18720
    float* xbuf   = axyz + 18720;          // 3194880
    float* xn     = xbuf + 3194880;        // 3194880
    float* qkv    = xn + 3194880;          // 9584640 (reused as ffh)
    float* attno  = qkv + 9584640;         // 3194880
    float* pooled = attno + 3194880;       // 4096
    float* h1     = pooled + 4096;         // 8192
    float* h2     = h1 + 8192;             // 8704
    float* ffh    = qkv;                   // alias: qkv dead after attention

    build_pts_kernel<<<650, 256, 0, stream>>>(points, pts);
    fps_kernel<<<24, 256, 0, stream>>>(pts, axyz);
    group_conv_kernel<<<NROWS, 64, 0, stream>>>(pts, axyz, conv_d_w, conv_f_w,
                                                pos_w, pos_b, xbuf);
    for (int l = 0; l < 5; l++) {
        ln_kernel<<<NROWS, 64, 0, stream>>>(xbuf, ln1_g + l * 512, ln1_b + l * 512, xn);
        gemm_kernel<0><<<dim3(1536 / TN, (NROWS + TM - 1) / TM), 256, 0, stream>>>(
            xn, qkv_w + (size_t)l * 512 * 1536, nullptr, nullptr, qkv, NROWS, 1536, 512);
        attn_kernel<<<dim3(SSEQ, NHEAD, BB), 256, 0, stream>>>(qkv, attno);
        gemm_kernel<3><<<dim3(512 / TN, (NROWS + TM - 1) / TM), 256, 0, stream>>>(
            attno, attn_out_w + (size_t)l * 512 * 512, attn_out_b + l * 512, xbuf, xbuf,
            NROWS, 512, 512);
        ln_kernel<<<NROWS, 64, 0, stream>>>(xbuf, ln2_g + l * 512, ln2_b + l * 512, xn);
        gemm_kernel<2><<<dim3(1024 / TN, (NROWS + TM - 1) / TM), 256, 0, stream>>>(
            xn, ff1_w + (size_t)l * 512 * 1024, ff1_b + l * 1024, nullptr, ffh,
            NROWS, 1024, 512);
        gemm_kernel<3><<<dim3(512 / TN, (NROWS + TM - 1) / TM), 256, 0, stream>>>(
            ffh, ff2_w + (size_t)l * 1024 * 512, ff2_b + l * 512, xbuf, xbuf,
            NROWS, 512, 1024);
    }
    pool_ln_kernel<<<BB, 512, 0, stream>>>(xbuf, head_ln_g, head_ln_b, pooled);
    head1_kernel<<<BB, 256, 0, stream>>>(pooled, head1_w, head1_b, h1);
    head2_kernel<<<BB, 256, 0, stream>>>(h1, head2_w, head2_b, h2);
    smax_anchor_kernel<<<BB * 17, 64, 0, stream>>>(h2, (float*)d_out);
}

// Round 2
// 4575.552 us; speedup vs baseline: 3.1842x; 3.1842x over previous
//
#include <hip/hip_runtime.h>
#include <hip/hip_bf16.h>
#include <cstddef>

// Problem constants
#define BB 8
#define LL 5
#define NN 4096
#define NANCH 64
#define NPTS 4160      // NN + NANCH
#define MM 260         // NPTS / 16
#define NFRAME 3
#define SSEQ 780       // NFRAME * MM
#define DIMC 512
#define NHEAD 8
#define DHEAD 64
#define MLPD 1024
#define OUTD 1088
#define NROWS 6240     // BB * SSEQ

// exact (non-contracted) squared distance, matching numpy fp32 op order
__device__ __forceinline__ float sqdist_rn(float x1, float y1, float z1,
                                           float x2, float y2, float z2) {
    float dx = __fsub_rn(x1, x2);
    float dy = __fsub_rn(y1, y2);
    float dz = __fsub_rn(z1, z2);
    return __fadd_rn(__fadd_rn(__fmul_rn(dx, dx), __fmul_rn(dy, dy)), __fmul_rn(dz, dz));
}

__device__ __forceinline__ float gelu_exact(float v) {
    return 0.5f * v * (1.0f + erff(v * 0.70710678118654752440f));
}

// ---------------------------------------------------------------------------
__global__ __launch_bounds__(256) void build_pts_kernel(const float* __restrict__ points,
                                                        float* __restrict__ pts) {
    int i = blockIdx.x * 256 + threadIdx.x;   // over B*L*NPTS = 166400
    if (i >= BB * LL * NPTS) return;
    int n = i % NPTS;
    int bl = i / NPTS;
    if (n < NN) {
        const float* src = points + ((size_t)bl * NN + n) * 3;
        pts[(size_t)i * 3 + 0] = src[0];
        pts[(size_t)i * 3 + 1] = src[1];
        pts[(size_t)i * 3 + 2] = src[2];
    } else {
        int j = n - NN;
        int ix = j >> 4, iy = (j >> 2) & 3, iz = j & 3;
        pts[(size_t)i * 3 + 0] = -1.5f + (float)ix;
        pts[(size_t)i * 3 + 1] = -1.5f + (float)iy;
        pts[(size_t)i * 3 + 2] = -1.5f + (float)iz;
    }
}

// ---------------------------------------------------------------------------
// Farthest point sampling: 1 block per (b, f). Sequential 260 iterations.
// ---------------------------------------------------------------------------
__global__ __launch_bounds__(256) void fps_kernel(const float* __restrict__ pts,
                                                  float* __restrict__ axyz) {
    int blk = blockIdx.x;           // 0..23
    int b = blk / 3, f = blk % 3;
    const float* P = pts + (size_t)(b * LL + 2 * f) * NPTS * 3;
    int tid = threadIdx.x;
    const int PPT = 17;             // ceil(4160/256)
    float px[PPT], py[PPT], pz[PPT], dist[PPT];
#pragma unroll
    for (int j = 0; j < PPT; j++) {
        int n = tid + 256 * j;
        if (n < NPTS) {
            px[j] = P[(size_t)n * 3 + 0];
            py[j] = P[(size_t)n * 3 + 1];
            pz[j] = P[(size_t)n * 3 + 2];
            dist[j] = 1e10f;
        } else {
            px[j] = 0.f; py[j] = 0.f; pz[j] = 0.f;
            dist[j] = -1.0f;   // never selected
        }
    }
    __shared__ float lx, ly, lz;
    __shared__ float redv[4];
    __shared__ int redi[4];
    if (tid == 0) { lx = px[0]; ly = py[0]; lz = pz[0]; }   // last = 0
    __syncthreads();
    float* out = axyz + (size_t)blk * MM * 3;
    for (int m = 0; m < MM; m++) {
        float ax = lx, ay = ly, az = lz;
        if (tid == 0) { out[m * 3 + 0] = ax; out[m * 3 + 1] = ay; out[m * 3 + 2] = az; }
        float bestv = -1.0f;
        int bestn = NPTS;
#pragma unroll
        for (int j = 0; j < PPT; j++) {
            int n = tid + 256 * j;
            if (n < NPTS) {
                float d = sqdist_rn(px[j], py[j], pz[j], ax, ay, az);
                float dj = fminf(dist[j], d);
                dist[j] = dj;
                if (dj > bestv) { bestv = dj; bestn = n; }
            }
        }
#pragma unroll
        for (int off = 32; off; off >>= 1) {
            float ov = __shfl_xor(bestv, off);
            int on = __shfl_xor(bestn, off);
            if (ov > bestv || (ov == bestv && on < bestn)) { bestv = ov; bestn = on; }
        }
        if ((tid & 63) == 0) { redv[tid >> 6] = bestv; redi[tid >> 6] = bestn; }
        __syncthreads();
        if (tid == 0) {
            float bv = redv[0]; int bn = redi[0];
#pragma unroll
            for (int w = 1; w < 4; w++) {
                if (redv[w] > bv || (redv[w] == bv && redi[w] < bn)) { bv = redv[w]; bn = redi[w]; }
            }
            lx = P[(size_t)bn * 3 + 0];
            ly = P[(size_t)bn * 3 + 1];
            lz = P[(size_t)bn * 3 + 2];
        }
        __syncthreads();
    }
}

// ---------------------------------------------------------------------------
// Ball query + grouped conv + max over k + max over window + pos embedding.
// ---------------------------------------------------------------------------
__global__ __launch_bounds__(64) void group_conv_kernel(
    const float* __restrict__ pts, const float* __restrict__ axyz,
    const float* __restrict__ conv_d_w, const float* __restrict__ conv_f_w,
    const float* __restrict__ pos_w, const float* __restrict__ pos_b,
    float* __restrict__ x) {
    int gid = blockIdx.x;                 // b*780 + f*260 + m
    int b = gid / SSEQ;
    int rem = gid % SSEQ;
    int f = rem / MM;
    int lane = threadIdx.x;
    const float* A = axyz + (size_t)gid * 3;
    float ax = A[0], ay = A[1], az = A[2];

    float cf0[8], cf1[8], cf2[8], cd0[8], cd1[8], cd2[8], cd3[8], fmx[8];
#pragma unroll
    for (int c = 0; c < 8; c++) {
        int d = lane + 64 * c;
        cf0[c] = conv_f_w[d * 3 + 0];
        cf1[c] = conv_f_w[d * 3 + 1];
        cf2[c] = conv_f_w[d * 3 + 2];
        cd0[c] = conv_d_w[d * 4 + 0];
        cd1[c] = conv_d_w[d * 4 + 1];
        cd2[c] = conv_d_w[d * 4 + 2];
        cd3[c] = conv_d_w[d * 4 + 3];
        fmx[c] = -INFINITY;
    }
    __shared__ int nbr[32];
    __shared__ float gxs[32], gys[32], gzs[32];
    const float R2 = 0.49000000953674316f;

    for (int wi = 0; wi < 3; wi++) {
        int l = 2 * f + wi - 1;
        l = l < 0 ? 0 : (l > 4 ? 4 : l);
        const float* P = pts + (size_t)(b * LL + l) * NPTS * 3;
        int cnt = 0;
        for (int base = 0; base < NPTS && cnt < 32; base += 64) {
            int n = base + lane;
            float d2 = sqdist_rn(P[(size_t)n * 3], P[(size_t)n * 3 + 1], P[(size_t)n * 3 + 2],
                                 ax, ay, az);
            bool hit = d2 < R2;
            unsigned long long mk = __ballot(hit);
            int rank = (int)__popcll(mk & (((unsigned long long)1 << lane) - 1ull));
            if (hit && (cnt + rank) < 32) nbr[cnt + rank] = n;
            cnt += (int)__popcll(mk);
        }
        __syncthreads();
        int eff = cnt < 32 ? cnt : 32;
        if (lane < 32) {
            int idx = (eff == 0) ? 0 : (lane < eff ? nbr[lane] : nbr[0]);
            gxs[lane] = P[(size_t)idx * 3 + 0];
            gys[lane] = P[(size_t)idx * 3 + 1];
            gzs[lane] = P[(size_t)idx * 3 + 2];
        }
        __syncthreads();
        float tf = (float)(wi - 1);
        for (int k = 0; k < 32; k++) {
            float gx = gxs[k], gy = gys[k], gz = gzs[k];
            float dx = gx - ax, dy = gy - ay, dz = gz - az;
#pragma unroll
            for (int c = 0; c < 8; c++) {
                float v = gx * cf0[c] + gy * cf1[c] + gz * cf2[c] +
                          dx * cd0[c] + dy * cd1[c] + dz * cd2[c] + tf * cd3[c];
                fmx[c] = fmaxf(fmx[c], v);
            }
        }
        __syncthreads();
    }
    float tcol = (float)(f + 1);
#pragma unroll
    for (int c = 0; c < 8; c++) {
        int d = lane + 64 * c;
        float pos = ax * pos_w[d * 4 + 0] + ay * pos_w[d * 4 + 1] +
                    az * pos_w[d * 4 + 2] + tcol * pos_w[d * 4 + 3] + pos_b[d];
        x[(size_t)gid * DIMC + d] = fmx[c] + pos;
    }
}

// ---------------------------------------------------------------------------
// LayerNorm over last dim 512. 1 wave per row.
// ---------------------------------------------------------------------------
__global__ __launch_bounds__(64) void ln_kernel(const float* __restrict__ x,
                                                const float* __restrict__ g,
                                                const float* __restrict__ b,
                                                float* __restrict__ y) {
    int r = blockIdx.x;
    int lane = threadIdx.x;
    const float* xr = x + (size_t)r * DIMC;
    float4 v0 = *(const float4*)(xr + lane * 8);
    float4 v1 = *(const float4*)(xr + lane * 8 + 4);
    float s = v0.x + v0.y + v0.z + v0.w + v1.x + v1.y + v1.z + v1.w;
#pragma unroll
    for (int off = 32; off; off >>= 1) s += __shfl_xor(s, off);
    float mean = s * (1.0f / 512.0f);
    float d0 = v0.x - mean, d1 = v0.y - mean, d2 = v0.z - mean, d3 = v0.w - mean;
    float d4 = v1.x - mean, d5 = v1.y - mean, d6 = v1.z - mean, d7 = v1.w - mean;
    float sq = d0 * d0 + d1 * d1 + d2 * d2 + d3 * d3 + d4 * d4 + d5 * d5 + d6 * d6 + d7 * d7;
#pragma unroll
    for (int off = 32; off; off >>= 1) sq += __shfl_xor(sq, off);
    float var = sq * (1.0f / 512.0f);
    float inv = 1.0f / sqrtf(var + 1e-5f);
    float* yr = y + (size_t)r * DIMC;
    int d = lane * 8;
    yr[d + 0] = d0 * inv * g[d + 0] + b[d + 0];
    yr[d + 1] = d1 * inv * g[d + 1] + b[d + 1];
    yr[d + 2] = d2 * inv * g[d + 2] + b[d + 2];
    yr[d + 3] = d3 * inv * g[d + 3] + b[d + 3];
    yr[d + 4] = d4 * inv * g[d + 4] + b[d + 4];
    yr[d + 5] = d5 * inv * g[d + 5] + b[d + 5];
    yr[d + 6] = d6 * inv * g[d + 6] + b[d + 6];
    yr[d + 7] = d7 * inv * g[d + 7] + b[d + 7];
}

// ---------------------------------------------------------------------------
// Generic fp32 GEMM (unchanged this round)
// ---------------------------------------------------------------------------
#define TM 64
#define TN 64
#define TK 16
#define LPAD 68

template <int EPI>
__global__ __launch_bounds__(256) void gemm_kernel(const float* __restrict__ A,
                                                   const float* __restrict__ W,
                                                   const float* __restrict__ bias,
                                                   const float* R, float* C,
                                                   int M, int N, int K) {
    __shared__ float As[TK][LPAD];
    __shared__ float Bs[TK][LPAD];
    int tid = threadIdx.x;
    int n0 = blockIdx.x * TN;
    int m0 = blockIdx.y * TM;
    int tx = tid & 15, ty = tid >> 4;
    int la_m = tid >> 2;
    int la_k = (tid & 3) * 4;
    int lb_k = tid >> 4;
    int lb_n = (tid & 15) * 4;
    float acc[4][4] = {};
    for (int k0 = 0; k0 < K; k0 += TK) {
        float4 av = make_float4(0.f, 0.f, 0.f, 0.f);
        if (m0 + la_m < M) av = *(const float4*)(A + (size_t)(m0 + la_m) * K + k0 + la_k);
        As[la_k + 0][la_m] = av.x;
        As[la_k + 1][la_m] = av.y;
        As[la_k + 2][la_m] = av.z;
        As[la_k + 3][la_m] = av.w;
        float4 bv = *(const float4*)(W + (size_t)(k0 + lb_k) * N + n0 + lb_n);
        *(float4*)&Bs[lb_k][lb_n] = bv;
        __syncthreads();
#pragma unroll
        for (int kk = 0; kk < TK; kk++) {
            float4 a4 = *(const float4*)&As[kk][ty * 4];
            float4 b4 = *(const float4*)&Bs[kk][tx * 4];
            acc[0][0] += a4.x * b4.x; acc[0][1] += a4.x * b4.y;
            acc[0][2] += a4.x * b4.z; acc[0][3] += a4.x * b4.w;
            acc[1][0] += a4.y * b4.x; acc[1][1] += a4.y * b4.y;
            acc[1][2] += a4.y * b4.z; acc[1][3] += a4.y * b4.w;
            acc[2][0] += a4.z * b4.x; acc[2][1] += a4.z * b4.y;
            acc[2][2] += a4.z * b4.z; acc[2][3] += a4.z * b4.w;
            acc[3][0] += a4.w * b4.x; acc[3][1] += a4.w * b4.y;
            acc[3][2] += a4.w * b4.z; acc[3][3] += a4.w * b4.w;
        }
        __syncthreads();
    }
#pragma unroll
    for (int i = 0; i < 4; i++) {
        int row = m0 + ty * 4 + i;
        if (row < M) {
#pragma unroll
            for (int j = 0; j < 4; j++) {
                int col = n0 + tx * 4 + j;
                float v = acc[i][j];
                if (EPI >= 2) v += bias[col];
                if (EPI == 2) v = gelu_exact(v);
                if (EPI == 3) v += R[(size_t)row * N + col];
                C[(size_t)row * N + col] = v;
            }
        }
    }
}

// ---------------------------------------------------------------------------
// Flash attention: 1 block (256 thr) per (q-tile of 64, head, batch).
// Grid (13, 8, 8). Q/K/V tiles staged in LDS, online softmax, O in regs.
// qkv layout (B*S, 1536): q @ +0, k @ +512, v @ +1024; head h at +h*64.
// Thread (tx=tid&15, ty=tid>>4):
//   S phase: owns S[4ty+i][tx+16j]  (i,j in 0..3)
//   PV phase: owns O[4ty+i][4tx+j]
// ---------------------------------------------------------------------------
#define APAD 68   // row pitch (floats) for 64-wide tiles; 17 float4 -> odd, spreads banks

__global__ __launch_bounds__(256) void attn_flash_kernel(const float* __restrict__ qkv,
                                                         float* __restrict__ o) {
    int qt = blockIdx.x, h = blockIdx.y, b = blockIdx.z;
    int tid = threadIdx.x;
    int tx = tid & 15, ty = tid >> 4;

    __shared__ __align__(16) float Qs[64][APAD];
    __shared__ __align__(16) float Ks[64][APAD];
    __shared__ __align__(16) float Vs[64][APAD];
    __shared__ __align__(16) float Pt[64][APAD];   // P transposed: Pt[k][q]
    __shared__ float pred[64][17];                 // per-row partial max/sum
    __shared__ float m_run[64], l_run[64], alpha_s[64];

    int q0 = qt * 64;
    int nq = SSEQ - q0; if (nq > 64) nq = 64;

    // load Q tile (rows clamped to valid)
    {
        int r = tid >> 4;          // 0..15
        int c4 = (tid & 15) * 4;
#pragma unroll
        for (int it = 0; it < 4; it++) {
            int row = r + it * 16;
            int gq = q0 + (row < nq ? row : nq - 1);
            const float* src = qkv + ((size_t)(b * SSEQ + gq) * 1536) + h * 64 + c4;
            *(float4*)&Qs[row][c4] = *(const float4*)src;
        }
    }
    if (tid < 64) { m_run[tid] = -INFINITY; l_run[tid] = 0.f; }

    float O[4][4] = {};

    for (int kt = 0; kt < 13; kt++) {
        int k0 = kt * 64;
        int nk = SSEQ - k0; if (nk > 64) nk = 64;
        __syncthreads();   // previous PV done before overwriting Ks/Vs
        // load K and V tiles (rows clamped)
        {
            int r = tid >> 4;
            int c4 = (tid & 15) * 4;
#pragma unroll
            for (int it = 0; it < 4; it++) {
                int row = r + it * 16;
                int gk = k0 + (row < nk ? row : nk - 1);
                const float* base = qkv + ((size_t)(b * SSEQ + gk) * 1536) + h * 64 + c4;
                *(float4*)&Ks[row][c4] = *(const float4*)(base + 512);
                *(float4*)&Vs[row][c4] = *(const float4*)(base + 1024);
            }
        }
        __syncthreads();

        // S = Q @ K^T * scale ; thread owns S[4ty+i][tx+16j]
        float s[4][4] = {};
#pragma unroll
        for (int d4 = 0; d4 < 64; d4 += 4) {
            float4 qv[4], kv[4];
#pragma unroll
            for (int i = 0; i < 4; i++) qv[i] = *(const float4*)&Qs[4 * ty + i][d4];
#pragma unroll
            for (int j = 0; j < 4; j++) kv[j] = *(const float4*)&Ks[tx + 16 * j][d4];
#pragma unroll
            for (int i = 0; i < 4; i++)
#pragma unroll
                for (int j = 0; j < 4; j++)
                    s[i][j] += qv[i].x * kv[j].x + qv[i].y * kv[j].y +
                               qv[i].z * kv[j].z + qv[i].w * kv[j].w;
        }
        // scale + mask invalid keys
#pragma unroll
        for (int i = 0; i < 4; i++)
#pragma unroll
            for (int j = 0; j < 4; j++) {
                s[i][j] *= 0.125f;
                if (tx + 16 * j >= nk) s[i][j] = -INFINITY;
            }
        // per-thread row max -> LDS
#pragma unroll
        for (int i = 0; i < 4; i++) {
            float lm = fmaxf(fmaxf(s[i][0], s[i][1]), fmaxf(s[i][2], s[i][3]));
            pred[4 * ty + i][tx] = lm;
        }
        __syncthreads();
        if (tid < 64) {
            float tm = -INFINITY;
#pragma unroll
            for (int c = 0; c < 16; c++) tm = fmaxf(tm, pred[tid][c]);
            float mo = m_run[tid];
            float mn = fmaxf(mo, tm);
            m_run[tid] = mn;
            alpha_s[tid] = __expf(mo - mn);
        }
        __syncthreads();
        // exp, rescale O, write Pt, partial sums
#pragma unroll
        for (int i = 0; i < 4; i++) {
            int q = 4 * ty + i;
            float mn = m_run[q];
            float al = alpha_s[q];
            float ls = 0.f;
#pragma unroll
            for (int j = 0; j < 4; j++) {
                float p = __expf(s[i][j] - mn);
                Pt[tx + 16 * j][q] = p;
                ls += p;
            }
            pred[q][tx] = ls;
#pragma unroll
            for (int j = 0; j < 4; j++) O[i][j] *= al;
        }
        __syncthreads();
        if (tid < 64) {
            float ts = 0.f;
#pragma unroll
            for (int c = 0; c < 16; c++) ts += pred[tid][c];
            l_run[tid] = l_run[tid] * alpha_s[tid] + ts;
        }
        // PV: O[4ty+i][4tx+j] += Pt[k][4ty+i] * Vs[k][4tx+j]
#pragma unroll 4
        for (int k = 0; k < 64; k++) {
            float4 pv = *(const float4*)&Pt[k][4 * ty];
            float4 vv = *(const float4*)&Vs[k][4 * tx];
            O[0][0] += pv.x * vv.x; O[0][1] += pv.x * vv.y; O[0][2] += pv.x * vv.z; O[0][3] += pv.x * vv.w;
            O[1][0] += pv.y * vv.x; O[1][1] += pv.y * vv.y; O[1][2] += pv.y * vv.z; O[1][3] += pv.y * vv.w;
            O[2][0] += pv.z * vv.x; O[2][1] += pv.z * vv.y; O[2][2] += pv.z * vv.z; O[2][3] += pv.z * vv.w;
            O[3][0] += pv.w * vv.x; O[3][1] += pv.w * vv.y; O[3][2] += pv.w * vv.z; O[3][3] += pv.w * vv.w;
        }
    }
    __syncthreads();
#pragma unroll
    for (int i = 0; i < 4; i++) {
        int q = 4 * ty + i;
        if (q < nq) {
            float inv = 1.0f / l_run[q];
            float4 r;
            r.x = O[i][0] * inv; r.y = O[i][1] * inv;
            r.z = O[i][2] * inv; r.w = O[i][3] * inv;
            float* dst = o + ((size_t)(b * SSEQ + q0 + q)) * DIMC + h * 64 + 4 * tx;
            *(float4*)dst = r;
        }
    }
}

// ---------------------------------------------------------------------------
// Final head
// ---------------------------------------------------------------------------
__global__ __launch_bounds__(512) void pool_ln_kernel(const float* __restrict__ x,
                                                      const float* __restrict__ g,
                                                      const float* __restrict__ b,
                                                      float* __restrict__ out) {
    int bb = blockIdx.x;
    int d = threadIdx.x;
    const float* xb = x + (size_t)bb * SSEQ * DIMC + d;
    float m = -INFINITY;
    for (int s = 0; s < SSEQ; s++) m = fmaxf(m, xb[(size_t)s * DIMC]);
    __shared__ float col[512];
    __shared__ float red[512];
    col[d] = m;
    red[d] = m;
    __syncthreads();
    for (int s = 256; s > 0; s >>= 1) {
        if (d < s) red[d] += red[d + s];
        __syncthreads();
    }
    float mean = red[0] * (1.0f / 512.0f);
    __syncthreads();
    float dv = col[d] - mean;
    red[d] = dv * dv;
    __syncthreads();
    for (int s = 256; s > 0; s >>= 1) {
        if (d < s) red[d] += red[d + s];
        __syncthreads();
    }
    float var = red[0] * (1.0f / 512.0f);
    float inv = 1.0f / sqrtf(var + 1e-5f);
    out[(size_t)bb * DIMC + d] = dv * inv * g[d] + b[d];
}

__global__ __launch_bounds__(256) void head1_kernel(const float* __restrict__ in,
                                                    const float* __restrict__ W,
                                                    const float* __restrict__ bias,
                                                    float* __restrict__ out) {
    int bb = blockIdx.x;
    int tid = threadIdx.x;
    __shared__ float xr[512];
    xr[tid] = in[(size_t)bb * 512 + tid];
    xr[tid + 256] = in[(size_t)bb * 512 + tid + 256];
    __syncthreads();
    float acc[4] = {0.f, 0.f, 0.f, 0.f};
    for (int k = 0; k < 512; k++) {
        float xv = xr[k];
#pragma unroll
        for (int i = 0; i < 4; i++) acc[i] += xv * W[(size_t)k * 1024 + tid + 256 * i];
    }
#pragma unroll
    for (int i = 0; i < 4; i++) {
        int n = tid + 256 * i;
        out[(size_t)bb * 1024 + n] = gelu_exact(acc[i] + bias[n]);
    }
}

__global__ __launch_bounds__(256) void head2_kernel(const float* __restrict__ in,
                                                    const float* __restrict__ W,
                                                    const float* __restrict__ bias,
                                                    float* __restrict__ out) {
    int bb = blockIdx.x;
    int tid = threadIdx.x;
    __shared__ float xr[1024];
    xr[tid] = in[(size_t)bb * 1024 + tid];
    xr[tid + 256] = in[(size_t)bb * 1024 + tid + 256];
    xr[tid + 512] = in[(size_t)bb * 1024 + tid + 512];
    xr[tid + 768] = in[(size_t)bb * 1024 + tid + 768];
    __syncthreads();
    float acc[5] = {0.f, 0.f, 0.f, 0.f, 0.f};
    for (int k = 0; k < 1024; k++) {
        float xv = xr[k];
#pragma unroll
        for (int i = 0; i < 4; i++) acc[i] += xv * W[(size_t)k * OUTD + tid + 256 * i];
        if (tid < 64) acc[4] += xv * W[(size_t)k * OUTD + 1024 + tid];
    }
#pragma unroll
    for (int i = 0; i < 4; i++) {
        int n = tid + 256 * i;
        out[(size_t)bb * OUTD + n] = acc[i] + bias[n];
    }
    if (tid < 64) out[(size_t)bb * OUTD + 1024 + tid] = acc[4] + bias[1024 + tid];
}

__global__ __launch_bounds__(64) void smax_anchor_kernel(const float* __restrict__ h2,
                                                         float* __restrict__ out) {
    int bb = blockIdx.x / 17;
    int gcol = blockIdx.x % 17;
    int j = threadIdx.x;
    float v = h2[(size_t)bb * OUTD + gcol * 64 + j];
    float mx = v;
#pragma unroll
    for (int off = 32; off; off >>= 1) mx = fmaxf(mx, __shfl_xor(mx, off));
    float p = expf(v - mx);
    float sum = p;
#pragma unroll
    for (int off = 32; off; off >>= 1) sum += __shfl_xor(sum, off);
    int ix = j >> 4, iy = (j >> 2) & 3, iz = j & 3;
    float sx = p * (-1.5f + (float)ix);
    float sy = p * (-1.5f + (float)iy);
    float sz = p * (-1.5f + (float)iz);
#pragma unroll
    for (int off = 32; off; off >>= 1) {
        sx += __shfl_xor(sx, off);
        sy += __shfl_xor(sy, off);
        sz += __shfl_xor(sz, off);
    }
    if (j == 0) {
        float* o = out + ((size_t)bb * 17 + gcol) * 3;
        o[0] = sx / sum;
        o[1] = sy / sum;
        o[2] = sz / sum;
    }
}

// ---------------------------------------------------------------------------
extern "C" void kernel_launch(void* const* d_in, const int* in_sizes, int n_in,
                              void* d_out, int out_size, void* d_ws, size_t ws_size,
                              hipStream_t stream) {
    const float* points     = (const float*)d_in[0];
    const float* conv_d_w   = (const float*)d_in[1];
    const float* conv_f_w   = (const float*)d_in[2];
    const float* pos_w      = (const float*)d_in[3];
    const float* pos_b      = (const float*)d_in[4];
    const float* ln1_g      = (const float*)d_in[5];
    const float* ln1_b      = (const float*)d_in[6];
    const float* qkv_w      = (const float*)d_in[7];
    const float* attn_out_w = (const float*)d_in[8];
    const float* attn_out_b = (const float*)d_in[9];
    const float* ln2_g      = (const float*)d_in[10];
    const float* ln2_b      = (const float*)d_in[11];
    const float* ff1_w      = (const float*)d_in[12];
    const float* ff1_b      = (const float*)d_in[13];
    const float* ff2_w      = (const float*)d_in[14];
    const float* ff2_b      = (const float*)d_in[15];
    const float* head_ln_g  = (const float*)d_in[16];
    const float* head_ln_b  = (const float*)d_in[17];
    const float* head1_w    = (const float*)d_in[18];
    const float* head1_b    = (const float*)d_in[19];
    const float* head2_w    = (const float*)d_in[20];
    const float* head2_b    = (const float*)d_in[21];

    float* ws = (float*)d_ws;
    float* pts    = ws;                    // 499200
    float* axyz   = pts + 499200;          // 18720
    float* xbuf   = axyz + 18720;          // 3194880
    float* xn     = xbuf + 3194880;        // 3194880
    float* qkv    = xn + 3194880;          // 9584640 (reused as ffh)
    float* attno  = qkv + 9584640;         // 3194880
    float* pooled = attno + 3194880;       // 4096
    float* h1     = pooled + 4096;         // 8192
    float* h2     = h1 + 8192;             // 8704
    float* ffh    = qkv;                   // alias: qkv dead after attention

    build_pts_kernel<<<650, 256, 0, stream>>>(points, pts);
    fps_kernel<<<24, 256, 0, stream>>>(pts, axyz);
    group_conv_kernel<<<NROWS, 64, 0, stream>>>(pts, axyz, conv_d_w, conv_f_w,
                                                pos_w, pos_b, xbuf);
    for (int l = 0; l < 5; l++) {
        ln_kernel<<<NROWS, 64, 0, stream>>>(xbuf, ln1_g + l * 512, ln1_b + l * 512, xn);
        gemm_kernel<0><<<dim3(1536 / TN, (NROWS + TM - 1) / TM), 256, 0, stream>>>(
            xn, qkv_w + (size_t)l * 512 * 1536, nullptr, nullptr, qkv, NROWS, 1536, 512);
        attn_flash_kernel<<<dim3(13, NHEAD, BB), 256, 0, stream>>>(qkv, attno);
        gemm_kernel<3><<<dim3(512 / TN, (NROWS + TM - 1) / TM), 256, 0, stream>>>(
            attno, attn_out_w + (size_t)l * 512 * 512, attn_out_b + l * 512, xbuf, xbuf,
            NROWS, 512, 512);
        ln_kernel<<<NROWS, 64, 0, stream>>>(xbuf, ln2_g + l * 512, ln2_b + l * 512, xn);
        gemm_kernel<2><<<dim3(1024 / TN, (NROWS + TM - 1) / TM), 256, 0, stream>>>(
            xn, ff1_w + (size_t)l * 512 * 1024, ff1_b + l * 1024, nullptr, ffh,
            NROWS, 1024, 512);
        gemm_kernel<3><<<dim3(512 / TN, (NROWS + TM - 1) / TM), 256, 0, stream>>>(
            ffh, ff2_w + (size_t)l * 1024 * 512, ff2_b + l * 512, xbuf, xbuf,
            NROWS, 512, 1024);
    }
    pool_ln_kernel<<<BB, 512, 0, stream>>>(xbuf, head_ln_g, head_ln_b, pooled);
    head1_kernel<<<BB, 256, 0, stream>>>(pooled, head1_w, head1_b, h1);
    head2_kernel<<<BB, 256, 0, stream>>>(h1, head2_w, head2_b, h2);
    smax_anchor_kernel<<<BB * 17, 64, 0, stream>>>(h2, (float*)d_out);
}

// Round 3
// 4149.736 us; speedup vs baseline: 3.5110x; 1.1026x over previous
//
#include <hip/hip_runtime.h>
#include <hip/hip_bf16.h>
#include <cstddef>

// Problem constants
#define BB 8
#define LL 5
#define NN 4096
#define NANCH 64
#define NPTS 4160      // NN + NANCH
#define MM 260         // NPTS / 16
#define NFRAME 3
#define SSEQ 780       // NFRAME * MM
#define DIMC 512
#define NHEAD 8
#define DHEAD 64
#define MLPD 1024
#define OUTD 1088
#define NROWS 6240     // BB * SSEQ

// exact (non-contracted) squared distance, matching numpy fp32 op order
__device__ __forceinline__ float sqdist_rn(float x1, float y1, float z1,
                                           float x2, float y2, float z2) {
    float dx = __fsub_rn(x1, x2);
    float dy = __fsub_rn(y1, y2);
    float dz = __fsub_rn(z1, z2);
    return __fadd_rn(__fadd_rn(__fmul_rn(dx, dx), __fmul_rn(dy, dy)), __fmul_rn(dz, dz));
}

__device__ __forceinline__ float gelu_exact(float v) {
    return 0.5f * v * (1.0f + erff(v * 0.70710678118654752440f));
}

// ---------------------------------------------------------------------------
__global__ __launch_bounds__(256) void build_pts_kernel(const float* __restrict__ points,
                                                        float* __restrict__ pts) {
    int i = blockIdx.x * 256 + threadIdx.x;   // over B*L*NPTS = 166400
    if (i >= BB * LL * NPTS) return;
    int n = i % NPTS;
    int bl = i / NPTS;
    if (n < NN) {
        const float* src = points + ((size_t)bl * NN + n) * 3;
        pts[(size_t)i * 3 + 0] = src[0];
        pts[(size_t)i * 3 + 1] = src[1];
        pts[(size_t)i * 3 + 2] = src[2];
    } else {
        int j = n - NN;
        int ix = j >> 4, iy = (j >> 2) & 3, iz = j & 3;
        pts[(size_t)i * 3 + 0] = -1.5f + (float)ix;
        pts[(size_t)i * 3 + 1] = -1.5f + (float)iy;
        pts[(size_t)i * 3 + 2] = -1.5f + (float)iz;
    }
}

// ---------------------------------------------------------------------------
// Farthest point sampling: 1 block per (b, f). Sequential 260 iterations.
// ---------------------------------------------------------------------------
__global__ __launch_bounds__(256) void fps_kernel(const float* __restrict__ pts,
                                                  float* __restrict__ axyz) {
    int blk = blockIdx.x;           // 0..23
    int b = blk / 3, f = blk % 3;
    const float* P = pts + (size_t)(b * LL + 2 * f) * NPTS * 3;
    int tid = threadIdx.x;
    const int PPT = 17;             // ceil(4160/256)
    float px[PPT], py[PPT], pz[PPT], dist[PPT];
#pragma unroll
    for (int j = 0; j < PPT; j++) {
        int n = tid + 256 * j;
        if (n < NPTS) {
            px[j] = P[(size_t)n * 3 + 0];
            py[j] = P[(size_t)n * 3 + 1];
            pz[j] = P[(size_t)n * 3 + 2];
            dist[j] = 1e10f;
        } else {
            px[j] = 0.f; py[j] = 0.f; pz[j] = 0.f;
            dist[j] = -1.0f;   // never selected
        }
    }
    __shared__ float lx, ly, lz;
    __shared__ float redv[4];
    __shared__ int redi[4];
    if (tid == 0) { lx = px[0]; ly = py[0]; lz = pz[0]; }   // last = 0
    __syncthreads();
    float* out = axyz + (size_t)blk * MM * 3;
    for (int m = 0; m < MM; m++) {
        float ax = lx, ay = ly, az = lz;
        if (tid == 0) { out[m * 3 + 0] = ax; out[m * 3 + 1] = ay; out[m * 3 + 2] = az; }
        float bestv = -1.0f;
        int bestn = NPTS;
#pragma unroll
        for (int j = 0; j < PPT; j++) {
            int n = tid + 256 * j;
            if (n < NPTS) {
                float d = sqdist_rn(px[j], py[j], pz[j], ax, ay, az);
                float dj = fminf(dist[j], d);
                dist[j] = dj;
                if (dj > bestv) { bestv = dj; bestn = n; }
            }
        }
#pragma unroll
        for (int off = 32; off; off >>= 1) {
            float ov = __shfl_xor(bestv, off);
            int on = __shfl_xor(bestn, off);
            if (ov > bestv || (ov == bestv && on < bestn)) { bestv = ov; bestn = on; }
        }
        if ((tid & 63) == 0) { redv[tid >> 6] = bestv; redi[tid >> 6] = bestn; }
        __syncthreads();
        if (tid == 0) {
            float bv = redv[0]; int bn = redi[0];
#pragma unroll
            for (int w = 1; w < 4; w++) {
                if (redv[w] > bv || (redv[w] == bv && redi[w] < bn)) { bv = redv[w]; bn = redi[w]; }
            }
            lx = P[(size_t)bn * 3 + 0];
            ly = P[(size_t)bn * 3 + 1];
            lz = P[(size_t)bn * 3 + 2];
        }
        __syncthreads();
    }
}

// ---------------------------------------------------------------------------
// Ball query + grouped conv + max over k + max over window + pos embedding.
// ---------------------------------------------------------------------------
__global__ __launch_bounds__(64) void group_conv_kernel(
    const float* __restrict__ pts, const float* __restrict__ axyz,
    const float* __restrict__ conv_d_w, const float* __restrict__ conv_f_w,
    const float* __restrict__ pos_w, const float* __restrict__ pos_b,
    float* __restrict__ x) {
    int gid = blockIdx.x;                 // b*780 + f*260 + m
    int b = gid / SSEQ;
    int rem = gid % SSEQ;
    int f = rem / MM;
    int lane = threadIdx.x;
    const float* A = axyz + (size_t)gid * 3;
    float ax = A[0], ay = A[1], az = A[2];

    float cf0[8], cf1[8], cf2[8], cd0[8], cd1[8], cd2[8], cd3[8], fmx[8];
#pragma unroll
    for (int c = 0; c < 8; c++) {
        int d = lane + 64 * c;
        cf0[c] = conv_f_w[d * 3 + 0];
        cf1[c] = conv_f_w[d * 3 + 1];
        cf2[c] = conv_f_w[d * 3 + 2];
        cd0[c] = conv_d_w[d * 4 + 0];
        cd1[c] = conv_d_w[d * 4 + 1];
        cd2[c] = conv_d_w[d * 4 + 2];
        cd3[c] = conv_d_w[d * 4 + 3];
        fmx[c] = -INFINITY;
    }
    __shared__ int nbr[32];
    __shared__ float gxs[32], gys[32], gzs[32];
    const float R2 = 0.49000000953674316f;

    for (int wi = 0; wi < 3; wi++) {
        int l = 2 * f + wi - 1;
        l = l < 0 ? 0 : (l > 4 ? 4 : l);
        const float* P = pts + (size_t)(b * LL + l) * NPTS * 3;
        int cnt = 0;
        for (int base = 0; base < NPTS && cnt < 32; base += 64) {
            int n = base + lane;
            float d2 = sqdist_rn(P[(size_t)n * 3], P[(size_t)n * 3 + 1], P[(size_t)n * 3 + 2],
                                 ax, ay, az);
            bool hit = d2 < R2;
            unsigned long long mk = __ballot(hit);
            int rank = (int)__popcll(mk & (((unsigned long long)1 << lane) - 1ull));
            if (hit && (cnt + rank) < 32) nbr[cnt + rank] = n;
            cnt += (int)__popcll(mk);
        }
        __syncthreads();
        int eff = cnt < 32 ? cnt : 32;
        if (lane < 32) {
            int idx = (eff == 0) ? 0 : (lane < eff ? nbr[lane] : nbr[0]);
            gxs[lane] = P[(size_t)idx * 3 + 0];
            gys[lane] = P[(size_t)idx * 3 + 1];
            gzs[lane] = P[(size_t)idx * 3 + 2];
        }
        __syncthreads();
        float tf = (float)(wi - 1);
        for (int k = 0; k < 32; k++) {
            float gx = gxs[k], gy = gys[k], gz = gzs[k];
            float dx = gx - ax, dy = gy - ay, dz = gz - az;
#pragma unroll
            for (int c = 0; c < 8; c++) {
                float v = gx * cf0[c] + gy * cf1[c] + gz * cf2[c] +
                          dx * cd0[c] + dy * cd1[c] + dz * cd2[c] + tf * cd3[c];
                fmx[c] = fmaxf(fmx[c], v);
            }
        }
        __syncthreads();
    }
    float tcol = (float)(f + 1);
#pragma unroll
    for (int c = 0; c < 8; c++) {
        int d = lane + 64 * c;
        float pos = ax * pos_w[d * 4 + 0] + ay * pos_w[d * 4 + 1] +
                    az * pos_w[d * 4 + 2] + tcol * pos_w[d * 4 + 3] + pos_b[d];
        x[(size_t)gid * DIMC + d] = fmx[c] + pos;
    }
}

// ---------------------------------------------------------------------------
// LayerNorm over last dim 512. 1 wave per row.
// ---------------------------------------------------------------------------
__global__ __launch_bounds__(64) void ln_kernel(const float* __restrict__ x,
                                                const float* __restrict__ g,
                                                const float* __restrict__ b,
                                                float* __restrict__ y) {
    int r = blockIdx.x;
    int lane = threadIdx.x;
    const float* xr = x + (size_t)r * DIMC;
    float4 v0 = *(const float4*)(xr + lane * 8);
    float4 v1 = *(const float4*)(xr + lane * 8 + 4);
    float s = v0.x + v0.y + v0.z + v0.w + v1.x + v1.y + v1.z + v1.w;
#pragma unroll
    for (int off = 32; off; off >>= 1) s += __shfl_xor(s, off);
    float mean = s * (1.0f / 512.0f);
    float d0 = v0.x - mean, d1 = v0.y - mean, d2 = v0.z - mean, d3 = v0.w - mean;
    float d4 = v1.x - mean, d5 = v1.y - mean, d6 = v1.z - mean, d7 = v1.w - mean;
    float sq = d0 * d0 + d1 * d1 + d2 * d2 + d3 * d3 + d4 * d4 + d5 * d5 + d6 * d6 + d7 * d7;
#pragma unroll
    for (int off = 32; off; off >>= 1) sq += __shfl_xor(sq, off);
    float var = sq * (1.0f / 512.0f);
    float inv = 1.0f / sqrtf(var + 1e-5f);
    float* yr = y + (size_t)r * DIMC;
    int d = lane * 8;
    yr[d + 0] = d0 * inv * g[d + 0] + b[d + 0];
    yr[d + 1] = d1 * inv * g[d + 1] + b[d + 1];
    yr[d + 2] = d2 * inv * g[d + 2] + b[d + 2];
    yr[d + 3] = d3 * inv * g[d + 3] + b[d + 3];
    yr[d + 4] = d4 * inv * g[d + 4] + b[d + 4];
    yr[d + 5] = d5 * inv * g[d + 5] + b[d + 5];
    yr[d + 6] = d6 * inv * g[d + 6] + b[d + 6];
    yr[d + 7] = d7 * inv * g[d + 7] + b[d + 7];
}

// ---------------------------------------------------------------------------
// Big-tile fp32 GEMM: C(M,N) = A(M,K) @ W(K,N), row-major.
// TM=128 rows, TNV columns per block; 256 threads as 16x16; each thread
// computes 8 rows x RN cols (RN = TNV/16). 64 (or 32) FMA per k-step per
// thread against 3-4 ds_read_b128 -> FMA-bound.
// EPI: 0 = none, 2 = +bias +gelu, 3 = +bias +residual R
// Requires K%16==0, N%TNV==0.
// ---------------------------------------------------------------------------
#define GTK 16
#define APITCH 132

template <int TNV, int RN, int EPI>
__global__ __launch_bounds__(256) void gemm_big(const float* __restrict__ A,
                                                const float* __restrict__ W,
                                                const float* __restrict__ bias,
                                                const float* R, float* C,
                                                int M, int N, int K) {
    __shared__ float As[GTK][APITCH];        // A transposed: As[k][m], m<128
    __shared__ float Bs[GTK][TNV + 4];
    int tid = threadIdx.x;
    int n0 = blockIdx.x * TNV;
    int m0 = blockIdx.y * 128;
    int tx = tid & 15, ty = tid >> 4;

    int la_m = tid >> 2;             // 0..63
    int la_k = (tid & 3) * 4;        // 0,4,8,12
    int lb_k = tid >> 4;             // 0..15
    int lb_n = (tid & 15) * 4;       // 0..60

    float acc[8][RN] = {};

    for (int k0 = 0; k0 < K; k0 += GTK) {
        float4 av0 = make_float4(0.f, 0.f, 0.f, 0.f);
        float4 av1 = make_float4(0.f, 0.f, 0.f, 0.f);
        if (m0 + la_m < M)      av0 = *(const float4*)(A + (size_t)(m0 + la_m) * K + k0 + la_k);
        if (m0 + la_m + 64 < M) av1 = *(const float4*)(A + (size_t)(m0 + la_m + 64) * K + k0 + la_k);
        float4 bv0 = *(const float4*)(W + (size_t)(k0 + lb_k) * N + n0 + lb_n);
        float4 bv1;
        if (TNV == 128) bv1 = *(const float4*)(W + (size_t)(k0 + lb_k) * N + n0 + lb_n + 64);
        As[la_k + 0][la_m] = av0.x;
        As[la_k + 1][la_m] = av0.y;
        As[la_k + 2][la_m] = av0.z;
        As[la_k + 3][la_m] = av0.w;
        As[la_k + 0][la_m + 64] = av1.x;
        As[la_k + 1][la_m + 64] = av1.y;
        As[la_k + 2][la_m + 64] = av1.z;
        As[la_k + 3][la_m + 64] = av1.w;
        *(float4*)&Bs[lb_k][lb_n] = bv0;
        if (TNV == 128) *(float4*)&Bs[lb_k][lb_n + 64] = bv1;
        __syncthreads();
#pragma unroll
        for (int kk = 0; kk < GTK; kk++) {
            float a[8], bfr[RN];
            *(float4*)&a[0] = *(const float4*)&As[kk][ty * 8];
            *(float4*)&a[4] = *(const float4*)&As[kk][ty * 8 + 4];
            *(float4*)&bfr[0] = *(const float4*)&Bs[kk][tx * RN];
            if (RN == 8) *(float4*)&bfr[4] = *(const float4*)&Bs[kk][tx * RN + 4];
#pragma unroll
            for (int i = 0; i < 8; i++)
#pragma unroll
                for (int j = 0; j < RN; j++)
                    acc[i][j] += a[i] * bfr[j];
        }
        __syncthreads();
    }
#pragma unroll
    for (int i = 0; i < 8; i++) {
        int row = m0 + ty * 8 + i;
        if (row < M) {
#pragma unroll
            for (int j = 0; j < RN; j++) {
                int col = n0 + tx * RN + j;
                float v = acc[i][j];
                if (EPI >= 2) v += bias[col];
                if (EPI == 2) v = gelu_exact(v);
                if (EPI == 3) v += R[(size_t)row * N + col];
                C[(size_t)row * N + col] = v;
            }
        }
    }
}

// ---------------------------------------------------------------------------
// Flash attention: 1 block (256 thr) per (q-tile of 64, head, batch).
// ---------------------------------------------------------------------------
#define APAD 68

__global__ __launch_bounds__(256) void attn_flash_kernel(const float* __restrict__ qkv,
                                                         float* __restrict__ o) {
    int qt = blockIdx.x, h = blockIdx.y, b = blockIdx.z;
    int tid = threadIdx.x;
    int tx = tid & 15, ty = tid >> 4;

    __shared__ __align__(16) float Qs[64][APAD];
    __shared__ __align__(16) float Ks[64][APAD];
    __shared__ __align__(16) float Vs[64][APAD];
    __shared__ __align__(16) float Pt[64][APAD];
    __shared__ float pred[64][17];
    __shared__ float m_run[64], l_run[64], alpha_s[64];

    int q0 = qt * 64;
    int nq = SSEQ - q0; if (nq > 64) nq = 64;

    {
        int r = tid >> 4;
        int c4 = (tid & 15) * 4;
#pragma unroll
        for (int it = 0; it < 4; it++) {
            int row = r + it * 16;
            int gq = q0 + (row < nq ? row : nq - 1);
            const float* src = qkv + ((size_t)(b * SSEQ + gq) * 1536) + h * 64 + c4;
            *(float4*)&Qs[row][c4] = *(const float4*)src;
        }
    }
    if (tid < 64) { m_run[tid] = -INFINITY; l_run[tid] = 0.f; }

    float O[4][4] = {};

    for (int kt = 0; kt < 13; kt++) {
        int k0 = kt * 64;
        int nk = SSEQ - k0; if (nk > 64) nk = 64;
        __syncthreads();
        {
            int r = tid >> 4;
            int c4 = (tid & 15) * 4;
#pragma unroll
            for (int it = 0; it < 4; it++) {
                int row = r + it * 16;
                int gk = k0 + (row < nk ? row : nk - 1);
                const float* base = qkv + ((size_t)(b * SSEQ + gk) * 1536) + h * 64 + c4;
                *(float4*)&Ks[row][c4] = *(const float4*)(base + 512);
                *(float4*)&Vs[row][c4] = *(const float4*)(base + 1024);
            }
        }
        __syncthreads();

        float s[4][4] = {};
#pragma unroll
        for (int d4 = 0; d4 < 64; d4 += 4) {
            float4 qv[4], kv[4];
#pragma unroll
            for (int i = 0; i < 4; i++) qv[i] = *(const float4*)&Qs[4 * ty + i][d4];
#pragma unroll
            for (int j = 0; j < 4; j++) kv[j] = *(const float4*)&Ks[tx + 16 * j][d4];
#pragma unroll
            for (int i = 0; i < 4; i++)
#pragma unroll
                for (int j = 0; j < 4; j++)
                    s[i][j] += qv[i].x * kv[j].x + qv[i].y * kv[j].y +
                               qv[i].z * kv[j].z + qv[i].w * kv[j].w;
        }
#pragma unroll
        for (int i = 0; i < 4; i++)
#pragma unroll
            for (int j = 0; j < 4; j++) {
                s[i][j] *= 0.125f;
                if (tx + 16 * j >= nk) s[i][j] = -INFINITY;
            }
#pragma unroll
        for (int i = 0; i < 4; i++) {
            float lm = fmaxf(fmaxf(s[i][0], s[i][1]), fmaxf(s[i][2], s[i][3]));
            pred[4 * ty + i][tx] = lm;
        }
        __syncthreads();
        if (tid < 64) {
            float tm = -INFINITY;
#pragma unroll
            for (int c = 0; c < 16; c++) tm = fmaxf(tm, pred[tid][c]);
            float mo = m_run[tid];
            float mn = fmaxf(mo, tm);
            m_run[tid] = mn;
            alpha_s[tid] = __expf(mo - mn);
        }
        __syncthreads();
#pragma unroll
        for (int i = 0; i < 4; i++) {
            int q = 4 * ty + i;
            float mn = m_run[q];
            float al = alpha_s[q];
            float ls = 0.f;
#pragma unroll
            for (int j = 0; j < 4; j++) {
                float p = __expf(s[i][j] - mn);
                Pt[tx + 16 * j][q] = p;
                ls += p;
            }
            pred[q][tx] = ls;
#pragma unroll
            for (int j = 0; j < 4; j++) O[i][j] *= al;
        }
        __syncthreads();
        if (tid < 64) {
            float ts = 0.f;
#pragma unroll
            for (int c = 0; c < 16; c++) ts += pred[tid][c];
            l_run[tid] = l_run[tid] * alpha_s[tid] + ts;
        }
#pragma unroll 4
        for (int k = 0; k < 64; k++) {
            float4 pv = *(const float4*)&Pt[k][4 * ty];
            float4 vv = *(const float4*)&Vs[k][4 * tx];
            O[0][0] += pv.x * vv.x; O[0][1] += pv.x * vv.y; O[0][2] += pv.x * vv.z; O[0][3] += pv.x * vv.w;
            O[1][0] += pv.y * vv.x; O[1][1] += pv.y * vv.y; O[1][2] += pv.y * vv.z; O[1][3] += pv.y * vv.w;
            O[2][0] += pv.z * vv.x; O[2][1] += pv.z * vv.y; O[2][2] += pv.z * vv.z; O[2][3] += pv.z * vv.w;
            O[3][0] += pv.w * vv.x; O[3][1] += pv.w * vv.y; O[3][2] += pv.w * vv.z; O[3][3] += pv.w * vv.w;
        }
    }
    __syncthreads();
#pragma unroll
    for (int i = 0; i < 4; i++) {
        int q = 4 * ty + i;
        if (q < nq) {
            float inv = 1.0f / l_run[q];
            float4 r;
            r.x = O[i][0] * inv; r.y = O[i][1] * inv;
            r.z = O[i][2] * inv; r.w = O[i][3] * inv;
            float* dst = o + ((size_t)(b * SSEQ + q0 + q)) * DIMC + h * 64 + 4 * tx;
            *(float4*)dst = r;
        }
    }
}

// ---------------------------------------------------------------------------
// Head: two-stage max-pool + LN, then parallel head GEMVs.
// ---------------------------------------------------------------------------
__global__ __launch_bounds__(512) void pool_max_kernel(const float* __restrict__ x,
                                                       float* __restrict__ partial) {
    int c = blockIdx.x;        // 0..12 (chunks of 60 rows)
    int bb = blockIdx.y;
    int d = threadIdx.x;
    const float* xb = x + ((size_t)(bb * SSEQ + c * 60)) * DIMC + d;
    float m = -INFINITY;
#pragma unroll 4
    for (int s = 0; s < 60; s++) m = fmaxf(m, xb[(size_t)s * DIMC]);
    partial[((size_t)bb * 13 + c) * DIMC + d] = m;
}

__global__ __launch_bounds__(512) void pool_ln_kernel(const float* __restrict__ partial,
                                                      const float* __restrict__ g,
                                                      const float* __restrict__ b,
                                                      float* __restrict__ out) {
    int bb = blockIdx.x;
    int d = threadIdx.x;
    const float* pb = partial + (size_t)bb * 13 * DIMC + d;
    float m = -INFINITY;
#pragma unroll
    for (int c = 0; c < 13; c++) m = fmaxf(m, pb[(size_t)c * DIMC]);
    __shared__ float col[512];
    __shared__ float red[512];
    col[d] = m;
    red[d] = m;
    __syncthreads();
    for (int s = 256; s > 0; s >>= 1) {
        if (d < s) red[d] += red[d + s];
        __syncthreads();
    }
    float mean = red[0] * (1.0f / 512.0f);
    __syncthreads();
    float dv = col[d] - mean;
    red[d] = dv * dv;
    __syncthreads();
    for (int s = 256; s > 0; s >>= 1) {
        if (d < s) red[d] += red[d + s];
        __syncthreads();
    }
    float var = red[0] * (1.0f / 512.0f);
    float inv = 1.0f / sqrtf(var + 1e-5f);
    out[(size_t)bb * DIMC + d] = dv * inv * g[d] + b[d];
}

// head1: grid (16, B); block computes 64 cols of gelu(x@W+b); 4 k-slices
__global__ __launch_bounds__(256) void head1_kernel(const float* __restrict__ in,
                                                    const float* __restrict__ W,
                                                    const float* __restrict__ bias,
                                                    float* __restrict__ out) {
    int g = blockIdx.x, bb = blockIdx.y;
    int tid = threadIdx.x;
    int c = tid & 63, ks = tid >> 6;
    int col = g * 64 + c;
    __shared__ float xr[512];
    xr[tid] = in[(size_t)bb * 512 + tid];
    xr[tid + 256] = in[(size_t)bb * 512 + tid + 256];
    __syncthreads();
    float acc = 0.f;
    const float* Wc = W + col;
    for (int k = ks * 128; k < ks * 128 + 128; k++)
        acc += xr[k] * Wc[(size_t)k * MLPD];
    __shared__ float red[256];
    red[tid] = acc;
    __syncthreads();
    if (ks == 0) {
        float v = red[c] + red[c + 64] + red[c + 128] + red[c + 192] + bias[col];
        out[(size_t)bb * MLPD + col] = gelu_exact(v);
    }
}

// head2: grid (17, B); block computes 64 cols of x@W+b; 4 k-slices
__global__ __launch_bounds__(256) void head2_kernel(const float* __restrict__ in,
                                                    const float* __restrict__ W,
                                                    const float* __restrict__ bias,
                                                    float* __restrict__ out) {
    int g = blockIdx.x, bb = blockIdx.y;
    int tid = threadIdx.x;
    int c = tid & 63, ks = tid >> 6;
    int col = g * 64 + c;
    __shared__ float xr[1024];
    xr[tid] = in[(size_t)bb * 1024 + tid];
    xr[tid + 256] = in[(size_t)bb * 1024 + tid + 256];
    xr[tid + 512] = in[(size_t)bb * 1024 + tid + 512];
    xr[tid + 768] = in[(size_t)bb * 1024 + tid + 768];
    __syncthreads();
    float acc = 0.f;
    const float* Wc = W + col;
    for (int k = ks * 256; k < ks * 256 + 256; k++)
        acc += xr[k] * Wc[(size_t)k * OUTD];
    __shared__ float red[256];
    red[tid] = acc;
    __syncthreads();
    if (ks == 0) {
        out[(size_t)bb * OUTD + col] = red[c] + red[c + 64] + red[c + 128] + red[c + 192] + bias[col];
    }
}

__global__ __launch_bounds__(64) void smax_anchor_kernel(const float* __restrict__ h2,
                                                         float* __restrict__ out) {
    int bb = blockIdx.x / 17;
    int gcol = blockIdx.x % 17;
    int j = threadIdx.x;
    float v = h2[(size_t)bb * OUTD + gcol * 64 + j];
    float mx = v;
#pragma unroll
    for (int off = 32; off; off >>= 1) mx = fmaxf(mx, __shfl_xor(mx, off));
    float p = expf(v - mx);
    float sum = p;
#pragma unroll
    for (int off = 32; off; off >>= 1) sum += __shfl_xor(sum, off);
    int ix = j >> 4, iy = (j >> 2) & 3, iz = j & 3;
    float sx = p * (-1.5f + (float)ix);
    float sy = p * (-1.5f + (float)iy);
    float sz = p * (-1.5f + (float)iz);
#pragma unroll
    for (int off = 32; off; off >>= 1) {
        sx += __shfl_xor(sx, off);
        sy += __shfl_xor(sy, off);
        sz += __shfl_xor(sz, off);
    }
    if (j == 0) {
        float* o = out + ((size_t)bb * 17 + gcol) * 3;
        o[0] = sx / sum;
        o[1] = sy / sum;
        o[2] = sz / sum;
    }
}

// ---------------------------------------------------------------------------
extern "C" void kernel_launch(void* const* d_in, const int* in_sizes, int n_in,
                              void* d_out, int out_size, void* d_ws, size_t ws_size,
                              hipStream_t stream) {
    const float* points     = (const float*)d_in[0];
    const float* conv_d_w   = (const float*)d_in[1];
    const float* conv_f_w   = (const float*)d_in[2];
    const float* pos_w      = (const float*)d_in[3];
    const float* pos_b      = (const float*)d_in[4];
    const float* ln1_g      = (const float*)d_in[5];
    const float* ln1_b      = (const float*)d_in[6];
    const float* qkv_w      = (const float*)d_in[7];
    const float* attn_out_w = (const float*)d_in[8];
    const float* attn_out_b = (const float*)d_in[9];
    const float* ln2_g      = (const float*)d_in[10];
    const float* ln2_b      = (const float*)d_in[11];
    const float* ff1_w      = (const float*)d_in[12];
    const float* ff1_b      = (const float*)d_in[13];
    const float* ff2_w      = (const float*)d_in[14];
    const float* ff2_b      = (const float*)d_in[15];
    const float* head_ln_g  = (const float*)d_in[16];
    const float* head_ln_b  = (const float*)d_in[17];
    const float* head1_w    = (const float*)d_in[18];
    const float* head1_b    = (const float*)d_in[19];
    const float* head2_w    = (const float*)d_in[20];
    const float* head2_b    = (const float*)d_in[21];

    float* ws = (float*)d_ws;
    float* pts    = ws;                    // 499200
    float* axyz   = pts + 499200;          // 18720
    float* xbuf   = axyz + 18720;          // 3194880
    float* xn     = xbuf + 3194880;        // 3194880 (also pool partials after layers)
    float* qkv    = xn + 3194880;          // 9584640 (reused as ffh)
    float* attno  = qkv + 9584640;         // 3194880
    float* pooled = attno + 3194880;       // 4096
    float* h1     = pooled + 4096;         // 8192
    float* h2     = h1 + 8192;             // 8704
    float* ffh    = qkv;                   // alias: qkv dead after attention
    float* ppart  = xn;                    // alias: xn dead after last ff2

    build_pts_kernel<<<650, 256, 0, stream>>>(points, pts);
    fps_kernel<<<24, 256, 0, stream>>>(pts, axyz);
    group_conv_kernel<<<NROWS, 64, 0, stream>>>(pts, axyz, conv_d_w, conv_f_w,
                                                pos_w, pos_b, xbuf);
    const int MB = (NROWS + 127) / 128;    // 49 row-blocks
    for (int l = 0; l < 5; l++) {
        ln_kernel<<<NROWS, 64, 0, stream>>>(xbuf, ln1_g + l * 512, ln1_b + l * 512, xn);
        gemm_big<128, 8, 0><<<dim3(1536 / 128, MB), 256, 0, stream>>>(
            xn, qkv_w + (size_t)l * 512 * 1536, nullptr, nullptr, qkv, NROWS, 1536, 512);
        attn_flash_kernel<<<dim3(13, NHEAD, BB), 256, 0, stream>>>(qkv, attno);
        gemm_big<64, 4, 3><<<dim3(512 / 64, MB), 256, 0, stream>>>(
            attno, attn_out_w + (size_t)l * 512 * 512, attn_out_b + l * 512, xbuf, xbuf,
            NROWS, 512, 512);
        ln_kernel<<<NROWS, 64, 0, stream>>>(xbuf, ln2_g + l * 512, ln2_b + l * 512, xn);
        gemm_big<128, 8, 2><<<dim3(1024 / 128, MB), 256, 0, stream>>>(
            xn, ff1_w + (size_t)l * 512 * 1024, ff1_b + l * 1024, nullptr, ffh,
            NROWS, 1024, 512);
        gemm_big<64, 4, 3><<<dim3(512 / 64, MB), 256, 0, stream>>>(
            ffh, ff2_w + (size_t)l * 1024 * 512, ff2_b + l * 512, xbuf, xbuf,
            NROWS, 512, 1024);
    }
    pool_max_kernel<<<dim3(13, BB), 512, 0, stream>>>(xbuf, ppart);
    pool_ln_kernel<<<BB, 512, 0, stream>>>(ppart, head_ln_g, head_ln_b, pooled);
    head1_kernel<<<dim3(16, BB), 256, 0, stream>>>(pooled, head1_w, head1_b, h1);
    head2_kernel<<<dim3(17, BB), 256, 0, stream>>>(h1, head2_w, head2_b, h2);
    smax_anchor_kernel<<<BB * 17, 64, 0, stream>>>(h2, (float*)d_out);
}

// Round 4
// 2774.016 us; speedup vs baseline: 5.2522x; 1.4959x over previous
//
#include <hip/hip_runtime.h>
#include <hip/hip_bf16.h>
#include <cstddef>

// Problem constants
#define BB 8
#define LL 5
#define NN 4096
#define NANCH 64
#define NPTS 4160      // NN + NANCH
#define MM 260         // NPTS / 16
#define NFRAME 3
#define SSEQ 780       // NFRAME * MM
#define DIMC 512
#define NHEAD 8
#define DHEAD 64
#define MLPD 1024
#define OUTD 1088
#define NROWS 6240     // BB * SSEQ

typedef __attribute__((ext_vector_type(8))) short s16x8;
typedef __attribute__((ext_vector_type(4))) float fx4;
typedef unsigned short ushort_t;
typedef unsigned int uint_t;

// exact (non-contracted) squared distance, matching numpy fp32 op order
__device__ __forceinline__ float sqdist_rn(float x1, float y1, float z1,
                                           float x2, float y2, float z2) {
    float dx = __fsub_rn(x1, x2);
    float dy = __fsub_rn(y1, y2);
    float dz = __fsub_rn(z1, z2);
    return __fadd_rn(__fadd_rn(__fmul_rn(dx, dx), __fmul_rn(dy, dy)), __fmul_rn(dz, dz));
}

__device__ __forceinline__ float gelu_exact(float v) {
    return 0.5f * v * (1.0f + erff(v * 0.70710678118654752440f));
}

// round-to-nearest-even-ish bf16 (round-half-away tie handling via LSB trick)
__device__ __forceinline__ uint_t bf16rn(float f) {
    uint_t u = __float_as_uint(f);
    return (u + 0x7FFFu + ((u >> 16) & 1u)) >> 16;
}
// split fp32 into bf16 hi + bf16 lo (residual)
__device__ __forceinline__ void split2(float f, ushort_t& h, ushort_t& l) {
    uint_t hb = bf16rn(f);
    h = (ushort_t)hb;
    float fh = __uint_as_float(hb << 16);
    l = (ushort_t)bf16rn(f - fh);
}

// ---------------------------------------------------------------------------
__global__ __launch_bounds__(256) void build_pts_kernel(const float* __restrict__ points,
                                                        float* __restrict__ pts) {
    int i = blockIdx.x * 256 + threadIdx.x;   // over B*L*NPTS = 166400
    if (i >= BB * LL * NPTS) return;
    int n = i % NPTS;
    int bl = i / NPTS;
    if (n < NN) {
        const float* src = points + ((size_t)bl * NN + n) * 3;
        pts[(size_t)i * 3 + 0] = src[0];
        pts[(size_t)i * 3 + 1] = src[1];
        pts[(size_t)i * 3 + 2] = src[2];
    } else {
        int j = n - NN;
        int ix = j >> 4, iy = (j >> 2) & 3, iz = j & 3;
        pts[(size_t)i * 3 + 0] = -1.5f + (float)ix;
        pts[(size_t)i * 3 + 1] = -1.5f + (float)iy;
        pts[(size_t)i * 3 + 2] = -1.5f + (float)iz;
    }
}

// ---------------------------------------------------------------------------
// FPS: 1 block per (b, f); 260 serial iterations with ONE barrier each.
// Coords mirrored in LDS so every thread can fetch the winner's point
// (removes the serial tid==0 section and the second barrier).
// ---------------------------------------------------------------------------
__global__ __launch_bounds__(256) void fps_kernel(const float* __restrict__ pts,
                                                  float* __restrict__ axyz) {
    int blk = blockIdx.x;           // 0..23
    int b = blk / 3, f = blk % 3;
    const float* P = pts + (size_t)(b * LL + 2 * f) * NPTS * 3;
    int tid = threadIdx.x;
    const int PPT = 17;             // ceil(4160/256)
    __shared__ float sx[NPTS], sy[NPTS], sz[NPTS];
    __shared__ float redv[2][4];
    __shared__ int redi[2][4];
    float px[PPT], py[PPT], pz[PPT], dist[PPT];
#pragma unroll
    for (int j = 0; j < PPT; j++) {
        int n = tid + 256 * j;
        if (n < NPTS) {
            float gx = P[(size_t)n * 3 + 0];
            float gy = P[(size_t)n * 3 + 1];
            float gz = P[(size_t)n * 3 + 2];
            px[j] = gx; py[j] = gy; pz[j] = gz;
            sx[n] = gx; sy[n] = gy; sz[n] = gz;
            dist[j] = 1e10f;
        } else {
            px[j] = 0.f; py[j] = 0.f; pz[j] = 0.f;
            dist[j] = -1.0f;   // never selected
        }
    }
    __syncthreads();
    float ax = sx[0], ay = sy[0], az = sz[0];
    float* out = axyz + (size_t)blk * MM * 3;
    for (int m = 0; m < MM; m++) {
        if (tid == 0) { out[m * 3 + 0] = ax; out[m * 3 + 1] = ay; out[m * 3 + 2] = az; }
        float bestv = -1.0f;
        int bestn = NPTS;
#pragma unroll
        for (int j = 0; j < PPT; j++) {
            int n = tid + 256 * j;
            if (n < NPTS) {
                float d = sqdist_rn(px[j], py[j], pz[j], ax, ay, az);
                float dj = fminf(dist[j], d);
                dist[j] = dj;
                if (dj > bestv) { bestv = dj; bestn = n; }
            }
        }
#pragma unroll
        for (int off = 32; off; off >>= 1) {
            float ov = __shfl_xor(bestv, off);
            int on = __shfl_xor(bestn, off);
            if (ov > bestv || (ov == bestv && on < bestn)) { bestv = ov; bestn = on; }
        }
        int par = m & 1;
        if ((tid & 63) == 0) { redv[par][tid >> 6] = bestv; redi[par][tid >> 6] = bestn; }
        __syncthreads();
        float bv = redv[par][0];
        int bn = redi[par][0];
#pragma unroll
        for (int w = 1; w < 4; w++) {
            float v2 = redv[par][w]; int i2 = redi[par][w];
            if (v2 > bv || (v2 == bv && i2 < bn)) { bv = v2; bn = i2; }
        }
        ax = sx[bn]; ay = sy[bn]; az = sz[bn];
    }
}

// ---------------------------------------------------------------------------
// Ball query + grouped conv + max over k + max over window + pos embedding.
// ---------------------------------------------------------------------------
__global__ __launch_bounds__(64) void group_conv_kernel(
    const float* __restrict__ pts, const float* __restrict__ axyz,
    const float* __restrict__ conv_d_w, const float* __restrict__ conv_f_w,
    const float* __restrict__ pos_w, const float* __restrict__ pos_b,
    float* __restrict__ x) {
    int gid = blockIdx.x;                 // b*780 + f*260 + m
    int b = gid / SSEQ;
    int rem = gid % SSEQ;
    int f = rem / MM;
    int lane = threadIdx.x;
    const float* A = axyz + (size_t)gid * 3;
    float ax = A[0], ay = A[1], az = A[2];

    float cf0[8], cf1[8], cf2[8], cd0[8], cd1[8], cd2[8], cd3[8], fmx[8];
#pragma unroll
    for (int c = 0; c < 8; c++) {
        int d = lane + 64 * c;
        cf0[c] = conv_f_w[d * 3 + 0];
        cf1[c] = conv_f_w[d * 3 + 1];
        cf2[c] = conv_f_w[d * 3 + 2];
        cd0[c] = conv_d_w[d * 4 + 0];
        cd1[c] = conv_d_w[d * 4 + 1];
        cd2[c] = conv_d_w[d * 4 + 2];
        cd3[c] = conv_d_w[d * 4 + 3];
        fmx[c] = -INFINITY;
    }
    __shared__ int nbr[32];
    __shared__ float gxs[32], gys[32], gzs[32];
    const float R2 = 0.49000000953674316f;

    for (int wi = 0; wi < 3; wi++) {
        int l = 2 * f + wi - 1;
        l = l < 0 ? 0 : (l > 4 ? 4 : l);
        const float* P = pts + (size_t)(b * LL + l) * NPTS * 3;
        int cnt = 0;
        for (int base = 0; base < NPTS && cnt < 32; base += 64) {
            int n = base + lane;
            float d2 = sqdist_rn(P[(size_t)n * 3], P[(size_t)n * 3 + 1], P[(size_t)n * 3 + 2],
                                 ax, ay, az);
            bool hit = d2 < R2;
            unsigned long long mk = __ballot(hit);
            int rank = (int)__popcll(mk & (((unsigned long long)1 << lane) - 1ull));
            if (hit && (cnt + rank) < 32) nbr[cnt + rank] = n;
            cnt += (int)__popcll(mk);
        }
        __syncthreads();
        int eff = cnt < 32 ? cnt : 32;
        if (lane < 32) {
            int idx = (eff == 0) ? 0 : (lane < eff ? nbr[lane] : nbr[0]);
            gxs[lane] = P[(size_t)idx * 3 + 0];
            gys[lane] = P[(size_t)idx * 3 + 1];
            gzs[lane] = P[(size_t)idx * 3 + 2];
        }
        __syncthreads();
        float tf = (float)(wi - 1);
        for (int k = 0; k < 32; k++) {
            float gx = gxs[k], gy = gys[k], gz = gzs[k];
            float dx = gx - ax, dy = gy - ay, dz = gz - az;
#pragma unroll
            for (int c = 0; c < 8; c++) {
                float v = gx * cf0[c] + gy * cf1[c] + gz * cf2[c] +
                          dx * cd0[c] + dy * cd1[c] + dz * cd2[c] + tf * cd3[c];
                fmx[c] = fmaxf(fmx[c], v);
            }
        }
        __syncthreads();
    }
    float tcol = (float)(f + 1);
#pragma unroll
    for (int c = 0; c < 8; c++) {
        int d = lane + 64 * c;
        float pos = ax * pos_w[d * 4 + 0] + ay * pos_w[d * 4 + 1] +
                    az * pos_w[d * 4 + 2] + tcol * pos_w[d * 4 + 3] + pos_b[d];
        x[(size_t)gid * DIMC + d] = fmx[c] + pos;
    }
}

// ---------------------------------------------------------------------------
// LayerNorm over last dim 512; output written as bf16 hi/lo split (GEMM A).
// ---------------------------------------------------------------------------
__global__ __launch_bounds__(64) void ln_kernel(const float* __restrict__ x,
                                                const float* __restrict__ g,
                                                const float* __restrict__ b,
                                                ushort_t* __restrict__ yh,
                                                ushort_t* __restrict__ yl) {
    int r = blockIdx.x;
    int lane = threadIdx.x;
    const float* xr = x + (size_t)r * DIMC;
    float4 v0 = *(const float4*)(xr + lane * 8);
    float4 v1 = *(const float4*)(xr + lane * 8 + 4);
    float s = v0.x + v0.y + v0.z + v0.w + v1.x + v1.y + v1.z + v1.w;
#pragma unroll
    for (int off = 32; off; off >>= 1) s += __shfl_xor(s, off);
    float mean = s * (1.0f / 512.0f);
    float dv[8];
    dv[0] = v0.x - mean; dv[1] = v0.y - mean; dv[2] = v0.z - mean; dv[3] = v0.w - mean;
    dv[4] = v1.x - mean; dv[5] = v1.y - mean; dv[6] = v1.z - mean; dv[7] = v1.w - mean;
    float sq = 0.f;
#pragma unroll
    for (int c = 0; c < 8; c++) sq += dv[c] * dv[c];
#pragma unroll
    for (int off = 32; off; off >>= 1) sq += __shfl_xor(sq, off);
    float var = sq * (1.0f / 512.0f);
    float inv = 1.0f / sqrtf(var + 1e-5f);
    int d = lane * 8;
    ushort_t hs[8], ls[8];
#pragma unroll
    for (int c = 0; c < 8; c++) {
        float v = dv[c] * inv * g[d + c] + b[d + c];
        split2(v, hs[c], ls[c]);
    }
    uint4 hv, lv;
    hv.x = hs[0] | ((uint_t)hs[1] << 16); hv.y = hs[2] | ((uint_t)hs[3] << 16);
    hv.z = hs[4] | ((uint_t)hs[5] << 16); hv.w = hs[6] | ((uint_t)hs[7] << 16);
    lv.x = ls[0] | ((uint_t)ls[1] << 16); lv.y = ls[2] | ((uint_t)ls[3] << 16);
    lv.z = ls[4] | ((uint_t)ls[5] << 16); lv.w = ls[6] | ((uint_t)ls[7] << 16);
    *(uint4*)(yh + (size_t)r * DIMC + d) = hv;
    *(uint4*)(yl + (size_t)r * DIMC + d) = lv;
}

// ---------------------------------------------------------------------------
// Weight transpose + bf16 split for one layer's 4 matrices.
// Output layout: Wt[n][k] (N x K), hi and lo arrays, at fixed offsets.
// ---------------------------------------------------------------------------
__global__ __launch_bounds__(256) void wsplit_kernel(const float* __restrict__ qkvw,
                                                     const float* __restrict__ projw,
                                                     const float* __restrict__ ff1w,
                                                     const float* __restrict__ ff2w,
                                                     ushort_t* __restrict__ th,
                                                     ushort_t* __restrict__ tl) {
    int bid = blockIdx.x;
    const float* src; int K, N; size_t dst;
    if (bid < 768)       { src = qkvw;  K = 512;  N = 1536; dst = 0;       }
    else if (bid < 1024) { src = projw; K = 512;  N = 512;  dst = 786432;  bid -= 768;  }
    else if (bid < 1536) { src = ff1w;  K = 512;  N = 1024; dst = 1048576; bid -= 1024; }
    else                 { src = ff2w;  K = 1024; N = 512;  dst = 1572864; bid -= 1536; }
    int ntn = N >> 5;
    int tn = bid % ntn, tk = bid / ntn;
    int n0 = tn * 32, k0 = tk * 32;
    __shared__ float T[32][33];
    int tid = threadIdx.x;
    int tx = tid & 31, ty = tid >> 5;
#pragma unroll
    for (int i = 0; i < 4; i++)
        T[ty + 8 * i][tx] = src[(size_t)(k0 + ty + 8 * i) * N + n0 + tx];
    __syncthreads();
#pragma unroll
    for (int i = 0; i < 4; i++) {
        int n = n0 + ty + 8 * i;
        int k = k0 + tx;
        ushort_t h, l;
        split2(T[tx][ty + 8 * i], h, l);
        th[dst + (size_t)n * K + k] = h;
        tl[dst + (size_t)n * K + k] = l;
    }
}

// ---------------------------------------------------------------------------
// bf16x3 MFMA GEMM (fp32 emulation): C = A @ W
// A given as hi/lo bf16 (M x K row-major); W given as hi/lo bf16 TRANSPOSED
// (N x K row-major). acc += Ah*Wh + Ah*Wl + Al*Wh via mfma_f32_16x16x32_bf16.
// Block tile 128 x BN, BK=32, 4 waves (2x2). Wave tile 64 x BN/2.
// EPI: 0 = store fp32 C; 2 = bias+gelu -> split store (Ch,Cl); 3 = bias+R -> C
// ---------------------------------------------------------------------------
#define KP 40   // LDS row pitch in ushorts (80 B: 16B-aligned, <=2-way banks)

template <int BN, int EPI>
__global__ __launch_bounds__(256, 2) void gemm_mfma(
    const ushort_t* __restrict__ Ahg, const ushort_t* __restrict__ Alg,
    const ushort_t* __restrict__ Bhg, const ushort_t* __restrict__ Blg,
    const float* __restrict__ bias, const float* __restrict__ R,
    float* __restrict__ C, ushort_t* __restrict__ Ch, ushort_t* __restrict__ Cl,
    int M, int N, int K) {
    const int WN = BN / 2, NT = WN / 16;
    __shared__ ushort_t Ah[128 * KP];
    __shared__ ushort_t Al[128 * KP];
    __shared__ ushort_t Bh[BN * KP];
    __shared__ ushort_t Bl[BN * KP];
    int tid = threadIdx.x;
    int lane = tid & 63, w = tid >> 6;
    int wm = w & 1, wn = w >> 1;
    int quad = lane >> 4, l15 = lane & 15;
    int m0 = blockIdx.y * 128, n0 = blockIdx.x * BN;

    fx4 acc[4][NT];
#pragma unroll
    for (int mi = 0; mi < 4; mi++)
#pragma unroll
        for (int nj = 0; nj < NT; nj++) acc[mi][nj] = (fx4){0.f, 0.f, 0.f, 0.f};

    for (int k0 = 0; k0 < K; k0 += 32) {
        // stage A (hi+lo): 128 rows x 32 k
#pragma unroll
        for (int i = 0; i < 2; i++) {
            int task = tid + 256 * i;
            int row = task >> 2, kc = (task & 3) * 8;
            if (m0 + row < M) {
                size_t go = (size_t)(m0 + row) * K + k0 + kc;
                *(float4*)&Ah[row * KP + kc] = *(const float4*)(Ahg + go);
                *(float4*)&Al[row * KP + kc] = *(const float4*)(Alg + go);
            }
        }
        // stage B (hi+lo): BN rows x 32 k (Wt is N x K)
#pragma unroll
        for (int i = 0; i < BN / 64; i++) {
            int task = tid + 256 * i;
            int row = task >> 2, kc = (task & 3) * 8;
            size_t go = (size_t)(n0 + row) * K + k0 + kc;
            *(float4*)&Bh[row * KP + kc] = *(const float4*)(Bhg + go);
            *(float4*)&Bl[row * KP + kc] = *(const float4*)(Blg + go);
        }
        __syncthreads();
        s16x8 af[4][2], bf[NT][2];
#pragma unroll
        for (int mi = 0; mi < 4; mi++) {
            int off = (64 * wm + 16 * mi + l15) * KP + quad * 8;
            af[mi][0] = *(const s16x8*)&Ah[off];
            af[mi][1] = *(const s16x8*)&Al[off];
        }
#pragma unroll
        for (int nj = 0; nj < NT; nj++) {
            int off = (WN * wn + 16 * nj + l15) * KP + quad * 8;
            bf[nj][0] = *(const s16x8*)&Bh[off];
            bf[nj][1] = *(const s16x8*)&Bl[off];
        }
#pragma unroll
        for (int mi = 0; mi < 4; mi++)
#pragma unroll
            for (int nj = 0; nj < NT; nj++) {
                acc[mi][nj] = __builtin_amdgcn_mfma_f32_16x16x32_bf16(af[mi][0], bf[nj][0], acc[mi][nj], 0, 0, 0);
                acc[mi][nj] = __builtin_amdgcn_mfma_f32_16x16x32_bf16(af[mi][0], bf[nj][1], acc[mi][nj], 0, 0, 0);
                acc[mi][nj] = __builtin_amdgcn_mfma_f32_16x16x32_bf16(af[mi][1], bf[nj][0], acc[mi][nj], 0, 0, 0);
            }
        __syncthreads();
    }
    // epilogue: D[row = quad*4 + r][col = l15] per 16x16 tile
#pragma unroll
    for (int mi = 0; mi < 4; mi++) {
#pragma unroll
        for (int r = 0; r < 4; r++) {
            int row = m0 + 64 * wm + 16 * mi + quad * 4 + r;
            if (row < M) {
#pragma unroll
                for (int nj = 0; nj < NT; nj++) {
                    int col = n0 + WN * wn + 16 * nj + l15;
                    float v = acc[mi][nj][r];
                    if (EPI == 0) {
                        C[(size_t)row * N + col] = v;
                    } else if (EPI == 3) {
                        C[(size_t)row * N + col] = v + bias[col] + R[(size_t)row * N + col];
                    } else if (EPI == 2) {
                        float gv = gelu_exact(v + bias[col]);
                        ushort_t h, l;
                        split2(gv, h, l);
                        Ch[(size_t)row * N + col] = h;
                        Cl[(size_t)row * N + col] = l;
                    }
                }
            }
        }
    }
}

// ---------------------------------------------------------------------------
// Flash attention: 1 block (256 thr) per (q-tile of 64, head, batch).
// Output written as bf16 hi/lo split (feeds proj GEMM).
// ---------------------------------------------------------------------------
#define APAD 68

__global__ __launch_bounds__(256) void attn_flash_kernel(const float* __restrict__ qkv,
                                                         ushort_t* __restrict__ oh,
                                                         ushort_t* __restrict__ ol) {
    int qt = blockIdx.x, h = blockIdx.y, b = blockIdx.z;
    int tid = threadIdx.x;
    int tx = tid & 15, ty = tid >> 4;

    __shared__ __align__(16) float Qs[64][APAD];
    __shared__ __align__(16) float Ks[64][APAD];
    __shared__ __align__(16) float Vs[64][APAD];
    __shared__ __align__(16) float Pt[64][APAD];
    __shared__ float pred[64][17];
    __shared__ float m_run[64], l_run[64], alpha_s[64];

    int q0 = qt * 64;
    int nq = SSEQ - q0; if (nq > 64) nq = 64;

    {
        int r = tid >> 4;
        int c4 = (tid & 15) * 4;
#pragma unroll
        for (int it = 0; it < 4; it++) {
            int row = r + it * 16;
            int gq = q0 + (row < nq ? row : nq - 1);
            const float* src = qkv + ((size_t)(b * SSEQ + gq) * 1536) + h * 64 + c4;
            *(float4*)&Qs[row][c4] = *(const float4*)src;
        }
    }
    if (tid < 64) { m_run[tid] = -INFINITY; l_run[tid] = 0.f; }

    float O[4][4] = {};

    for (int kt = 0; kt < 13; kt++) {
        int k0 = kt * 64;
        int nk = SSEQ - k0; if (nk > 64) nk = 64;
        __syncthreads();
        {
            int r = tid >> 4;
            int c4 = (tid & 15) * 4;
#pragma unroll
            for (int it = 0; it < 4; it++) {
                int row = r + it * 16;
                int gk = k0 + (row < nk ? row : nk - 1);
                const float* base = qkv + ((size_t)(b * SSEQ + gk) * 1536) + h * 64 + c4;
                *(float4*)&Ks[row][c4] = *(const float4*)(base + 512);
                *(float4*)&Vs[row][c4] = *(const float4*)(base + 1024);
            }
        }
        __syncthreads();

        float s[4][4] = {};
#pragma unroll
        for (int d4 = 0; d4 < 64; d4 += 4) {
            float4 qv[4], kv[4];
#pragma unroll
            for (int i = 0; i < 4; i++) qv[i] = *(const float4*)&Qs[4 * ty + i][d4];
#pragma unroll
            for (int j = 0; j < 4; j++) kv[j] = *(const float4*)&Ks[tx + 16 * j][d4];
#pragma unroll
            for (int i = 0; i < 4; i++)
#pragma unroll
                for (int j = 0; j < 4; j++)
                    s[i][j] += qv[i].x * kv[j].x + qv[i].y * kv[j].y +
                               qv[i].z * kv[j].z + qv[i].w * kv[j].w;
        }
#pragma unroll
        for (int i = 0; i < 4; i++)
#pragma unroll
            for (int j = 0; j < 4; j++) {
                s[i][j] *= 0.125f;
                if (tx + 16 * j >= nk) s[i][j] = -INFINITY;
            }
#pragma unroll
        for (int i = 0; i < 4; i++) {
            float lm = fmaxf(fmaxf(s[i][0], s[i][1]), fmaxf(s[i][2], s[i][3]));
            pred[4 * ty + i][tx] = lm;
        }
        __syncthreads();
        if (tid < 64) {
            float tm = -INFINITY;
#pragma unroll
            for (int c = 0; c < 16; c++) tm = fmaxf(tm, pred[tid][c]);
            float mo = m_run[tid];
            float mn = fmaxf(mo, tm);
            m_run[tid] = mn;
            alpha_s[tid] = __expf(mo - mn);
        }
        __syncthreads();
#pragma unroll
        for (int i = 0; i < 4; i++) {
            int q = 4 * ty + i;
            float mn = m_run[q];
            float al = alpha_s[q];
            float ls = 0.f;
#pragma unroll
            for (int j = 0; j < 4; j++) {
                float p = __expf(s[i][j] - mn);
                Pt[tx + 16 * j][q] = p;
                ls += p;
            }
            pred[q][tx] = ls;
#pragma unroll
            for (int j = 0; j < 4; j++) O[i][j] *= al;
        }
        __syncthreads();
        if (tid < 64) {
            float ts = 0.f;
#pragma unroll
            for (int c = 0; c < 16; c++) ts += pred[tid][c];
            l_run[tid] = l_run[tid] * alpha_s[tid] + ts;
        }
#pragma unroll 4
        for (int k = 0; k < 64; k++) {
            float4 pv = *(const float4*)&Pt[k][4 * ty];
            float4 vv = *(const float4*)&Vs[k][4 * tx];
            O[0][0] += pv.x * vv.x; O[0][1] += pv.x * vv.y; O[0][2] += pv.x * vv.z; O[0][3] += pv.x * vv.w;
            O[1][0] += pv.y * vv.x; O[1][1] += pv.y * vv.y; O[1][2] += pv.y * vv.z; O[1][3] += pv.y * vv.w;
            O[2][0] += pv.z * vv.x; O[2][1] += pv.z * vv.y; O[2][2] += pv.z * vv.z; O[2][3] += pv.z * vv.w;
            O[3][0] += pv.w * vv.x; O[3][1] += pv.w * vv.y; O[3][2] += pv.w * vv.z; O[3][3] += pv.w * vv.w;
        }
    }
    __syncthreads();
#pragma unroll
    for (int i = 0; i < 4; i++) {
        int q = 4 * ty + i;
        if (q < nq) {
            float inv = 1.0f / l_run[q];
            ushort_t hh[4], lll[4];
#pragma unroll
            for (int j = 0; j < 4; j++) split2(O[i][j] * inv, hh[j], lll[j]);
            size_t base = ((size_t)(b * SSEQ + q0 + q)) * DIMC + h * 64 + 4 * tx;
            uint2 hv, lv;
            hv.x = hh[0] | ((uint_t)hh[1] << 16); hv.y = hh[2] | ((uint_t)hh[3] << 16);
            lv.x = lll[0] | ((uint_t)lll[1] << 16); lv.y = lll[2] | ((uint_t)lll[3] << 16);
            *(uint2*)(oh + base) = hv;
            *(uint2*)(ol + base) = lv;
        }
    }
}

// ---------------------------------------------------------------------------
// Head: two-stage max-pool + LN, then parallel head GEMVs (fp32).
// ---------------------------------------------------------------------------
__global__ __launch_bounds__(512) void pool_max_kernel(const float* __restrict__ x,
                                                       float* __restrict__ partial) {
    int c = blockIdx.x;        // 0..12 (chunks of 60 rows)
    int bb = blockIdx.y;
    int d = threadIdx.x;
    const float* xb = x + ((size_t)(bb * SSEQ + c * 60)) * DIMC + d;
    float m = -INFINITY;
#pragma unroll 4
    for (int s = 0; s < 60; s++) m = fmaxf(m, xb[(size_t)s * DIMC]);
    partial[((size_t)bb * 13 + c) * DIMC + d] = m;
}

__global__ __launch_bounds__(512) void pool_ln_kernel(const float* __restrict__ partial,
                                                      const float* __restrict__ g,
                                                      const float* __restrict__ b,
                                                      float* __restrict__ out) {
    int bb = blockIdx.x;
    int d = threadIdx.x;
    const float* pb = partial + (size_t)bb * 13 * DIMC + d;
    float m = -INFINITY;
#pragma unroll
    for (int c = 0; c < 13; c++) m = fmaxf(m, pb[(size_t)c * DIMC]);
    __shared__ float col[512];
    __shared__ float red[512];
    col[d] = m;
    red[d] = m;
    __syncthreads();
    for (int s = 256; s > 0; s >>= 1) {
        if (d < s) red[d] += red[d + s];
        __syncthreads();
    }
    float mean = red[0] * (1.0f / 512.0f);
    __syncthreads();
    float dv = col[d] - mean;
    red[d] = dv * dv;
    __syncthreads();
    for (int s = 256; s > 0; s >>= 1) {
        if (d < s) red[d] += red[d + s];
        __syncthreads();
    }
    float var = red[0] * (1.0f / 512.0f);
    float inv = 1.0f / sqrtf(var + 1e-5f);
    out[(size_t)bb * DIMC + d] = dv * inv * g[d] + b[d];
}

__global__ __launch_bounds__(256) void head1_kernel(const float* __restrict__ in,
                                                    const float* __restrict__ W,
                                                    const float* __restrict__ bias,
                                                    float* __restrict__ out) {
    int g = blockIdx.x, bb = blockIdx.y;
    int tid = threadIdx.x;
    int c = tid & 63, ks = tid >> 6;
    int col = g * 64 + c;
    __shared__ float xr[512];
    xr[tid] = in[(size_t)bb * 512 + tid];
    xr[tid + 256] = in[(size_t)bb * 512 + tid + 256];
    __syncthreads();
    float acc = 0.f;
    const float* Wc = W + col;
    for (int k = ks * 128; k < ks * 128 + 128; k++)
        acc += xr[k] * Wc[(size_t)k * MLPD];
    __shared__ float red[256];
    red[tid] = acc;
    __syncthreads();
    if (ks == 0) {
        float v = red[c] + red[c + 64] + red[c + 128] + red[c + 192] + bias[col];
        out[(size_t)bb * MLPD + col] = gelu_exact(v);
    }
}

__global__ __launch_bounds__(256) void head2_kernel(const float* __restrict__ in,
                                                    const float* __restrict__ W,
                                                    const float* __restrict__ bias,
                                                    float* __restrict__ out) {
    int g = blockIdx.x, bb = blockIdx.y;
    int tid = threadIdx.x;
    int c = tid & 63, ks = tid >> 6;
    int col = g * 64 + c;
    __shared__ float xr[1024];
    xr[tid] = in[(size_t)bb * 1024 + tid];
    xr[tid + 256] = in[(size_t)bb * 1024 + tid + 256];
    xr[tid + 512] = in[(size_t)bb * 1024 + tid + 512];
    xr[tid + 768] = in[(size_t)bb * 1024 + tid + 768];
    __syncthreads();
    float acc = 0.f;
    const float* Wc = W + col;
    for (int k = ks * 256; k < ks * 256 + 256; k++)
        acc += xr[k] * Wc[(size_t)k * OUTD];
    __shared__ float red[256];
    red[tid] = acc;
    __syncthreads();
    if (ks == 0) {
        out[(size_t)bb * OUTD + col] = red[c] + red[c + 64] + red[c + 128] + red[c + 192] + bias[col];
    }
}

__global__ __launch_bounds__(64) void smax_anchor_kernel(const float* __restrict__ h2,
                                                         float* __restrict__ out) {
    int bb = blockIdx.x / 17;
    int gcol = blockIdx.x % 17;
    int j = threadIdx.x;
    float v = h2[(size_t)bb * OUTD + gcol * 64 + j];
    float mx = v;
#pragma unroll
    for (int off = 32; off; off >>= 1) mx = fmaxf(mx, __shfl_xor(mx, off));
    float p = expf(v - mx);
    float sum = p;
#pragma unroll
    for (int off = 32; off; off >>= 1) sum += __shfl_xor(sum, off);
    int ix = j >> 4, iy = (j >> 2) & 3, iz = j & 3;
    float sx = p * (-1.5f + (float)ix);
    float sy = p * (-1.5f + (float)iy);
    float sz = p * (-1.5f + (float)iz);
#pragma unroll
    for (int off = 32; off; off >>= 1) {
        sx += __shfl_xor(sx, off);
        sy += __shfl_xor(sy, off);
        sz += __shfl_xor(sz, off);
    }
    if (j == 0) {
        float* o = out + ((size_t)bb * 17 + gcol) * 3;
        o[0] = sx / sum;
        o[1] = sy / sum;
        o[2] = sz / sum;
    }
}

// ---------------------------------------------------------------------------
extern "C" void kernel_launch(void* const* d_in, const int* in_sizes, int n_in,
                              void* d_out, int out_size, void* d_ws, size_t ws_size,
                              hipStream_t stream) {
    const float* points     = (const float*)d_in[0];
    const float* conv_d_w   = (const float*)d_in[1];
    const float* conv_f_w   = (const float*)d_in[2];
    const float* pos_w      = (const float*)d_in[3];
    const float* pos_b      = (const float*)d_in[4];
    const float* ln1_g      = (const float*)d_in[5];
    const float* ln1_b      = (const float*)d_in[6];
    const float* qkv_w      = (const float*)d_in[7];
    const float* attn_out_w = (const float*)d_in[8];
    const float* attn_out_b = (const float*)d_in[9];
    const float* ln2_g      = (const float*)d_in[10];
    const float* ln2_b      = (const float*)d_in[11];
    const float* ff1_w      = (const float*)d_in[12];
    const float* ff1_b      = (const float*)d_in[13];
    const float* ff2_w      = (const float*)d_in[14];
    const float* ff2_b      = (const float*)d_in[15];
    const float* head_ln_g  = (const float*)d_in[16];
    const float* head_ln_b  = (const float*)d_in[17];
    const float* head1_w    = (const float*)d_in[18];
    const float* head1_b    = (const float*)d_in[19];
    const float* head2_w    = (const float*)d_in[20];
    const float* head2_b    = (const float*)d_in[21];

    // fp32 region
    float* ws = (float*)d_ws;
    float* pts    = ws;                    //   499,200 f
    float* axyz   = pts + 499200;          //    18,720 f
    float* xbuf   = axyz + 18720;          // 3,194,880 f
    float* qkv    = xbuf + 3194880;        // 9,584,640 f
    float* pooled = qkv + 9584640;         //     4,096 f
    float* h1     = pooled + 4096;         //     8,192 f
    float* h2     = h1 + 8192;             //     8,704 f
    float* fend   = h2 + 8704;
    // bf16 hi/lo region (ushort)
    ushort_t* us   = (ushort_t*)fend;
    ushort_t* xnh  = us;                   // 3,194,880 us
    ushort_t* xnl  = xnh + 3194880;
    ushort_t* atth = xnl + 3194880;
    ushort_t* attl = atth + 3194880;
    ushort_t* ffhh = attl + 3194880;       // 6,389,760 us
    ushort_t* ffhl = ffhh + 6389760;
    ushort_t* wth  = ffhl + 6389760;       // 2,097,152 us (qkv|proj|ff1|ff2 Wt)
    ushort_t* wtl  = wth + 2097152;
    float* ppart = qkv;                    // alias: qkv dead after last layer

    build_pts_kernel<<<650, 256, 0, stream>>>(points, pts);
    fps_kernel<<<24, 256, 0, stream>>>(pts, axyz);
    group_conv_kernel<<<NROWS, 64, 0, stream>>>(pts, axyz, conv_d_w, conv_f_w,
                                                pos_w, pos_b, xbuf);
    const int MB = (NROWS + 127) / 128;    // 49 row-blocks
    for (int l = 0; l < 5; l++) {
        wsplit_kernel<<<2048, 256, 0, stream>>>(
            qkv_w + (size_t)l * 512 * 1536, attn_out_w + (size_t)l * 512 * 512,
            ff1_w + (size_t)l * 512 * 1024, ff2_w + (size_t)l * 1024 * 512, wth, wtl);
        ln_kernel<<<NROWS, 64, 0, stream>>>(xbuf, ln1_g + l * 512, ln1_b + l * 512, xnh, xnl);
        gemm_mfma<128, 0><<<dim3(1536 / 128, MB), 256, 0, stream>>>(
            xnh, xnl, wth, wtl, nullptr, nullptr, qkv, nullptr, nullptr,
            NROWS, 1536, 512);
        attn_flash_kernel<<<dim3(13, NHEAD, BB), 256, 0, stream>>>(qkv, atth, attl);
        gemm_mfma<64, 3><<<dim3(512 / 64, MB), 256, 0, stream>>>(
            atth, attl, wth + 786432, wtl + 786432, attn_out_b + l * 512, xbuf,
            xbuf, nullptr, nullptr, NROWS, 512, 512);
        ln_kernel<<<NROWS, 64, 0, stream>>>(xbuf, ln2_g + l * 512, ln2_b + l * 512, xnh, xnl);
        gemm_mfma<128, 2><<<dim3(1024 / 128, MB), 256, 0, stream>>>(
            xnh, xnl, wth + 1048576, wtl + 1048576, ff1_b + l * 1024, nullptr,
            nullptr, ffhh, ffhl, NROWS, 1024, 512);
        gemm_mfma<64, 3><<<dim3(512 / 64, MB), 256, 0, stream>>>(
            ffhh, ffhl, wth + 1572864, wtl + 1572864, ff2_b + l * 512, xbuf,
            xbuf, nullptr, nullptr, NROWS, 512, 1024);
    }
    pool_max_kernel<<<dim3(13, BB), 512, 0, stream>>>(xbuf, ppart);
    pool_ln_kernel<<<BB, 512, 0, stream>>>(ppart, head_ln_g, head_ln_b, pooled);
    head1_kernel<<<dim3(16, BB), 256, 0, stream>>>(pooled, head1_w, head1_b, h1);
    head2_kernel<<<dim3(17, BB), 256, 0, stream>>>(h1, head2_w, head2_b, h2);
    smax_anchor_kernel<<<BB * 17, 64, 0, stream>>>(h2, (float*)d_out);
}

// Round 5
// 2207.636 us; speedup vs baseline: 6.5997x; 1.2566x over previous
//
#include <hip/hip_runtime.h>
#include <hip/hip_bf16.h>
#include <cstddef>

// Problem constants
#define BB 8
#define LL 5
#define NN 4096
#define NANCH 64
#define NPTS 4160      // NN + NANCH
#define MM 260         // NPTS / 16
#define NFRAME 3
#define SSEQ 780       // NFRAME * MM
#define DIMC 512
#define NHEAD 8
#define DHEAD 64
#define MLPD 1024
#define OUTD 1088
#define NROWS 6240     // BB * SSEQ

typedef __attribute__((ext_vector_type(8))) short s16x8;
typedef __attribute__((ext_vector_type(4))) float fx4;
typedef unsigned short ushort_t;
typedef unsigned int uint_t;

// exact (non-contracted) squared distance, matching numpy fp32 op order
__device__ __forceinline__ float sqdist_rn(float x1, float y1, float z1,
                                           float x2, float y2, float z2) {
    float dx = __fsub_rn(x1, x2);
    float dy = __fsub_rn(y1, y2);
    float dz = __fsub_rn(z1, z2);
    return __fadd_rn(__fadd_rn(__fmul_rn(dx, dx), __fmul_rn(dy, dy)), __fmul_rn(dz, dz));
}

__device__ __forceinline__ float gelu_exact(float v) {
    return 0.5f * v * (1.0f + erff(v * 0.70710678118654752440f));
}

// round-to-nearest bf16
__device__ __forceinline__ uint_t bf16rn(float f) {
    uint_t u = __float_as_uint(f);
    return (u + 0x7FFFu + ((u >> 16) & 1u)) >> 16;
}
// split fp32 into bf16 hi + bf16 lo (residual)
__device__ __forceinline__ void split2(float f, ushort_t& h, ushort_t& l) {
    uint_t hb = bf16rn(f);
    h = (ushort_t)hb;
    float fh = __uint_as_float(hb << 16);
    l = (ushort_t)bf16rn(f - fh);
}

// ---------------------------------------------------------------------------
__global__ __launch_bounds__(256) void build_pts_kernel(const float* __restrict__ points,
                                                        float* __restrict__ pts) {
    int i = blockIdx.x * 256 + threadIdx.x;   // over B*L*NPTS = 166400
    if (i >= BB * LL * NPTS) return;
    int n = i % NPTS;
    int bl = i / NPTS;
    if (n < NN) {
        const float* src = points + ((size_t)bl * NN + n) * 3;
        pts[(size_t)i * 3 + 0] = src[0];
        pts[(size_t)i * 3 + 1] = src[1];
        pts[(size_t)i * 3 + 2] = src[2];
    } else {
        int j = n - NN;
        int ix = j >> 4, iy = (j >> 2) & 3, iz = j & 3;
        pts[(size_t)i * 3 + 0] = -1.5f + (float)ix;
        pts[(size_t)i * 3 + 1] = -1.5f + (float)iy;
        pts[(size_t)i * 3 + 2] = -1.5f + (float)iz;
    }
}

// ---------------------------------------------------------------------------
// FPS: 1 block per (b, f); 260 serial iterations.
// ---------------------------------------------------------------------------
__global__ __launch_bounds__(256) void fps_kernel(const float* __restrict__ pts,
                                                  float* __restrict__ axyz) {
    int blk = blockIdx.x;           // 0..23
    int b = blk / 3, f = blk % 3;
    const float* P = pts + (size_t)(b * LL + 2 * f) * NPTS * 3;
    int tid = threadIdx.x;
    const int PPT = 17;             // ceil(4160/256)
    __shared__ float sx[NPTS], sy[NPTS], sz[NPTS];
    __shared__ float redv[2][4];
    __shared__ int redi[2][4];
    float px[PPT], py[PPT], pz[PPT], dist[PPT];
#pragma unroll
    for (int j = 0; j < PPT; j++) {
        int n = tid + 256 * j;
        if (n < NPTS) {
            float gx = P[(size_t)n * 3 + 0];
            float gy = P[(size_t)n * 3 + 1];
            float gz = P[(size_t)n * 3 + 2];
            px[j] = gx; py[j] = gy; pz[j] = gz;
            sx[n] = gx; sy[n] = gy; sz[n] = gz;
            dist[j] = 1e10f;
        } else {
            px[j] = 0.f; py[j] = 0.f; pz[j] = 0.f;
            dist[j] = -1.0f;   // never selected
        }
    }
    __syncthreads();
    float ax = sx[0], ay = sy[0], az = sz[0];
    float* out = axyz + (size_t)blk * MM * 3;
    for (int m = 0; m < MM; m++) {
        if (tid == 0) { out[m * 3 + 0] = ax; out[m * 3 + 1] = ay; out[m * 3 + 2] = az; }
        float bestv = -1.0f;
        int bestn = NPTS;
#pragma unroll
        for (int j = 0; j < PPT; j++) {
            int n = tid + 256 * j;
            if (n < NPTS) {
                float d = sqdist_rn(px[j], py[j], pz[j], ax, ay, az);
                float dj = fminf(dist[j], d);
                dist[j] = dj;
                if (dj > bestv) { bestv = dj; bestn = n; }
            }
        }
#pragma unroll
        for (int off = 32; off; off >>= 1) {
            float ov = __shfl_xor(bestv, off);
            int on = __shfl_xor(bestn, off);
            if (ov > bestv || (ov == bestv && on < bestn)) { bestv = ov; bestn = on; }
        }
        int par = m & 1;
        if ((tid & 63) == 0) { redv[par][tid >> 6] = bestv; redi[par][tid >> 6] = bestn; }
        __syncthreads();
        float bv = redv[par][0];
        int bn = redi[par][0];
#pragma unroll
        for (int w = 1; w < 4; w++) {
            float v2 = redv[par][w]; int i2 = redi[par][w];
            if (v2 > bv || (v2 == bv && i2 < bn)) { bv = v2; bn = i2; }
        }
        ax = sx[bn]; ay = sy[bn]; az = sz[bn];
    }
}

// ---------------------------------------------------------------------------
// Ball query + grouped conv + max over k + max over window + pos embedding.
// ---------------------------------------------------------------------------
__global__ __launch_bounds__(64) void group_conv_kernel(
    const float* __restrict__ pts, const float* __restrict__ axyz,
    const float* __restrict__ conv_d_w, const float* __restrict__ conv_f_w,
    const float* __restrict__ pos_w, const float* __restrict__ pos_b,
    float* __restrict__ x) {
    int gid = blockIdx.x;                 // b*780 + f*260 + m
    int b = gid / SSEQ;
    int rem = gid % SSEQ;
    int f = rem / MM;
    int lane = threadIdx.x;
    const float* A = axyz + (size_t)gid * 3;
    float ax = A[0], ay = A[1], az = A[2];

    float cf0[8], cf1[8], cf2[8], cd0[8], cd1[8], cd2[8], cd3[8], fmx[8];
#pragma unroll
    for (int c = 0; c < 8; c++) {
        int d = lane + 64 * c;
        cf0[c] = conv_f_w[d * 3 + 0];
        cf1[c] = conv_f_w[d * 3 + 1];
        cf2[c] = conv_f_w[d * 3 + 2];
        cd0[c] = conv_d_w[d * 4 + 0];
        cd1[c] = conv_d_w[d * 4 + 1];
        cd2[c] = conv_d_w[d * 4 + 2];
        cd3[c] = conv_d_w[d * 4 + 3];
        fmx[c] = -INFINITY;
    }
    __shared__ int nbr[32];
    __shared__ float gxs[32], gys[32], gzs[32];
    const float R2 = 0.49000000953674316f;

    for (int wi = 0; wi < 3; wi++) {
        int l = 2 * f + wi - 1;
        l = l < 0 ? 0 : (l > 4 ? 4 : l);
        const float* P = pts + (size_t)(b * LL + l) * NPTS * 3;
        int cnt = 0;
        for (int base = 0; base < NPTS && cnt < 32; base += 64) {
            int n = base + lane;
            float d2 = sqdist_rn(P[(size_t)n * 3], P[(size_t)n * 3 + 1], P[(size_t)n * 3 + 2],
                                 ax, ay, az);
            bool hit = d2 < R2;
            unsigned long long mk = __ballot(hit);
            int rank = (int)__popcll(mk & (((unsigned long long)1 << lane) - 1ull));
            if (hit && (cnt + rank) < 32) nbr[cnt + rank] = n;
            cnt += (int)__popcll(mk);
        }
        __syncthreads();
        int eff = cnt < 32 ? cnt : 32;
        if (lane < 32) {
            int idx = (eff == 0) ? 0 : (lane < eff ? nbr[lane] : nbr[0]);
            gxs[lane] = P[(size_t)idx * 3 + 0];
            gys[lane] = P[(size_t)idx * 3 + 1];
            gzs[lane] = P[(size_t)idx * 3 + 2];
        }
        __syncthreads();
        float tf = (float)(wi - 1);
        for (int k = 0; k < 32; k++) {
            float gx = gxs[k], gy = gys[k], gz = gzs[k];
            float dx = gx - ax, dy = gy - ay, dz = gz - az;
#pragma unroll
            for (int c = 0; c < 8; c++) {
                float v = gx * cf0[c] + gy * cf1[c] + gz * cf2[c] +
                          dx * cd0[c] + dy * cd1[c] + dz * cd2[c] + tf * cd3[c];
                fmx[c] = fmaxf(fmx[c], v);
            }
        }
        __syncthreads();
    }
    float tcol = (float)(f + 1);
#pragma unroll
    for (int c = 0; c < 8; c++) {
        int d = lane + 64 * c;
        float pos = ax * pos_w[d * 4 + 0] + ay * pos_w[d * 4 + 1] +
                    az * pos_w[d * 4 + 2] + tcol * pos_w[d * 4 + 3] + pos_b[d];
        x[(size_t)gid * DIMC + d] = fmx[c] + pos;
    }
}

// ---------------------------------------------------------------------------
// LayerNorm over last dim 512; output written as bf16 hi/lo split (GEMM A).
// ---------------------------------------------------------------------------
__global__ __launch_bounds__(64) void ln_kernel(const float* __restrict__ x,
                                                const float* __restrict__ g,
                                                const float* __restrict__ b,
                                                ushort_t* __restrict__ yh,
                                                ushort_t* __restrict__ yl) {
    int r = blockIdx.x;
    int lane = threadIdx.x;
    const float* xr = x + (size_t)r * DIMC;
    float4 v0 = *(const float4*)(xr + lane * 8);
    float4 v1 = *(const float4*)(xr + lane * 8 + 4);
    float s = v0.x + v0.y + v0.z + v0.w + v1.x + v1.y + v1.z + v1.w;
#pragma unroll
    for (int off = 32; off; off >>= 1) s += __shfl_xor(s, off);
    float mean = s * (1.0f / 512.0f);
    float dv[8];
    dv[0] = v0.x - mean; dv[1] = v0.y - mean; dv[2] = v0.z - mean; dv[3] = v0.w - mean;
    dv[4] = v1.x - mean; dv[5] = v1.y - mean; dv[6] = v1.z - mean; dv[7] = v1.w - mean;
    float sq = 0.f;
#pragma unroll
    for (int c = 0; c < 8; c++) sq += dv[c] * dv[c];
#pragma unroll
    for (int off = 32; off; off >>= 1) sq += __shfl_xor(sq, off);
    float var = sq * (1.0f / 512.0f);
    float inv = 1.0f / sqrtf(var + 1e-5f);
    int d = lane * 8;
    ushort_t hs[8], ls[8];
#pragma unroll
    for (int c = 0; c < 8; c++) {
        float v = dv[c] * inv * g[d + c] + b[d + c];
        split2(v, hs[c], ls[c]);
    }
    uint4 hv, lv;
    hv.x = hs[0] | ((uint_t)hs[1] << 16); hv.y = hs[2] | ((uint_t)hs[3] << 16);
    hv.z = hs[4] | ((uint_t)hs[5] << 16); hv.w = hs[6] | ((uint_t)hs[7] << 16);
    lv.x = ls[0] | ((uint_t)ls[1] << 16); lv.y = ls[2] | ((uint_t)ls[3] << 16);
    lv.z = ls[4] | ((uint_t)ls[5] << 16); lv.w = ls[6] | ((uint_t)ls[7] << 16);
    *(uint4*)(yh + (size_t)r * DIMC + d) = hv;
    *(uint4*)(yl + (size_t)r * DIMC + d) = lv;
}

// ---------------------------------------------------------------------------
// Weight transpose + bf16 split for one layer's 4 matrices.
// ---------------------------------------------------------------------------
__global__ __launch_bounds__(256) void wsplit_kernel(const float* __restrict__ qkvw,
                                                     const float* __restrict__ projw,
                                                     const float* __restrict__ ff1w,
                                                     const float* __restrict__ ff2w,
                                                     ushort_t* __restrict__ th,
                                                     ushort_t* __restrict__ tl) {
    int bid = blockIdx.x;
    const float* src; int K, N; size_t dst;
    if (bid < 768)       { src = qkvw;  K = 512;  N = 1536; dst = 0;       }
    else if (bid < 1024) { src = projw; K = 512;  N = 512;  dst = 786432;  bid -= 768;  }
    else if (bid < 1536) { src = ff1w;  K = 512;  N = 1024; dst = 1048576; bid -= 1024; }
    else                 { src = ff2w;  K = 1024; N = 512;  dst = 1572864; bid -= 1536; }
    int ntn = N >> 5;
    int tn = bid % ntn, tk = bid / ntn;
    int n0 = tn * 32, k0 = tk * 32;
    __shared__ float T[32][33];
    int tid = threadIdx.x;
    int tx = tid & 31, ty = tid >> 5;
#pragma unroll
    for (int i = 0; i < 4; i++)
        T[ty + 8 * i][tx] = src[(size_t)(k0 + ty + 8 * i) * N + n0 + tx];
    __syncthreads();
#pragma unroll
    for (int i = 0; i < 4; i++) {
        int n = n0 + ty + 8 * i;
        int k = k0 + tx;
        ushort_t h, l;
        split2(T[tx][ty + 8 * i], h, l);
        th[dst + (size_t)n * K + k] = h;
        tl[dst + (size_t)n * K + k] = l;
    }
}

// ---------------------------------------------------------------------------
// bf16x3 MFMA GEMM (fp32 emulation): C = A @ W
// EPI: 0 = fp32 C; 2 = bias+gelu -> split (Ch,Cl); 3 = bias+R -> C;
//      4 = plain split store -> (Ch,Cl)
// ---------------------------------------------------------------------------
#define KP 40   // LDS row pitch in ushorts

template <int BN, int EPI>
__global__ __launch_bounds__(256, 2) void gemm_mfma(
    const ushort_t* __restrict__ Ahg, const ushort_t* __restrict__ Alg,
    const ushort_t* __restrict__ Bhg, const ushort_t* __restrict__ Blg,
    const float* __restrict__ bias, const float* __restrict__ R,
    float* __restrict__ C, ushort_t* __restrict__ Ch, ushort_t* __restrict__ Cl,
    int M, int N, int K) {
    const int WN = BN / 2, NT = WN / 16;
    __shared__ ushort_t Ah[128 * KP];
    __shared__ ushort_t Al[128 * KP];
    __shared__ ushort_t Bh[BN * KP];
    __shared__ ushort_t Bl[BN * KP];
    int tid = threadIdx.x;
    int lane = tid & 63, w = tid >> 6;
    int wm = w & 1, wn = w >> 1;
    int quad = lane >> 4, l15 = lane & 15;
    int m0 = blockIdx.y * 128, n0 = blockIdx.x * BN;

    fx4 acc[4][NT];
#pragma unroll
    for (int mi = 0; mi < 4; mi++)
#pragma unroll
        for (int nj = 0; nj < NT; nj++) acc[mi][nj] = (fx4){0.f, 0.f, 0.f, 0.f};

    for (int k0 = 0; k0 < K; k0 += 32) {
#pragma unroll
        for (int i = 0; i < 2; i++) {
            int task = tid + 256 * i;
            int row = task >> 2, kc = (task & 3) * 8;
            if (m0 + row < M) {
                size_t go = (size_t)(m0 + row) * K + k0 + kc;
                *(float4*)&Ah[row * KP + kc] = *(const float4*)(Ahg + go);
                *(float4*)&Al[row * KP + kc] = *(const float4*)(Alg + go);
            }
        }
#pragma unroll
        for (int i = 0; i < BN / 64; i++) {
            int task = tid + 256 * i;
            int row = task >> 2, kc = (task & 3) * 8;
            size_t go = (size_t)(n0 + row) * K + k0 + kc;
            *(float4*)&Bh[row * KP + kc] = *(const float4*)(Bhg + go);
            *(float4*)&Bl[row * KP + kc] = *(const float4*)(Blg + go);
        }
        __syncthreads();
        s16x8 af[4][2], bf[NT][2];
#pragma unroll
        for (int mi = 0; mi < 4; mi++) {
            int off = (64 * wm + 16 * mi + l15) * KP + quad * 8;
            af[mi][0] = *(const s16x8*)&Ah[off];
            af[mi][1] = *(const s16x8*)&Al[off];
        }
#pragma unroll
        for (int nj = 0; nj < NT; nj++) {
            int off = (WN * wn + 16 * nj + l15) * KP + quad * 8;
            bf[nj][0] = *(const s16x8*)&Bh[off];
            bf[nj][1] = *(const s16x8*)&Bl[off];
        }
#pragma unroll
        for (int mi = 0; mi < 4; mi++)
#pragma unroll
            for (int nj = 0; nj < NT; nj++) {
                acc[mi][nj] = __builtin_amdgcn_mfma_f32_16x16x32_bf16(af[mi][0], bf[nj][0], acc[mi][nj], 0, 0, 0);
                acc[mi][nj] = __builtin_amdgcn_mfma_f32_16x16x32_bf16(af[mi][0], bf[nj][1], acc[mi][nj], 0, 0, 0);
                acc[mi][nj] = __builtin_amdgcn_mfma_f32_16x16x32_bf16(af[mi][1], bf[nj][0], acc[mi][nj], 0, 0, 0);
            }
        __syncthreads();
    }
#pragma unroll
    for (int mi = 0; mi < 4; mi++) {
#pragma unroll
        for (int r = 0; r < 4; r++) {
            int row = m0 + 64 * wm + 16 * mi + quad * 4 + r;
            if (row < M) {
#pragma unroll
                for (int nj = 0; nj < NT; nj++) {
                    int col = n0 + WN * wn + 16 * nj + l15;
                    float v = acc[mi][nj][r];
                    if (EPI == 0) {
                        C[(size_t)row * N + col] = v;
                    } else if (EPI == 3) {
                        C[(size_t)row * N + col] = v + bias[col] + R[(size_t)row * N + col];
                    } else if (EPI == 2) {
                        float gv = gelu_exact(v + bias[col]);
                        ushort_t h, l;
                        split2(gv, h, l);
                        Ch[(size_t)row * N + col] = h;
                        Cl[(size_t)row * N + col] = l;
                    } else if (EPI == 4) {
                        ushort_t h, l;
                        split2(v, h, l);
                        Ch[(size_t)row * N + col] = h;
                        Cl[(size_t)row * N + col] = l;
                    }
                }
            }
        }
    }
}

// ---------------------------------------------------------------------------
// MFMA flash attention, no-max softmax (softmax is shift-invariant; scores
// here are O(1): exp(s) directly; denominator l computed by MFMA vs ones-B).
// Block = (q-tile 64, head, batch), 4 waves; wave w owns q-rows 16w..16w+15.
// qkv given as hi/lo bf16 (B*S, 1536). x3 MFMA for QK^T and PV.
// ---------------------------------------------------------------------------
#define AP 72   // ushort pitch (144 B rows): frag reads 2-way bank alias = free

__global__ __launch_bounds__(256, 2) void attn_mfma_kernel(
    const ushort_t* __restrict__ qkvh, const ushort_t* __restrict__ qkvl,
    ushort_t* __restrict__ oh, ushort_t* __restrict__ ol) {
    int qt = blockIdx.x, h = blockIdx.y, b = blockIdx.z;
    int tid = threadIdx.x;
    int lane = tid & 63, w = tid >> 6;
    int quad = lane >> 4, l15 = lane & 15;

    __shared__ __align__(16) ushort_t Qh[64 * AP], Ql[64 * AP];
    __shared__ __align__(16) ushort_t Kh[64 * AP], Kl[64 * AP];
    __shared__ __align__(16) ushort_t Vth[64 * AP], Vtl[64 * AP];  // V transposed [d][key]
    __shared__ __align__(16) ushort_t Ph[64 * AP], Pl[64 * AP];

    int q0 = qt * 64;
    int nq = SSEQ - q0; if (nq > 64) nq = 64;

    // stage Q (hi/lo), rows clamped
#pragma unroll
    for (int i = 0; i < 2; i++) {
        int t = tid + 256 * i;
        int row = t >> 3, c = (t & 7) * 8;
        int gq = q0 + (row < nq ? row : nq - 1);
        size_t go = (size_t)(b * SSEQ + gq) * 1536 + h * 64 + c;
        *(uint4*)&Qh[row * AP + c] = *(const uint4*)(qkvh + go);
        *(uint4*)&Ql[row * AP + c] = *(const uint4*)(qkvl + go);
    }

    fx4 accO[4];
#pragma unroll
    for (int dj = 0; dj < 4; dj++) accO[dj] = (fx4){0.f, 0.f, 0.f, 0.f};
    fx4 accL = (fx4){0.f, 0.f, 0.f, 0.f};

    s16x8 ones;
#pragma unroll
    for (int j = 0; j < 8; j++) ones[j] = (short)16256;   // bf16 1.0

    for (int kt = 0; kt < 13; kt++) {
        int k0 = kt * 64;
        int nk = SSEQ - k0; if (nk > 64) nk = 64;
        __syncthreads();   // prior QK/PV reads done before overwrite
        // stage K (row-major) and V (transposed), hi/lo, rows clamped
#pragma unroll
        for (int i = 0; i < 2; i++) {
            int t = tid + 256 * i;
            int row = t >> 3, c = (t & 7) * 8;
            int gk = k0 + (row < nk ? row : nk - 1);
            size_t go = (size_t)(b * SSEQ + gk) * 1536 + h * 64 + c;
            *(uint4*)&Kh[row * AP + c] = *(const uint4*)(qkvh + go + 512);
            *(uint4*)&Kl[row * AP + c] = *(const uint4*)(qkvl + go + 512);
            uint4 vh = *(const uint4*)(qkvh + go + 1024);
            uint4 vl = *(const uint4*)(qkvl + go + 1024);
            const ushort_t* vhp = (const ushort_t*)&vh;
            const ushort_t* vlp = (const ushort_t*)&vl;
#pragma unroll
            for (int j = 0; j < 8; j++) {
                Vth[(c + j) * AP + row] = vhp[j];
                Vtl[(c + j) * AP + row] = vlp[j];
            }
        }
        __syncthreads();

        // S = Q K^T (x3): wave's 16 q rows x 64 keys
        fx4 accS[4];
#pragma unroll
        for (int nj = 0; nj < 4; nj++) accS[nj] = (fx4){0.f, 0.f, 0.f, 0.f};
#pragma unroll
        for (int ks = 0; ks < 2; ks++) {
            s16x8 aH = *(const s16x8*)&Qh[(16 * w + l15) * AP + 32 * ks + quad * 8];
            s16x8 aL = *(const s16x8*)&Ql[(16 * w + l15) * AP + 32 * ks + quad * 8];
#pragma unroll
            for (int nj = 0; nj < 4; nj++) {
                s16x8 bH = *(const s16x8*)&Kh[(16 * nj + l15) * AP + 32 * ks + quad * 8];
                s16x8 bL = *(const s16x8*)&Kl[(16 * nj + l15) * AP + 32 * ks + quad * 8];
                accS[nj] = __builtin_amdgcn_mfma_f32_16x16x32_bf16(aH, bH, accS[nj], 0, 0, 0);
                accS[nj] = __builtin_amdgcn_mfma_f32_16x16x32_bf16(aH, bL, accS[nj], 0, 0, 0);
                accS[nj] = __builtin_amdgcn_mfma_f32_16x16x32_bf16(aL, bH, accS[nj], 0, 0, 0);
            }
        }
        // P = exp(S * scale), split hi/lo, write to wave-local LDS region
#pragma unroll
        for (int nj = 0; nj < 4; nj++) {
            int key = 16 * nj + l15;
            bool valid = key < nk;
#pragma unroll
            for (int r = 0; r < 4; r++) {
                float s = accS[nj][r] * 0.125f;
                float p = valid ? __expf(s) : 0.f;
                ushort_t hh, ll;
                split2(p, hh, ll);
                int qrow = 16 * w + quad * 4 + r;
                Ph[qrow * AP + key] = hh;
                Pl[qrow * AP + key] = ll;
            }
        }
        // PV (x3) + l-sum (ones-B); wave-local, in-order DS => no barrier
#pragma unroll
        for (int ks = 0; ks < 2; ks++) {
            s16x8 aPh = *(const s16x8*)&Ph[(16 * w + l15) * AP + 32 * ks + quad * 8];
            s16x8 aPl = *(const s16x8*)&Pl[(16 * w + l15) * AP + 32 * ks + quad * 8];
            accL = __builtin_amdgcn_mfma_f32_16x16x32_bf16(aPh, ones, accL, 0, 0, 0);
            accL = __builtin_amdgcn_mfma_f32_16x16x32_bf16(aPl, ones, accL, 0, 0, 0);
#pragma unroll
            for (int dj = 0; dj < 4; dj++) {
                s16x8 bVh = *(const s16x8*)&Vth[(16 * dj + l15) * AP + 32 * ks + quad * 8];
                s16x8 bVl = *(const s16x8*)&Vtl[(16 * dj + l15) * AP + 32 * ks + quad * 8];
                accO[dj] = __builtin_amdgcn_mfma_f32_16x16x32_bf16(aPh, bVh, accO[dj], 0, 0, 0);
                accO[dj] = __builtin_amdgcn_mfma_f32_16x16x32_bf16(aPh, bVl, accO[dj], 0, 0, 0);
                accO[dj] = __builtin_amdgcn_mfma_f32_16x16x32_bf16(aPl, bVh, accO[dj], 0, 0, 0);
            }
        }
    }
    // store O / l ; rows of accL align with rows of accO (C-layout)
#pragma unroll
    for (int r = 0; r < 4; r++) {
        int lq = 16 * w + quad * 4 + r;
        if (lq < nq) {
            float inv = 1.0f / accL[r];
            size_t base = (size_t)(b * SSEQ + q0 + lq) * DIMC + h * 64 + l15;
#pragma unroll
            for (int dj = 0; dj < 4; dj++) {
                ushort_t hh, ll;
                split2(accO[dj][r] * inv, hh, ll);
                oh[base + 16 * dj] = hh;
                ol[base + 16 * dj] = ll;
            }
        }
    }
}

// ---------------------------------------------------------------------------
// Head: two-stage max-pool + LN, then parallel head GEMVs (fp32).
// ---------------------------------------------------------------------------
__global__ __launch_bounds__(512) void pool_max_kernel(const float* __restrict__ x,
                                                       float* __restrict__ partial) {
    int c = blockIdx.x;        // 0..12 (chunks of 60 rows)
    int bb = blockIdx.y;
    int d = threadIdx.x;
    const float* xb = x + ((size_t)(bb * SSEQ + c * 60)) * DIMC + d;
    float m = -INFINITY;
#pragma unroll 4
    for (int s = 0; s < 60; s++) m = fmaxf(m, xb[(size_t)s * DIMC]);
    partial[((size_t)bb * 13 + c) * DIMC + d] = m;
}

__global__ __launch_bounds__(512) void pool_ln_kernel(const float* __restrict__ partial,
                                                      const float* __restrict__ g,
                                                      const float* __restrict__ b,
                                                      float* __restrict__ out) {
    int bb = blockIdx.x;
    int d = threadIdx.x;
    const float* pb = partial + (size_t)bb * 13 * DIMC + d;
    float m = -INFINITY;
#pragma unroll
    for (int c = 0; c < 13; c++) m = fmaxf(m, pb[(size_t)c * DIMC]);
    __shared__ float col[512];
    __shared__ float red[512];
    col[d] = m;
    red[d] = m;
    __syncthreads();
    for (int s = 256; s > 0; s >>= 1) {
        if (d < s) red[d] += red[d + s];
        __syncthreads();
    }
    float mean = red[0] * (1.0f / 512.0f);
    __syncthreads();
    float dv = col[d] - mean;
    red[d] = dv * dv;
    __syncthreads();
    for (int s = 256; s > 0; s >>= 1) {
        if (d < s) red[d] += red[d + s];
        __syncthreads();
    }
    float var = red[0] * (1.0f / 512.0f);
    float inv = 1.0f / sqrtf(var + 1e-5f);
    out[(size_t)bb * DIMC + d] = dv * inv * g[d] + b[d];
}

__global__ __launch_bounds__(256) void head1_kernel(const float* __restrict__ in,
                                                    const float* __restrict__ W,
                                                    const float* __restrict__ bias,
                                                    float* __restrict__ out) {
    int g = blockIdx.x, bb = blockIdx.y;
    int tid = threadIdx.x;
    int c = tid & 63, ks = tid >> 6;
    int col = g * 64 + c;
    __shared__ float xr[512];
    xr[tid] = in[(size_t)bb * 512 + tid];
    xr[tid + 256] = in[(size_t)bb * 512 + tid + 256];
    __syncthreads();
    float acc = 0.f;
    const float* Wc = W + col;
    for (int k = ks * 128; k < ks * 128 + 128; k++)
        acc += xr[k] * Wc[(size_t)k * MLPD];
    __shared__ float red[256];
    red[tid] = acc;
    __syncthreads();
    if (ks == 0) {
        float v = red[c] + red[c + 64] + red[c + 128] + red[c + 192] + bias[col];
        out[(size_t)bb * MLPD + col] = gelu_exact(v);
    }
}

__global__ __launch_bounds__(256) void head2_kernel(const float* __restrict__ in,
                                                    const float* __restrict__ W,
                                                    const float* __restrict__ bias,
                                                    float* __restrict__ out) {
    int g = blockIdx.x, bb = blockIdx.y;
    int tid = threadIdx.x;
    int c = tid & 63, ks = tid >> 6;
    int col = g * 64 + c;
    __shared__ float xr[1024];
    xr[tid] = in[(size_t)bb * 1024 + tid];
    xr[tid + 256] = in[(size_t)bb * 1024 + tid + 256];
    xr[tid + 512] = in[(size_t)bb * 1024 + tid + 512];
    xr[tid + 768] = in[(size_t)bb * 1024 + tid + 768];
    __syncthreads();
    float acc = 0.f;
    const float* Wc = W + col;
    for (int k = ks * 256; k < ks * 256 + 256; k++)
        acc += xr[k] * Wc[(size_t)k * OUTD];
    __shared__ float red[256];
    red[tid] = acc;
    __syncthreads();
    if (ks == 0) {
        out[(size_t)bb * OUTD + col] = red[c] + red[c + 64] + red[c + 128] + red[c + 192] + bias[col];
    }
}

__global__ __launch_bounds__(64) void smax_anchor_kernel(const float* __restrict__ h2,
                                                         float* __restrict__ out) {
    int bb = blockIdx.x / 17;
    int gcol = blockIdx.x % 17;
    int j = threadIdx.x;
    float v = h2[(size_t)bb * OUTD + gcol * 64 + j];
    float mx = v;
#pragma unroll
    for (int off = 32; off; off >>= 1) mx = fmaxf(mx, __shfl_xor(mx, off));
    float p = expf(v - mx);
    float sum = p;
#pragma unroll
    for (int off = 32; off; off >>= 1) sum += __shfl_xor(sum, off);
    int ix = j >> 4, iy = (j >> 2) & 3, iz = j & 3;
    float sx = p * (-1.5f + (float)ix);
    float sy = p * (-1.5f + (float)iy);
    float sz = p * (-1.5f + (float)iz);
#pragma unroll
    for (int off = 32; off; off >>= 1) {
        sx += __shfl_xor(sx, off);
        sy += __shfl_xor(sy, off);
        sz += __shfl_xor(sz, off);
    }
    if (j == 0) {
        float* o = out + ((size_t)bb * 17 + gcol) * 3;
        o[0] = sx / sum;
        o[1] = sy / sum;
        o[2] = sz / sum;
    }
}

// ---------------------------------------------------------------------------
extern "C" void kernel_launch(void* const* d_in, const int* in_sizes, int n_in,
                              void* d_out, int out_size, void* d_ws, size_t ws_size,
                              hipStream_t stream) {
    const float* points     = (const float*)d_in[0];
    const float* conv_d_w   = (const float*)d_in[1];
    const float* conv_f_w   = (const float*)d_in[2];
    const float* pos_w      = (const float*)d_in[3];
    const float* pos_b      = (const float*)d_in[4];
    const float* ln1_g      = (const float*)d_in[5];
    const float* ln1_b      = (const float*)d_in[6];
    const float* qkv_w      = (const float*)d_in[7];
    const float* attn_out_w = (const float*)d_in[8];
    const float* attn_out_b = (const float*)d_in[9];
    const float* ln2_g      = (const float*)d_in[10];
    const float* ln2_b      = (const float*)d_in[11];
    const float* ff1_w      = (const float*)d_in[12];
    const float* ff1_b      = (const float*)d_in[13];
    const float* ff2_w      = (const float*)d_in[14];
    const float* ff2_b      = (const float*)d_in[15];
    const float* head_ln_g  = (const float*)d_in[16];
    const float* head_ln_b  = (const float*)d_in[17];
    const float* head1_w    = (const float*)d_in[18];
    const float* head1_b    = (const float*)d_in[19];
    const float* head2_w    = (const float*)d_in[20];
    const float* head2_b    = (const float*)d_in[21];

    // fp32 region
    float* ws = (float*)d_ws;
    float* pts    = ws;                    //   499,200 f
    float* axyz   = pts + 499200;          //    18,720 f
    float* xbuf   = axyz + 18720;          // 3,194,880 f
    float* qkvreg = xbuf + 3194880;        // 9,584,640 f (as 2x ushort arrays)
    float* pooled = qkvreg + 9584640;      //     4,096 f
    float* h1     = pooled + 4096;         //     8,192 f
    float* h2     = h1 + 8192;             //     8,704 f
    float* fend   = h2 + 8704;
    // qkv as hi/lo bf16 inside qkvreg
    ushort_t* qkvh = (ushort_t*)qkvreg;            // 9,584,640 us
    ushort_t* qkvl = qkvh + 9584640;               // 9,584,640 us
    // bf16 hi/lo region (ushort)
    ushort_t* us   = (ushort_t*)fend;
    ushort_t* xnh  = us;                   // 3,194,880 us
    ushort_t* xnl  = xnh + 3194880;
    ushort_t* atth = xnl + 3194880;
    ushort_t* attl = atth + 3194880;
    ushort_t* ffhh = attl + 3194880;       // 6,389,760 us
    ushort_t* ffhl = ffhh + 6389760;
    ushort_t* wth  = ffhl + 6389760;       // 2,097,152 us (qkv|proj|ff1|ff2 Wt)
    ushort_t* wtl  = wth + 2097152;
    float* ppart = qkvreg;                 // alias: qkv dead after last layer

    build_pts_kernel<<<650, 256, 0, stream>>>(points, pts);
    fps_kernel<<<24, 256, 0, stream>>>(pts, axyz);
    group_conv_kernel<<<NROWS, 64, 0, stream>>>(pts, axyz, conv_d_w, conv_f_w,
                                                pos_w, pos_b, xbuf);
    const int MB = (NROWS + 127) / 128;    // 49 row-blocks
    for (int l = 0; l < 5; l++) {
        wsplit_kernel<<<2048, 256, 0, stream>>>(
            qkv_w + (size_t)l * 512 * 1536, attn_out_w + (size_t)l * 512 * 512,
            ff1_w + (size_t)l * 512 * 1024, ff2_w + (size_t)l * 1024 * 512, wth, wtl);
        ln_kernel<<<NROWS, 64, 0, stream>>>(xbuf, ln1_g + l * 512, ln1_b + l * 512, xnh, xnl);
        gemm_mfma<128, 4><<<dim3(1536 / 128, MB), 256, 0, stream>>>(
            xnh, xnl, wth, wtl, nullptr, nullptr, nullptr, qkvh, qkvl,
            NROWS, 1536, 512);
        attn_mfma_kernel<<<dim3(13, NHEAD, BB), 256, 0, stream>>>(qkvh, qkvl, atth, attl);
        gemm_mfma<64, 3><<<dim3(512 / 64, MB), 256, 0, stream>>>(
            atth, attl, wth + 786432, wtl + 786432, attn_out_b + l * 512, xbuf,
            xbuf, nullptr, nullptr, NROWS, 512, 512);
        ln_kernel<<<NROWS, 64, 0, stream>>>(xbuf, ln2_g + l * 512, ln2_b + l * 512, xnh, xnl);
        gemm_mfma<128, 2><<<dim3(1024 / 128, MB), 256, 0, stream>>>(
            xnh, xnl, wth + 1048576, wtl + 1048576, ff1_b + l * 1024, nullptr,
            nullptr, ffhh, ffhl, NROWS, 1024, 512);
        gemm_mfma<64, 3><<<dim3(512 / 64, MB), 256, 0, stream>>>(
            ffhh, ffhl, wth + 1572864, wtl + 1572864, ff2_b + l * 512, xbuf,
            xbuf, nullptr, nullptr, NROWS, 512, 1024);
    }
    pool_max_kernel<<<dim3(13, BB), 512, 0, stream>>>(xbuf, ppart);
    pool_ln_kernel<<<BB, 512, 0, stream>>>(ppart, head_ln_g, head_ln_b, pooled);
    head1_kernel<<<dim3(16, BB), 256, 0, stream>>>(pooled, head1_w, head1_b, h1);
    head2_kernel<<<dim3(17, BB), 256, 0, stream>>>(h1, head2_w, head2_b, h2);
    smax_anchor_kernel<<<BB * 17, 64, 0, stream>>>(h2, (float*)d_out);
}

// Round 7
// 2026.965 us; speedup vs baseline: 7.1879x; 1.0891x over previous
//
#include <hip/hip_runtime.h>
#include <hip/hip_bf16.h>
#include <cstddef>

// Problem constants
#define BB 8
#define LL 5
#define NN 4096
#define NANCH 64
#define NPTS 4160      // NN + NANCH
#define MM 260         // NPTS / 16
#define NFRAME 3
#define SSEQ 780       // NFRAME * MM
#define DIMC 512
#define NHEAD 8
#define DHEAD 64
#define MLPD 1024
#define OUTD 1088
#define NROWS 6240     // BB * SSEQ
#define VPITCH 784     // vT key pitch (780 padded to 16B-aligned rows)

typedef __attribute__((ext_vector_type(8))) short s16x8;
typedef __attribute__((ext_vector_type(4))) float fx4;
typedef unsigned short ushort_t;
typedef unsigned int uint_t;

// exact (non-contracted) squared distance, matching numpy fp32 op order
__device__ __forceinline__ float sqdist_rn(float x1, float y1, float z1,
                                           float x2, float y2, float z2) {
    float dx = __fsub_rn(x1, x2);
    float dy = __fsub_rn(y1, y2);
    float dz = __fsub_rn(z1, z2);
    return __fadd_rn(__fadd_rn(__fmul_rn(dx, dx), __fmul_rn(dy, dy)), __fmul_rn(dz, dz));
}

__device__ __forceinline__ float gelu_exact(float v) {
    return 0.5f * v * (1.0f + erff(v * 0.70710678118654752440f));
}

// round-to-nearest bf16
__device__ __forceinline__ uint_t bf16rn(float f) {
    uint_t u = __float_as_uint(f);
    return (u + 0x7FFFu + ((u >> 16) & 1u)) >> 16;
}
// split fp32 into bf16 hi + bf16 lo (residual)
__device__ __forceinline__ void split2(float f, ushort_t& h, ushort_t& l) {
    uint_t hb = bf16rn(f);
    h = (ushort_t)hb;
    float fh = __uint_as_float(hb << 16);
    l = (ushort_t)bf16rn(f - fh);
}

// ---- DPP wave64 reductions. ctrl must be an immediate -> template param.
// row_shr:N = 0x110|N, row_bcast15 = 0x142, row_bcast31 = 0x143.
// bound_ctrl=true: shifted-in lanes read 0 (safe here: fps dists >= 0; sums
// get +0; smax uses result only as a lane-consistent softmax shift).
template <int CTRL>
__device__ __forceinline__ int dpp_mov(int v) {
    return __builtin_amdgcn_update_dpp(0, v, CTRL, 0xF, 0xF, true);
}
#define DPP_STEP_F(op, v, ctrl) v = op(v, __int_as_float(dpp_mov<ctrl>(__float_as_int(v))))
__device__ __forceinline__ float wave_max_bcast(float v) {
    DPP_STEP_F(fmaxf, v, 0x111); DPP_STEP_F(fmaxf, v, 0x112);
    DPP_STEP_F(fmaxf, v, 0x114); DPP_STEP_F(fmaxf, v, 0x118);
    DPP_STEP_F(fmaxf, v, 0x142); DPP_STEP_F(fmaxf, v, 0x143);
    return __int_as_float(__builtin_amdgcn_readlane(__float_as_int(v), 63));
}
__device__ __forceinline__ float faddf(float a, float b) { return a + b; }
__device__ __forceinline__ float wave_sum_bcast(float v) {
    DPP_STEP_F(faddf, v, 0x111); DPP_STEP_F(faddf, v, 0x112);
    DPP_STEP_F(faddf, v, 0x114); DPP_STEP_F(faddf, v, 0x118);
    DPP_STEP_F(faddf, v, 0x142); DPP_STEP_F(faddf, v, 0x143);
    return __int_as_float(__builtin_amdgcn_readlane(__float_as_int(v), 63));
}
#define DPP_STEP_I(v, ctrl) { int _x = dpp_mov<ctrl>(v); v = v > _x ? v : _x; }
__device__ __forceinline__ int wave_maxi_bcast(int v) {
    DPP_STEP_I(v, 0x111); DPP_STEP_I(v, 0x112);
    DPP_STEP_I(v, 0x114); DPP_STEP_I(v, 0x118);
    DPP_STEP_I(v, 0x142); DPP_STEP_I(v, 0x143);
    return __builtin_amdgcn_readlane(v, 63);
}

// ---------------------------------------------------------------------------
__global__ __launch_bounds__(256) void build_pts_kernel(const float* __restrict__ points,
                                                        float* __restrict__ pts) {
    int i = blockIdx.x * 256 + threadIdx.x;   // over B*L*NPTS = 166400
    if (i >= BB * LL * NPTS) return;
    int n = i % NPTS;
    int bl = i / NPTS;
    if (n < NN) {
        const float* src = points + ((size_t)bl * NN + n) * 3;
        pts[(size_t)i * 3 + 0] = src[0];
        pts[(size_t)i * 3 + 1] = src[1];
        pts[(size_t)i * 3 + 2] = src[2];
    } else {
        int j = n - NN;
        int ix = j >> 4, iy = (j >> 2) & 3, iz = j & 3;
        pts[(size_t)i * 3 + 0] = -1.5f + (float)ix;
        pts[(size_t)i * 3 + 1] = -1.5f + (float)iy;
        pts[(size_t)i * 3 + 2] = -1.5f + (float)iz;
    }
}

// ---------------------------------------------------------------------------
// FPS: 1 block per (b, f); 260 serial iterations, DPP argmax reduction.
// argmax semantics == numpy: max value, first index on ties.
// ---------------------------------------------------------------------------
__global__ __launch_bounds__(256) void fps_kernel(const float* __restrict__ pts,
                                                  float* __restrict__ axyz) {
    int blk = blockIdx.x;           // 0..23
    int b = blk / 3, f = blk % 3;
    const float* P = pts + (size_t)(b * LL + 2 * f) * NPTS * 3;
    int tid = threadIdx.x;
    int lane = tid & 63, wid = tid >> 6;
    const int PPT = 17;             // ceil(4160/256)
    __shared__ float sx[NPTS], sy[NPTS], sz[NPTS];
    __shared__ float redv[2][4];
    __shared__ int redi[2][4];
    float px[PPT], py[PPT], pz[PPT], dist[PPT];
#pragma unroll
    for (int j = 0; j < PPT; j++) {
        int n = tid + 256 * j;
        if (n < NPTS) {
            float gx = P[(size_t)n * 3 + 0];
            float gy = P[(size_t)n * 3 + 1];
            float gz = P[(size_t)n * 3 + 2];
            px[j] = gx; py[j] = gy; pz[j] = gz;
            sx[n] = gx; sy[n] = gy; sz[n] = gz;
            dist[j] = 1e10f;
        } else {
            px[j] = 0.f; py[j] = 0.f; pz[j] = 0.f;
            dist[j] = -1.0f;   // never selected
        }
    }
    __syncthreads();
    float ax = sx[0], ay = sy[0], az = sz[0];
    float* out = axyz + (size_t)blk * MM * 3;
    for (int m = 0; m < MM; m++) {
        if (tid == 0) { out[m * 3 + 0] = ax; out[m * 3 + 1] = ay; out[m * 3 + 2] = az; }
        float bestv = -1.0f;
        int bestn = NPTS;
#pragma unroll
        for (int j = 0; j < PPT; j++) {
            int n = tid + 256 * j;
            if (n < NPTS) {
                float d = sqdist_rn(px[j], py[j], pz[j], ax, ay, az);
                float dj = fminf(dist[j], d);
                dist[j] = dj;
                if (dj > bestv) { bestv = dj; bestn = n; }   // ascending n: keeps first
            }
        }
        // wave-level: exact max (dist >= 0 so DPP's shifted-in 0 is harmless),
        // then min-index among lanes holding the max (via max of INT_MAX-n).
        float wm = wave_max_bcast(bestv);
        int wn = 0x7FFFFFFF - wave_maxi_bcast(bestv == wm ? (0x7FFFFFFF - bestn) : 0);
        int par = m & 1;
        if (lane == 0) { redv[par][wid] = wm; redi[par][wid] = wn; }
        __syncthreads();
        float bv = redv[par][0];
        int bn = redi[par][0];
#pragma unroll
        for (int w = 1; w < 4; w++) {
            float v2 = redv[par][w]; int i2 = redi[par][w];
            if (v2 > bv || (v2 == bv && i2 < bn)) { bv = v2; bn = i2; }
        }
        ax = sx[bn]; ay = sy[bn]; az = sz[bn];
    }
}

// ---------------------------------------------------------------------------
// Ball query + grouped conv + max over k + max over window + pos embedding.
// ---------------------------------------------------------------------------
__global__ __launch_bounds__(64) void group_conv_kernel(
    const float* __restrict__ pts, const float* __restrict__ axyz,
    const float* __restrict__ conv_d_w, const float* __restrict__ conv_f_w,
    const float* __restrict__ pos_w, const float* __restrict__ pos_b,
    float* __restrict__ x) {
    int gid = blockIdx.x;                 // b*780 + f*260 + m
    int b = gid / SSEQ;
    int rem = gid % SSEQ;
    int f = rem / MM;
    int lane = threadIdx.x;
    const float* A = axyz + (size_t)gid * 3;
    float ax = A[0], ay = A[1], az = A[2];

    float cf0[8], cf1[8], cf2[8], cd0[8], cd1[8], cd2[8], cd3[8], fmx[8];
#pragma unroll
    for (int c = 0; c < 8; c++) {
        int d = lane + 64 * c;
        cf0[c] = conv_f_w[d * 3 + 0];
        cf1[c] = conv_f_w[d * 3 + 1];
        cf2[c] = conv_f_w[d * 3 + 2];
        cd0[c] = conv_d_w[d * 4 + 0];
        cd1[c] = conv_d_w[d * 4 + 1];
        cd2[c] = conv_d_w[d * 4 + 2];
        cd3[c] = conv_d_w[d * 4 + 3];
        fmx[c] = -INFINITY;
    }
    __shared__ int nbr[32];
    __shared__ float gxs[32], gys[32], gzs[32];
    const float R2 = 0.49000000953674316f;

    for (int wi = 0; wi < 3; wi++) {
        int l = 2 * f + wi - 1;
        l = l < 0 ? 0 : (l > 4 ? 4 : l);
        const float* P = pts + (size_t)(b * LL + l) * NPTS * 3;
        int cnt = 0;
        for (int base = 0; base < NPTS && cnt < 32; base += 64) {
            int n = base + lane;
            float d2 = sqdist_rn(P[(size_t)n * 3], P[(size_t)n * 3 + 1], P[(size_t)n * 3 + 2],
                                 ax, ay, az);
            bool hit = d2 < R2;
            unsigned long long mk = __ballot(hit);
            int rank = (int)__popcll(mk & (((unsigned long long)1 << lane) - 1ull));
            if (hit && (cnt + rank) < 32) nbr[cnt + rank] = n;
            cnt += (int)__popcll(mk);
        }
        __syncthreads();
        int eff = cnt < 32 ? cnt : 32;
        if (lane < 32) {
            int idx = (eff == 0) ? 0 : (lane < eff ? nbr[lane] : nbr[0]);
            gxs[lane] = P[(size_t)idx * 3 + 0];
            gys[lane] = P[(size_t)idx * 3 + 1];
            gzs[lane] = P[(size_t)idx * 3 + 2];
        }
        __syncthreads();
        float tf = (float)(wi - 1);
        for (int k = 0; k < 32; k++) {
            float gx = gxs[k], gy = gys[k], gz = gzs[k];
            float dx = gx - ax, dy = gy - ay, dz = gz - az;
#pragma unroll
            for (int c = 0; c < 8; c++) {
                float v = gx * cf0[c] + gy * cf1[c] + gz * cf2[c] +
                          dx * cd0[c] + dy * cd1[c] + dz * cd2[c] + tf * cd3[c];
                fmx[c] = fmaxf(fmx[c], v);
            }
        }
        __syncthreads();
    }
    float tcol = (float)(f + 1);
#pragma unroll
    for (int c = 0; c < 8; c++) {
        int d = lane + 64 * c;
        float pos = ax * pos_w[d * 4 + 0] + ay * pos_w[d * 4 + 1] +
                    az * pos_w[d * 4 + 2] + tcol * pos_w[d * 4 + 3] + pos_b[d];
        x[(size_t)gid * DIMC + d] = fmx[c] + pos;
    }
}

// ---------------------------------------------------------------------------
// LayerNorm over last dim 512; output written as bf16 hi/lo split (GEMM A).
// DPP sums (no bpermute chains).
// ---------------------------------------------------------------------------
__global__ __launch_bounds__(64) void ln_kernel(const float* __restrict__ x,
                                                const float* __restrict__ g,
                                                const float* __restrict__ b,
                                                ushort_t* __restrict__ yh,
                                                ushort_t* __restrict__ yl) {
    int r = blockIdx.x;
    int lane = threadIdx.x;
    const float* xr = x + (size_t)r * DIMC;
    float4 v0 = *(const float4*)(xr + lane * 8);
    float4 v1 = *(const float4*)(xr + lane * 8 + 4);
    float s = v0.x + v0.y + v0.z + v0.w + v1.x + v1.y + v1.z + v1.w;
    s = wave_sum_bcast(s);
    float mean = s * (1.0f / 512.0f);
    float dv[8];
    dv[0] = v0.x - mean; dv[1] = v0.y - mean; dv[2] = v0.z - mean; dv[3] = v0.w - mean;
    dv[4] = v1.x - mean; dv[5] = v1.y - mean; dv[6] = v1.z - mean; dv[7] = v1.w - mean;
    float sq = 0.f;
#pragma unroll
    for (int c = 0; c < 8; c++) sq += dv[c] * dv[c];
    sq = wave_sum_bcast(sq);
    float var = sq * (1.0f / 512.0f);
    float inv = 1.0f / sqrtf(var + 1e-5f);
    int d = lane * 8;
    ushort_t hs[8], ls[8];
#pragma unroll
    for (int c = 0; c < 8; c++) {
        float v = dv[c] * inv * g[d + c] + b[d + c];
        split2(v, hs[c], ls[c]);
    }
    uint4 hv, lv;
    hv.x = hs[0] | ((uint_t)hs[1] << 16); hv.y = hs[2] | ((uint_t)hs[3] << 16);
    hv.z = hs[4] | ((uint_t)hs[5] << 16); hv.w = hs[6] | ((uint_t)hs[7] << 16);
    lv.x = ls[0] | ((uint_t)ls[1] << 16); lv.y = ls[2] | ((uint_t)ls[3] << 16);
    lv.z = ls[4] | ((uint_t)ls[5] << 16); lv.w = ls[6] | ((uint_t)ls[7] << 16);
    *(uint4*)(yh + (size_t)r * DIMC + d) = hv;
    *(uint4*)(yl + (size_t)r * DIMC + d) = lv;
}

// ---------------------------------------------------------------------------
// Weight transpose + bf16 split for one layer's 4 matrices.
// ---------------------------------------------------------------------------
__global__ __launch_bounds__(256) void wsplit_kernel(const float* __restrict__ qkvw,
                                                     const float* __restrict__ projw,
                                                     const float* __restrict__ ff1w,
                                                     const float* __restrict__ ff2w,
                                                     ushort_t* __restrict__ th,
                                                     ushort_t* __restrict__ tl) {
    int bid = blockIdx.x;
    const float* src; int K, N; size_t dst;
    if (bid < 768)       { src = qkvw;  K = 512;  N = 1536; dst = 0;       }
    else if (bid < 1024) { src = projw; K = 512;  N = 512;  dst = 786432;  bid -= 768;  }
    else if (bid < 1536) { src = ff1w;  K = 512;  N = 1024; dst = 1048576; bid -= 1024; }
    else                 { src = ff2w;  K = 1024; N = 512;  dst = 1572864; bid -= 1536; }
    int ntn = N >> 5;
    int tn = bid % ntn, tk = bid / ntn;
    int n0 = tn * 32, k0 = tk * 32;
    __shared__ float T[32][33];
    int tid = threadIdx.x;
    int tx = tid & 31, ty = tid >> 5;
#pragma unroll
    for (int i = 0; i < 4; i++)
        T[ty + 8 * i][tx] = src[(size_t)(k0 + ty + 8 * i) * N + n0 + tx];
    __syncthreads();
#pragma unroll
    for (int i = 0; i < 4; i++) {
        int n = n0 + ty + 8 * i;
        int k = k0 + tx;
        ushort_t h, l;
        split2(T[tx][ty + 8 * i], h, l);
        th[dst + (size_t)n * K + k] = h;
        tl[dst + (size_t)n * K + k] = l;
    }
}

// ---------------------------------------------------------------------------
// bf16x3 MFMA GEMM (fp32 emulation): C = A @ W
// EPI: 0 = fp32 C; 2 = bias+gelu -> split (Ch,Cl); 3 = bias+R -> C;
//      5 = qkv: Q/K cols -> split (Ch,Cl) stride 1024; V cols -> transposed
//          vT[(b*8+h)*64+d][key] split (Vh,Vl), key pitch VPITCH.
// ---------------------------------------------------------------------------
#define KP 40   // LDS row pitch in ushorts

template <int BN, int EPI>
__global__ __launch_bounds__(256, 2) void gemm_mfma(
    const ushort_t* __restrict__ Ahg, const ushort_t* __restrict__ Alg,
    const ushort_t* __restrict__ Bhg, const ushort_t* __restrict__ Blg,
    const float* __restrict__ bias, const float* __restrict__ R,
    float* __restrict__ C, ushort_t* __restrict__ Ch, ushort_t* __restrict__ Cl,
    ushort_t* __restrict__ Vh, ushort_t* __restrict__ Vl,
    int M, int N, int K) {
    const int WN = BN / 2, NT = WN / 16;
    __shared__ ushort_t Ah[128 * KP];
    __shared__ ushort_t Al[128 * KP];
    __shared__ ushort_t Bh[BN * KP];
    __shared__ ushort_t Bl[BN * KP];
    int tid = threadIdx.x;
    int lane = tid & 63, w = tid >> 6;
    int wm = w & 1, wn = w >> 1;
    int quad = lane >> 4, l15 = lane & 15;
    int m0 = blockIdx.y * 128, n0 = blockIdx.x * BN;

    fx4 acc[4][NT];
#pragma unroll
    for (int mi = 0; mi < 4; mi++)
#pragma unroll
        for (int nj = 0; nj < NT; nj++) acc[mi][nj] = (fx4){0.f, 0.f, 0.f, 0.f};

    for (int k0 = 0; k0 < K; k0 += 32) {
#pragma unroll
        for (int i = 0; i < 2; i++) {
            int task = tid + 256 * i;
            int row = task >> 2, kc = (task & 3) * 8;
            if (m0 + row < M) {
                size_t go = (size_t)(m0 + row) * K + k0 + kc;
                *(float4*)&Ah[row * KP + kc] = *(const float4*)(Ahg + go);
                *(float4*)&Al[row * KP + kc] = *(const float4*)(Alg + go);
            }
        }
#pragma unroll
        for (int i = 0; i < BN / 64; i++) {
            int task = tid + 256 * i;
            int row = task >> 2, kc = (task & 3) * 8;
            size_t go = (size_t)(n0 + row) * K + k0 + kc;
            *(float4*)&Bh[row * KP + kc] = *(const float4*)(Bhg + go);
            *(float4*)&Bl[row * KP + kc] = *(const float4*)(Blg + go);
        }
        __syncthreads();
        s16x8 af[4][2], bf[NT][2];
#pragma unroll
        for (int mi = 0; mi < 4; mi++) {
            int off = (64 * wm + 16 * mi + l15) * KP + quad * 8;
            af[mi][0] = *(const s16x8*)&Ah[off];
            af[mi][1] = *(const s16x8*)&Al[off];
        }
#pragma unroll
        for (int nj = 0; nj < NT; nj++) {
            int off = (WN * wn + 16 * nj + l15) * KP + quad * 8;
            bf[nj][0] = *(const s16x8*)&Bh[off];
            bf[nj][1] = *(const s16x8*)&Bl[off];
        }
#pragma unroll
        for (int mi = 0; mi < 4; mi++)
#pragma unroll
            for (int nj = 0; nj < NT; nj++) {
                acc[mi][nj] = __builtin_amdgcn_mfma_f32_16x16x32_bf16(af[mi][0], bf[nj][0], acc[mi][nj], 0, 0, 0);
                acc[mi][nj] = __builtin_amdgcn_mfma_f32_16x16x32_bf16(af[mi][0], bf[nj][1], acc[mi][nj], 0, 0, 0);
                acc[mi][nj] = __builtin_amdgcn_mfma_f32_16x16x32_bf16(af[mi][1], bf[nj][0], acc[mi][nj], 0, 0, 0);
            }
        __syncthreads();
    }
#pragma unroll
    for (int mi = 0; mi < 4; mi++) {
#pragma unroll
        for (int r = 0; r < 4; r++) {
            int row = m0 + 64 * wm + 16 * mi + quad * 4 + r;
            if (row < M) {
#pragma unroll
                for (int nj = 0; nj < NT; nj++) {
                    int col = n0 + WN * wn + 16 * nj + l15;
                    float v = acc[mi][nj][r];
                    if (EPI == 0) {
                        C[(size_t)row * N + col] = v;
                    } else if (EPI == 3) {
                        C[(size_t)row * N + col] = v + bias[col] + R[(size_t)row * N + col];
                    } else if (EPI == 2) {
                        float gv = gelu_exact(v + bias[col]);
                        ushort_t h, l;
                        split2(gv, h, l);
                        Ch[(size_t)row * N + col] = h;
                        Cl[(size_t)row * N + col] = l;
                    } else if (EPI == 5) {
                        ushort_t h, l;
                        split2(v, h, l);
                        if (col < 1024) {
                            Ch[(size_t)row * 1024 + col] = h;
                            Cl[(size_t)row * 1024 + col] = l;
                        } else {
                            int bb = row / SSEQ, key = row % SSEQ;
                            int hh = (col - 1024) >> 6, dd = (col - 1024) & 63;
                            size_t vo = ((size_t)((bb * 8 + hh) * 64 + dd)) * VPITCH + key;
                            Vh[vo] = h;
                            Vl[vo] = l;
                        }
                    }
                }
            }
        }
    }
}

// ---------------------------------------------------------------------------
// MFMA flash attention, no-max softmax. qk given as hi/lo bf16 (B*S, 1024)
// (Q at +0, K at +512); V given pre-transposed: vT[(b*8+h)*64+d][key].
// ---------------------------------------------------------------------------
#define AP 72   // ushort pitch

__global__ __launch_bounds__(256, 2) void attn_mfma_kernel(
    const ushort_t* __restrict__ qkh, const ushort_t* __restrict__ qkl,
    const ushort_t* __restrict__ vth, const ushort_t* __restrict__ vtl,
    ushort_t* __restrict__ oh, ushort_t* __restrict__ ol) {
    int qt = blockIdx.x, h = blockIdx.y, b = blockIdx.z;
    int tid = threadIdx.x;
    int lane = tid & 63, w = tid >> 6;
    int quad = lane >> 4, l15 = lane & 15;
    int bh = b * 8 + h;

    __shared__ __align__(16) ushort_t Qh[64 * AP], Ql[64 * AP];
    __shared__ __align__(16) ushort_t Kh[64 * AP], Kl[64 * AP];
    __shared__ __align__(16) ushort_t Vth[64 * AP], Vtl[64 * AP];  // [d][key]
    __shared__ __align__(16) ushort_t Ph[64 * AP], Pl[64 * AP];

    int q0 = qt * 64;
    int nq = SSEQ - q0; if (nq > 64) nq = 64;

    // stage Q (hi/lo), rows clamped
#pragma unroll
    for (int i = 0; i < 2; i++) {
        int t = tid + 256 * i;
        int row = t >> 3, c = (t & 7) * 8;
        int gq = q0 + (row < nq ? row : nq - 1);
        size_t go = (size_t)(b * SSEQ + gq) * 1024 + h * 64 + c;
        *(uint4*)&Qh[row * AP + c] = *(const uint4*)(qkh + go);
        *(uint4*)&Ql[row * AP + c] = *(const uint4*)(qkl + go);
    }

    fx4 accO[4];
#pragma unroll
    for (int dj = 0; dj < 4; dj++) accO[dj] = (fx4){0.f, 0.f, 0.f, 0.f};
    fx4 accL = (fx4){0.f, 0.f, 0.f, 0.f};

    s16x8 ones;
#pragma unroll
    for (int j = 0; j < 8; j++) ones[j] = (short)16256;   // bf16 1.0

    for (int kt = 0; kt < 13; kt++) {
        int k0 = kt * 64;
        int nk = SSEQ - k0; if (nk > 64) nk = 64;
        __syncthreads();   // prior QK/PV reads done before overwrite
        // stage K (row-major, rows clamped) and V (direct from vT: rows=d,
        // cols=keys; overreads past key 779 are killed by P=0)
#pragma unroll
        for (int i = 0; i < 2; i++) {
            int t = tid + 256 * i;
            int row = t >> 3, c = (t & 7) * 8;
            int gk = k0 + (row < nk ? row : nk - 1);
            size_t go = (size_t)(b * SSEQ + gk) * 1024 + h * 64 + c;
            *(uint4*)&Kh[row * AP + c] = *(const uint4*)(qkh + go + 512);
            *(uint4*)&Kl[row * AP + c] = *(const uint4*)(qkl + go + 512);
            size_t vo = ((size_t)(bh * 64 + row)) * VPITCH + k0 + c;
            *(uint4*)&Vth[row * AP + c] = *(const uint4*)(vth + vo);
            *(uint4*)&Vtl[row * AP + c] = *(const uint4*)(vtl + vo);
        }
        __syncthreads();

        // S = Q K^T (x3): wave's 16 q rows x 64 keys
        fx4 accS[4];
#pragma unroll
        for (int nj = 0; nj < 4; nj++) accS[nj] = (fx4){0.f, 0.f, 0.f, 0.f};
#pragma unroll
        for (int ks = 0; ks < 2; ks++) {
            s16x8 aH = *(const s16x8*)&Qh[(16 * w + l15) * AP + 32 * ks + quad * 8];
            s16x8 aL = *(const s16x8*)&Ql[(16 * w + l15) * AP + 32 * ks + quad * 8];
#pragma unroll
            for (int nj = 0; nj < 4; nj++) {
                s16x8 bH = *(const s16x8*)&Kh[(16 * nj + l15) * AP + 32 * ks + quad * 8];
                s16x8 bL = *(const s16x8*)&Kl[(16 * nj + l15) * AP + 32 * ks + quad * 8];
                accS[nj] = __builtin_amdgcn_mfma_f32_16x16x32_bf16(aH, bH, accS[nj], 0, 0, 0);
                accS[nj] = __builtin_amdgcn_mfma_f32_16x16x32_bf16(aH, bL, accS[nj], 0, 0, 0);
                accS[nj] = __builtin_amdgcn_mfma_f32_16x16x32_bf16(aL, bH, accS[nj], 0, 0, 0);
            }
        }
        // P = exp(S * scale), split hi/lo, write to wave-local LDS region
#pragma unroll
        for (int nj = 0; nj < 4; nj++) {
            int key = 16 * nj + l15;
            bool valid = key < nk;
#pragma unroll
            for (int r = 0; r < 4; r++) {
                float s = accS[nj][r] * 0.125f;
                float p = valid ? __expf(s) : 0.f;
                ushort_t hh, ll;
                split2(p, hh, ll);
                int qrow = 16 * w + quad * 4 + r;
                Ph[qrow * AP + key] = hh;
                Pl[qrow * AP + key] = ll;
            }
        }
        // PV (x3) + l-sum (ones-B); wave-local, in-order DS => no barrier
#pragma unroll
        for (int ks = 0; ks < 2; ks++) {
            s16x8 aPh = *(const s16x8*)&Ph[(16 * w + l15) * AP + 32 * ks + quad * 8];
            s16x8 aPl = *(const s16x8*)&Pl[(16 * w + l15) * AP + 32 * ks + quad * 8];
            accL = __builtin_amdgcn_mfma_f32_16x16x32_bf16(aPh, ones, accL, 0, 0, 0);
            accL = __builtin_amdgcn_mfma_f32_16x16x32_bf16(aPl, ones, accL, 0, 0, 0);
#pragma unroll
            for (int dj = 0; dj < 4; dj++) {
                s16x8 bVh = *(const s16x8*)&Vth[(16 * dj + l15) * AP + 32 * ks + quad * 8];
                s16x8 bVl = *(const s16x8*)&Vtl[(16 * dj + l15) * AP + 32 * ks + quad * 8];
                accO[dj] = __builtin_amdgcn_mfma_f32_16x16x32_bf16(aPh, bVh, accO[dj], 0, 0, 0);
                accO[dj] = __builtin_amdgcn_mfma_f32_16x16x32_bf16(aPh, bVl, accO[dj], 0, 0, 0);
                accO[dj] = __builtin_amdgcn_mfma_f32_16x16x32_bf16(aPl, bVh, accO[dj], 0, 0, 0);
            }
        }
    }
    // store O / l ; rows of accL align with rows of accO (C-layout)
#pragma unroll
    for (int r = 0; r < 4; r++) {
        int lq = 16 * w + quad * 4 + r;
        if (lq < nq) {
            float inv = 1.0f / accL[r];
            size_t base = (size_t)(b * SSEQ + q0 + lq) * DIMC + h * 64 + l15;
#pragma unroll
            for (int dj = 0; dj < 4; dj++) {
                ushort_t hh, ll;
                split2(accO[dj][r] * inv, hh, ll);
                oh[base + 16 * dj] = hh;
                ol[base + 16 * dj] = ll;
            }
        }
    }
}

// ---------------------------------------------------------------------------
// Head: two-stage max-pool + LN, then parallel head GEMVs (fp32).
// ---------------------------------------------------------------------------
__global__ __launch_bounds__(512) void pool_max_kernel(const float* __restrict__ x,
                                                       float* __restrict__ partial) {
    int c = blockIdx.x;        // 0..12 (chunks of 60 rows)
    int bb = blockIdx.y;
    int d = threadIdx.x;
    const float* xb = x + ((size_t)(bb * SSEQ + c * 60)) * DIMC + d;
    float m = -INFINITY;
#pragma unroll 4
    for (int s = 0; s < 60; s++) m = fmaxf(m, xb[(size_t)s * DIMC]);
    partial[((size_t)bb * 13 + c) * DIMC + d] = m;
}

__global__ __launch_bounds__(512) void pool_ln_kernel(const float* __restrict__ partial,
                                                      const float* __restrict__ g,
                                                      const float* __restrict__ b,
                                                      float* __restrict__ out) {
    int bb = blockIdx.x;
    int d = threadIdx.x;
    const float* pb = partial + (size_t)bb * 13 * DIMC + d;
    float m = -INFINITY;
#pragma unroll
    for (int c = 0; c < 13; c++) m = fmaxf(m, pb[(size_t)c * DIMC]);
    __shared__ float col[512];
    __shared__ float red[512];
    col[d] = m;
    red[d] = m;
    __syncthreads();
    for (int s = 256; s > 0; s >>= 1) {
        if (d < s) red[d] += red[d + s];
        __syncthreads();
    }
    float mean = red[0] * (1.0f / 512.0f);
    __syncthreads();
    float dv = col[d] - mean;
    red[d] = dv * dv;
    __syncthreads();
    for (int s = 256; s > 0; s >>= 1) {
        if (d < s) red[d] += red[d + s];
        __syncthreads();
    }
    float var = red[0] * (1.0f / 512.0f);
    float inv = 1.0f / sqrtf(var + 1e-5f);
    out[(size_t)bb * DIMC + d] = dv * inv * g[d] + b[d];
}

__global__ __launch_bounds__(256) void head1_kernel(const float* __restrict__ in,
                                                    const float* __restrict__ W,
                                                    const float* __restrict__ bias,
                                                    float* __restrict__ out) {
    int g = blockIdx.x, bb = blockIdx.y;
    int tid = threadIdx.x;
    int c = tid & 63, ks = tid >> 6;
    int col = g * 64 + c;
    __shared__ float xr[512];
    xr[tid] = in[(size_t)bb * 512 + tid];
    xr[tid + 256] = in[(size_t)bb * 512 + tid + 256];
    __syncthreads();
    float acc = 0.f;
    const float* Wc = W + col;
    for (int k = ks * 128; k < ks * 128 + 128; k++)
        acc += xr[k] * Wc[(size_t)k * MLPD];
    __shared__ float red[256];
    red[tid] = acc;
    __syncthreads();
    if (ks == 0) {
        float v = red[c] + red[c + 64] + red[c + 128] + red[c + 192] + bias[col];
        out[(size_t)bb * MLPD + col] = gelu_exact(v);
    }
}

__global__ __launch_bounds__(256) void head2_kernel(const float* __restrict__ in,
                                                    const float* __restrict__ W,
                                                    const float* __restrict__ bias,
                                                    float* __restrict__ out) {
    int g = blockIdx.x, bb = blockIdx.y;
    int tid = threadIdx.x;
    int c = tid & 63, ks = tid >> 6;
    int col = g * 64 + c;
    __shared__ float xr[1024];
    xr[tid] = in[(size_t)bb * 1024 + tid];
    xr[tid + 256] = in[(size_t)bb * 1024 + tid + 256];
    xr[tid + 512] = in[(size_t)bb * 1024 + tid + 512];
    xr[tid + 768] = in[(size_t)bb * 1024 + tid + 768];
    __syncthreads();
    float acc = 0.f;
    const float* Wc = W + col;
    for (int k = ks * 256; k < ks * 256 + 256; k++)
        acc += xr[k] * Wc[(size_t)k * OUTD];
    __shared__ float red[256];
    red[tid] = acc;
    __syncthreads();
    if (ks == 0) {
        out[(size_t)bb * OUTD + col] = red[c] + red[c + 64] + red[c + 128] + red[c + 192] + bias[col];
    }
}

__global__ __launch_bounds__(64) void smax_anchor_kernel(const float* __restrict__ h2,
                                                         float* __restrict__ out) {
    int bb = blockIdx.x / 17;
    int gcol = blockIdx.x % 17;
    int j = threadIdx.x;
    float v = h2[(size_t)bb * OUTD + gcol * 64 + j];
    float mx = wave_max_bcast(v);
    float p = expf(v - mx);
    float sum = wave_sum_bcast(p);
    int ix = j >> 4, iy = (j >> 2) & 3, iz = j & 3;
    float sx = wave_sum_bcast(p * (-1.5f + (float)ix));
    float sy = wave_sum_bcast(p * (-1.5f + (float)iy));
    float sz = wave_sum_bcast(p * (-1.5f + (float)iz));
    if (j == 0) {
        float* o = out + ((size_t)bb * 17 + gcol) * 3;
        o[0] = sx / sum;
        o[1] = sy / sum;
        o[2] = sz / sum;
    }
}

// ---------------------------------------------------------------------------
extern "C" void kernel_launch(void* const* d_in, const int* in_sizes, int n_in,
                              void* d_out, int out_size, void* d_ws, size_t ws_size,
                              hipStream_t stream) {
    const float* points     = (const float*)d_in[0];
    const float* conv_d_w   = (const float*)d_in[1];
    const float* conv_f_w   = (const float*)d_in[2];
    const float* pos_w      = (const float*)d_in[3];
    const float* pos_b      = (const float*)d_in[4];
    const float* ln1_g      = (const float*)d_in[5];
    const float* ln1_b      = (const float*)d_in[6];
    const float* qkv_w      = (const float*)d_in[7];
    const float* attn_out_w = (const float*)d_in[8];
    const float* attn_out_b = (const float*)d_in[9];
    const float* ln2_g      = (const float*)d_in[10];
    const float* ln2_b      = (const float*)d_in[11];
    const float* ff1_w      = (const float*)d_in[12];
    const float* ff1_b      = (const float*)d_in[13];
    const float* ff2_w      = (const float*)d_in[14];
    const float* ff2_b      = (const float*)d_in[15];
    const float* head_ln_g  = (const float*)d_in[16];
    const float* head_ln_b  = (const float*)d_in[17];
    const float* head1_w    = (const float*)d_in[18];
    const float* head1_b    = (const float*)d_in[19];
    const float* head2_w    = (const float*)d_in[20];
    const float* head2_b    = (const float*)d_in[21];

    // fp32 region
    float* ws = (float*)d_ws;
    float* pts    = ws;                    //   499,200 f
    float* axyz   = pts + 499200;          //    18,720 f
    float* xbuf   = axyz + 18720;          // 3,194,880 f
    float* qkvreg = xbuf + 3194880;        // 9,601,024 f (qk + vT, hi/lo)
    float* pooled = qkvreg + 9601024;      //     4,096 f
    float* h1     = pooled + 4096;         //     8,192 f
    float* h2     = h1 + 8192;             //     8,704 f
    float* fend   = h2 + 8704;
    // qk (stride 1024) + vT hi/lo inside qkvreg
    ushort_t* qkh = (ushort_t*)qkvreg;             // 6,389,760 us
    ushort_t* qkl = qkh + 6389760;                 // 6,389,760 us
    ushort_t* vth = qkl + 6389760;                 // 3,211,264 us (8*8*64*784)
    ushort_t* vtl = vth + 3211264;                 // 3,211,264 us
    // bf16 hi/lo region (ushort)
    ushort_t* us   = (ushort_t*)fend;
    ushort_t* xnh  = us;                   // 3,194,880 us
    ushort_t* xnl  = xnh + 3194880;
    ushort_t* atth = xnl + 3194880;
    ushort_t* attl = atth + 3194880;
    ushort_t* ffhh = attl + 3194880;       // 6,389,760 us
    ushort_t* ffhl = ffhh + 6389760;
    ushort_t* wth  = ffhl + 6389760;       // 2,097,152 us (qkv|proj|ff1|ff2 Wt)
    ushort_t* wtl  = wth + 2097152;
    float* ppart = qkvreg;                 // alias: qkv dead after last layer

    build_pts_kernel<<<650, 256, 0, stream>>>(points, pts);
    fps_kernel<<<24, 256, 0, stream>>>(pts, axyz);
    group_conv_kernel<<<NROWS, 64, 0, stream>>>(pts, axyz, conv_d_w, conv_f_w,
                                                pos_w, pos_b, xbuf);
    const int MB = (NROWS + 127) / 128;    // 49 row-blocks
    for (int l = 0; l < 5; l++) {
        wsplit_kernel<<<2048, 256, 0, stream>>>(
            qkv_w + (size_t)l * 512 * 1536, attn_out_w + (size_t)l * 512 * 512,
            ff1_w + (size_t)l * 512 * 1024, ff2_w + (size_t)l * 1024 * 512, wth, wtl);
        ln_kernel<<<NROWS, 64, 0, stream>>>(xbuf, ln1_g + l * 512, ln1_b + l * 512, xnh, xnl);
        gemm_mfma<128, 5><<<dim3(1536 / 128, MB), 256, 0, stream>>>(
            xnh, xnl, wth, wtl, nullptr, nullptr, nullptr, qkh, qkl, vth, vtl,
            NROWS, 1536, 512);
        attn_mfma_kernel<<<dim3(13, NHEAD, BB), 256, 0, stream>>>(qkh, qkl, vth, vtl,
                                                                  atth, attl);
        gemm_mfma<64, 3><<<dim3(512 / 64, MB), 256, 0, stream>>>(
            atth, attl, wth + 786432, wtl + 786432, attn_out_b + l * 512, xbuf,
            xbuf, nullptr, nullptr, nullptr, nullptr, NROWS, 512, 512);
        ln_kernel<<<NROWS, 64, 0, stream>>>(xbuf, ln2_g + l * 512, ln2_b + l * 512, xnh, xnl);
        gemm_mfma<128, 2><<<dim3(1024 / 128, MB), 256, 0, stream>>>(
            xnh, xnl, wth + 1048576, wtl + 1048576, ff1_b + l * 1024, nullptr,
            nullptr, ffhh, ffhl, nullptr, nullptr, NROWS, 1024, 512);
        gemm_mfma<64, 3><<<dim3(512 / 64, MB), 256, 0, stream>>>(
            ffhh, ffhl, wth + 1572864, wtl + 1572864, ff2_b + l * 512, xbuf,
            xbuf, nullptr, nullptr, nullptr, nullptr, NROWS, 512, 1024);
    }
    pool_max_kernel<<<dim3(13, BB), 512, 0, stream>>>(xbuf, ppart);
    pool_ln_kernel<<<BB, 512, 0, stream>>>(ppart, head_ln_g, head_ln_b, pooled);
    head1_kernel<<<dim3(16, BB), 256, 0, stream>>>(pooled, head1_w, head1_b, h1);
    head2_kernel<<<dim3(17, BB), 256, 0, stream>>>(h1, head2_w, head2_b, h2);
    smax_anchor_kernel<<<BB * 17, 64, 0, stream>>>(h2, (float*)d_out);
}